// Round 6
// baseline (4178.960 us; speedup 1.0000x reference)
//
#include <hip/hip_runtime.h>
#include <cstdint>
#include <cstddef>

#define NPTS 2048
#define BATCH 8
#define KNN 20
#define BIGF 3.402823466e38f

typedef short bf16x8 __attribute__((ext_vector_type(8)));
typedef float f32x4 __attribute__((ext_vector_type(4)));

__device__ __forceinline__ unsigned short f2bf(float v) {
    uint32_t u = __float_as_uint(v);
    uint32_t r = (u + 0x7FFFu + ((u >> 16) & 1u)) >> 16;
    return (unsigned short)r;
}
__device__ __forceinline__ float bf2f(unsigned short h) {
    return __uint_as_float(((uint32_t)h) << 16);
}

// ======================= sum of squares per point =======================
__global__ __launch_bounds__(256) void sq_kernel(const float* __restrict__ x, int lda, int F,
                                                 float* __restrict__ sq)
{
    int p = blockIdx.x * 256 + threadIdx.x;   // 0..16383
    const float* xp = x + (size_t)p * lda;
    float s = 0.f;
    for (int f = 0; f < F; ++f) { float v = xp[f]; s = fmaf(v, v, s); }
    sq[p] = s;
}

// ======================= FUSED dist + top-20 select =======================
// Block: 512 threads (8 waves), 64 rows, one batch. j streamed in 16 tiles of 128.
// Per-row top-20 kept in LDS as packed u64 (flip(d2)<<32 | j): min-20 by (key, idx)
// == lax.top_k(-d2,20) set with lowest-index tie-break. d2 never materialized.
// Rows are partitioned per quarter-wave (16 lanes): merge needs no barriers.
template <int F>
__global__ __launch_bounds__(512) void distsel_kernel(const float* __restrict__ x, int lda,
                                                      const float* __restrict__ sq,
                                                      int* __restrict__ idx)
{
    constexpr int NCH = (F + 7) / 8;
    __shared__ float As[64][132];                 // x_i panel: [row][f]  (F<=128)
    __shared__ __align__(16) float Bs[8][132];    // x_j chunk: [f][col]
    __shared__ uint64_t s_arr[64][20];
    __shared__ uint64_t s_thr[64];
    __shared__ int s_cnt[64], s_amx[64];

    const int t    = threadIdx.x;
    const int lane = t & 63;
    const int qw   = lane >> 4;                   // quarter-wave id within wave
    const int tx   = t & 15;                      // col group
    const int ty   = t >> 4;                      // row group: rows ty*2, ty*2+1
    const int b    = blockIdx.y;
    const int i0   = blockIdx.x * 64;
    const float* xb  = x + (size_t)b * NPTS * lda;
    const float* sqb = sq + (size_t)b * NPTS;

    // init state + stage x_i panel
    if (t < 64) { s_thr[t] = ~0ull; s_cnt[t] = 0; s_amx[t] = 0; }
    {
        // 64 rows x up to 128 f : strided fill
        for (int e = t; e < 64 * F; e += 512) {
            int row = e / F, f = e % F;
            As[row][f] = xb[(size_t)(i0 + row) * lda + f];
        }
        if (F & 7) {            // zero-pad f up to multiple of 8 (F=3)
            for (int e = t; e < 64 * (NCH * 8 - F); e += 512) {
                int row = e / (NCH * 8 - F), f = F + e % (NCH * 8 - F);
                As[row][f] = 0.f;
            }
        }
    }
    const float sqi0 = sqb[i0 + ty * 2 + 0];
    const float sqi1 = sqb[i0 + ty * 2 + 1];
    __syncthreads();

    volatile uint64_t* vthr = s_thr;
    volatile int* vcnt = s_cnt;
    volatile int* vamx = s_amx;

    for (int jt = 0; jt < 16; ++jt) {
        const int j0 = jt * 128;
        float acc[2][8];
#pragma unroll
        for (int r = 0; r < 2; ++r)
#pragma unroll
            for (int c = 0; c < 8; ++c) acc[r][c] = 0.f;

        for (int ch = 0; ch < NCH; ++ch) {
            const int k0 = ch * 8;
            // stage Bs: 128 cols x 8 f = 1024 entries, 2 per thread
#pragma unroll
            for (int q = 0; q < 2; ++q) {
                int e = t + q * 512;
                int col = e >> 3, f = e & 7;
                float v = 0.f;
                if (F % 8 == 0 || k0 + f < F)
                    v = xb[(size_t)(j0 + col) * lda + k0 + f];
                Bs[f][col] = v;
            }
            __syncthreads();
#pragma unroll
            for (int k = 0; k < 8; ++k) {
                float a0 = As[ty * 2 + 0][k0 + k];
                float a1 = As[ty * 2 + 1][k0 + k];
                float4 b0 = *reinterpret_cast<const float4*>(&Bs[k][tx * 4]);
                float4 b1 = *reinterpret_cast<const float4*>(&Bs[k][64 + tx * 4]);
                float bv[8] = {b0.x, b0.y, b0.z, b0.w, b1.x, b1.y, b1.z, b1.w};
#pragma unroll
                for (int c = 0; c < 8; ++c) {
                    acc[0][c] = fmaf(a0, bv[c], acc[0][c]);
                    acc[1][c] = fmaf(a1, bv[c], acc[1][c]);
                }
            }
            __syncthreads();
        }

        // epilogue: d2 keys + merge into per-row top-20
        float4 sj0 = *reinterpret_cast<const float4*>(&sqb[j0 + tx * 4]);
        float4 sj1 = *reinterpret_cast<const float4*>(&sqb[j0 + 64 + tx * 4]);
        float sj[8] = {sj0.x, sj0.y, sj0.z, sj0.w, sj1.x, sj1.y, sj1.z, sj1.w};

#pragma unroll
        for (int r = 0; r < 2; ++r) {
            const int row = ty * 2 + r;
            const float si = r ? sqi1 : sqi0;
            uint64_t pk[8];
#pragma unroll
            for (int c = 0; c < 8; ++c) {
                float d = si + sj[c] - 2.f * acc[r][c];
                uint32_t u = __float_as_uint(d);
                uint32_t key = (u & 0x80000000u) ? ~u : (u | 0x80000000u);
                int j = j0 + ((c < 4) ? tx * 4 + c : 64 + tx * 4 + (c - 4));
                pk[c] = ((uint64_t)key << 32) | (uint32_t)j;
            }
            volatile uint64_t* a = &s_arr[row][0];
            uint64_t th = vthr[row];
            bool has = false;
#pragma unroll
            for (int q = 0; q < 8; ++q) has |= (pk[q] < th);
            for (;;) {
                unsigned long long bal = __ballot(has);
                unsigned mym = (unsigned)((bal >> (qw * 16)) & 0xFFFFull);
                if (!mym) break;
                int leader = qw * 16 + (__ffs((int)mym) - 1);
                if (lane == leader) {
                    uint64_t t2 = vthr[row];
                    int c2 = vcnt[row], am = vamx[row];
#pragma unroll
                    for (int q = 0; q < 8; ++q) {
                        uint64_t v = pk[q];
                        if (v < t2) {
                            if (c2 < 20) {
                                a[c2] = v; ++c2;
                                if (c2 == 20) {
                                    uint64_t mx = 0; int am2 = 0;
                                    for (int s = 0; s < 20; ++s) {
                                        uint64_t w = a[s];
                                        if (w > mx) { mx = w; am2 = s; }
                                    }
                                    t2 = mx; am = am2;
                                }
                            } else {
                                a[am] = v;
                                uint64_t mx = 0; int am2 = 0;
                                for (int s = 0; s < 20; ++s) {
                                    uint64_t w = a[s];
                                    if (w > mx) { mx = w; am2 = s; }
                                }
                                t2 = mx; am = am2;
                            }
                        }
                    }
                    vthr[row] = (c2 == 20) ? t2 : ~0ull;
                    vcnt[row] = c2; vamx[row] = am;
                    has = false;
                }
                th = vthr[row];
                if (has) {
                    bool h2 = false;
#pragma unroll
                    for (int q = 0; q < 8; ++q) h2 |= (pk[q] < th);
                    has = h2;
                }
            }
        }
    }

    __syncthreads();
    int* out = idx + ((size_t)b * NPTS + i0) * KNN;
    for (int e = t; e < 64 * KNN; e += 512) {
        int row = e / KNN, s = e % KNN;
        out[(size_t)row * KNN + s] = (int)(uint32_t)s_arr[row][s];
    }
}

// ======================= generic small GEMM: C[M,Nc] = A[M,F] @ B[F,Nc] =======================
__global__ __launch_bounds__(256) void gemm64_kernel(const float* __restrict__ A, int lda, int F,
                                                     const float* __restrict__ Bw, int ldb,
                                                     float* __restrict__ C, int ldc)
{
    __shared__ float As[16][65];
    __shared__ float Bs[16][65];
    const int i0 = blockIdx.x * 64, j0 = blockIdx.y * 64;
    const int t = threadIdx.x, tx = t & 15, ty = t >> 4;
    float acc[4][4];
#pragma unroll
    for (int r = 0; r < 4; ++r)
#pragma unroll
        for (int c = 0; c < 4; ++c) acc[r][c] = 0.f;
    const int arow = t >> 2, akq = (t & 3) * 4;
    const int bk = t >> 4, bj = (t & 15) * 4;
    for (int k0 = 0; k0 < F; k0 += 16) {
#pragma unroll
        for (int q = 0; q < 4; ++q) {
            int kk = k0 + akq + q;
            As[akq + q][arow] = (kk < F) ? A[(size_t)(i0 + arow) * lda + kk] : 0.f;
        }
        {
            int kk = k0 + bk;
#pragma unroll
            for (int q = 0; q < 4; ++q)
                Bs[bk][bj + q] = (kk < F) ? Bw[(size_t)kk * ldb + j0 + bj + q] : 0.f;
        }
        __syncthreads();
#pragma unroll
        for (int k = 0; k < 16; ++k) {
            float a[4], bb[4];
#pragma unroll
            for (int r = 0; r < 4; ++r) a[r] = As[k][ty * 4 + r];
#pragma unroll
            for (int c = 0; c < 4; ++c) bb[c] = Bs[k][tx * 4 + c];
#pragma unroll
            for (int r = 0; r < 4; ++r)
#pragma unroll
                for (int c = 0; c < 4; ++c) acc[r][c] = fmaf(a[r], bb[c], acc[r][c]);
        }
        __syncthreads();
    }
#pragma unroll
    for (int r = 0; r < 4; ++r)
#pragma unroll
        for (int c = 0; c < 4; ++c)
            C[(size_t)(i0 + ty * 4 + r) * ldc + j0 + tx * 4 + c] = acc[r][c];
}

// ======================= EdgeConv aggregate (float4 lanes, multi-point blocks) =======================
template <int FOUT>
__global__ __launch_bounds__(256) void aggregate_kernel(const float* __restrict__ apart,
                                                        const float* __restrict__ bpart,
                                                        const int* __restrict__ idx,
                                                        const float* __restrict__ g,
                                                        const float* __restrict__ be,
                                                        const float* __restrict__ mu,
                                                        const float* __restrict__ var,
                                                        float* __restrict__ out)
{
    constexpr int G   = FOUT / 4;
    constexpr int PPB = 256 / G;
    const int t  = threadIdx.x;
    const int pi = t / G;
    const int fi = t % G;
    const int p  = blockIdx.x * PPB + pi;
    const int b  = p >> 11;
    const int* nb = idx + (size_t)p * KNN;
    const float4* bp4 = reinterpret_cast<const float4*>(bpart);
    const float4* bb  = bp4 + ((size_t)b << 11) * G;

    float4 m = {-BIGF, -BIGF, -BIGF, -BIGF};
#pragma unroll 4
    for (int k = 0; k < KNN; ++k) {
        int j = nb[k];
        float4 v = bb[(size_t)j * G + fi];
        m.x = fmaxf(m.x, v.x); m.y = fmaxf(m.y, v.y);
        m.z = fmaxf(m.z, v.z); m.w = fmaxf(m.w, v.w);
    }
    float4 av = reinterpret_cast<const float4*>(apart)[(size_t)p * G + fi];
    float4 bv = bp4[(size_t)p * G + fi];
    float4 gg = reinterpret_cast<const float4*>(g)[fi];
    float4 bee = reinterpret_cast<const float4*>(be)[fi];
    float4 muu = reinterpret_cast<const float4*>(mu)[fi];
    float4 vaa = reinterpret_cast<const float4*>(var)[fi];

    float4 r;
    {
        float s, sh, vv, y;
        s = gg.x * rsqrtf(vaa.x + 1e-5f); sh = bee.x - muu.x * s;
        vv = av.x - bv.x + m.x; y = vv * s + sh; r.x = (y >= 0.f) ? y : 0.2f * y;
        s = gg.y * rsqrtf(vaa.y + 1e-5f); sh = bee.y - muu.y * s;
        vv = av.y - bv.y + m.y; y = vv * s + sh; r.y = (y >= 0.f) ? y : 0.2f * y;
        s = gg.z * rsqrtf(vaa.z + 1e-5f); sh = bee.z - muu.z * s;
        vv = av.z - bv.z + m.z; y = vv * s + sh; r.z = (y >= 0.f) ? y : 0.2f * y;
        s = gg.w * rsqrtf(vaa.w + 1e-5f); sh = bee.w - muu.w * s;
        vv = av.w - bv.w + m.w; y = vv * s + sh; r.w = (y >= 0.f) ? y : 0.2f * y;
    }
    *reinterpret_cast<float4*>(out + (size_t)p * 512 + fi * 4) = r;
}

// ======================= split-bf16 converters =======================
__global__ __launch_bounds__(256) void cvt_kernel(const float* __restrict__ in,
                                                  unsigned short* __restrict__ hi,
                                                  unsigned short* __restrict__ lo)
{
    int i = blockIdx.x * 256 + threadIdx.x;
    const float4* p = reinterpret_cast<const float4*>(in) + (size_t)i * 2;
    float4 a = p[0], b = p[1];
    float v[8] = {a.x, a.y, a.z, a.w, b.x, b.y, b.z, b.w};
    uint32_t h[8], l[8];
#pragma unroll
    for (int q = 0; q < 8; ++q) {
        unsigned short hb = f2bf(v[q]);
        h[q] = hb;
        l[q] = f2bf(v[q] - bf2f(hb));
    }
    uint4 uh, ul;
    uh.x = h[0] | (h[1] << 16); uh.y = h[2] | (h[3] << 16);
    uh.z = h[4] | (h[5] << 16); uh.w = h[6] | (h[7] << 16);
    ul.x = l[0] | (l[1] << 16); ul.y = l[2] | (l[3] << 16);
    ul.z = l[4] | (l[5] << 16); ul.w = l[6] | (l[7] << 16);
    reinterpret_cast<uint4*>(hi)[i] = uh;
    reinterpret_cast<uint4*>(lo)[i] = ul;
}

__global__ __launch_bounds__(256) void cvtT_kernel(const float* __restrict__ Wm,
                                                   unsigned short* __restrict__ hiT,
                                                   unsigned short* __restrict__ loT)
{
    __shared__ float tile[32][33];
    const int n0 = blockIdx.x * 32;
    const int k0 = blockIdx.y * 32;
    const int t = threadIdx.x;
    const int c = t & 31, r = t >> 5;
#pragma unroll
    for (int rr = 0; rr < 4; ++rr)
        tile[r + rr * 8][c] = Wm[(size_t)(k0 + r + rr * 8) * 1024 + n0 + c];
    __syncthreads();
#pragma unroll
    for (int rr = 0; rr < 4; ++rr) {
        int nn = r + rr * 8, kk = c;
        float v = tile[kk][nn];
        unsigned short hb = f2bf(v);
        hiT[(size_t)(n0 + nn) * 512 + k0 + kk] = hb;
        loT[(size_t)(n0 + nn) * 512 + k0 + kk] = f2bf(v - bf2f(hb));
    }
}

// ======================= Wm via split-bf16 MFMA + BN + lrelu + pooling =======================
__global__ __launch_bounds__(256) void wm_mfma_pool(const unsigned short* __restrict__ AH,
                                                    const unsigned short* __restrict__ AL,
                                                    const unsigned short* __restrict__ BH,
                                                    const unsigned short* __restrict__ BL,
                                                    const float* __restrict__ g,
                                                    const float* __restrict__ be,
                                                    const float* __restrict__ mu,
                                                    const float* __restrict__ var,
                                                    float* __restrict__ partmax,
                                                    float* __restrict__ partsum)
{
    __shared__ unsigned short AsH[128][40], AsL[128][40], BsH[128][40], BsL[128][40];
    __shared__ float redm[4][64], reds[4][64];
    const int t = threadIdx.x;
    const int i0 = blockIdx.x * 128, j0 = blockIdx.y * 128;
    const int lane = t & 63, wid = t >> 6, wy = wid >> 1, wx = wid & 1;
    const int lc = lane & 15, kg = lane >> 4;

    f32x4 acc[4][4];
#pragma unroll
    for (int mi = 0; mi < 4; ++mi)
#pragma unroll
        for (int ni = 0; ni < 4; ++ni) acc[mi][ni] = (f32x4){0.f, 0.f, 0.f, 0.f};

    for (int k0 = 0; k0 < 512; k0 += 32) {
        __syncthreads();
#pragma unroll
        for (int q = 0; q < 2; ++q) {
            int c = t + q * 256;
            int row = c >> 2, ko = (c & 3) * 8;
            *reinterpret_cast<uint4*>(&AsH[row][ko]) =
                *reinterpret_cast<const uint4*>(&AH[(size_t)(i0 + row) * 512 + k0 + ko]);
            *reinterpret_cast<uint4*>(&AsL[row][ko]) =
                *reinterpret_cast<const uint4*>(&AL[(size_t)(i0 + row) * 512 + k0 + ko]);
            *reinterpret_cast<uint4*>(&BsH[row][ko]) =
                *reinterpret_cast<const uint4*>(&BH[(size_t)(j0 + row) * 512 + k0 + ko]);
            *reinterpret_cast<uint4*>(&BsL[row][ko]) =
                *reinterpret_cast<const uint4*>(&BL[(size_t)(j0 + row) * 512 + k0 + ko]);
        }
        __syncthreads();

        bf16x8 aH[4], aL[4], bH[4], bL[4];
#pragma unroll
        for (int mi = 0; mi < 4; ++mi) {
            int ar = wy * 64 + mi * 16 + lc;
            aH[mi] = *reinterpret_cast<const bf16x8*>(&AsH[ar][kg * 8]);
            aL[mi] = *reinterpret_cast<const bf16x8*>(&AsL[ar][kg * 8]);
        }
#pragma unroll
        for (int ni = 0; ni < 4; ++ni) {
            int br = wx * 64 + ni * 16 + lc;
            bH[ni] = *reinterpret_cast<const bf16x8*>(&BsH[br][kg * 8]);
            bL[ni] = *reinterpret_cast<const bf16x8*>(&BsL[br][kg * 8]);
        }
#pragma unroll
        for (int mi = 0; mi < 4; ++mi)
#pragma unroll
            for (int ni = 0; ni < 4; ++ni) {
                acc[mi][ni] = __builtin_amdgcn_mfma_f32_16x16x32_bf16(aH[mi], bH[ni], acc[mi][ni], 0, 0, 0);
                acc[mi][ni] = __builtin_amdgcn_mfma_f32_16x16x32_bf16(aH[mi], bL[ni], acc[mi][ni], 0, 0, 0);
                acc[mi][ni] = __builtin_amdgcn_mfma_f32_16x16x32_bf16(aL[mi], bH[ni], acc[mi][ni], 0, 0, 0);
            }
    }

    float pmax[4], psum[4];
#pragma unroll
    for (int ni = 0; ni < 4; ++ni) {
        int j = j0 + wx * 64 + ni * 16 + lc;
        float s = g[j] * rsqrtf(var[j] + 1e-5f);
        float sh = be[j] - mu[j] * s;
        float pm = -BIGF, ps = 0.f;
#pragma unroll
        for (int mi = 0; mi < 4; ++mi)
#pragma unroll
            for (int r = 0; r < 4; ++r) {
                float y = fmaf(acc[mi][ni][r], s, sh);
                y = (y >= 0.f) ? y : 0.2f * y;
                pm = fmaxf(pm, y);
                ps += y;
            }
        pmax[ni] = pm; psum[ni] = ps;
    }
#pragma unroll
    for (int ni = 0; ni < 4; ++ni) {
        pmax[ni] = fmaxf(pmax[ni], __shfl_xor(pmax[ni], 16, 64));
        pmax[ni] = fmaxf(pmax[ni], __shfl_xor(pmax[ni], 32, 64));
        psum[ni] += __shfl_xor(psum[ni], 16, 64);
        psum[ni] += __shfl_xor(psum[ni], 32, 64);
    }
    if (lane < 16) {
#pragma unroll
        for (int ni = 0; ni < 4; ++ni) {
            redm[wid][ni * 16 + lc] = pmax[ni];
            reds[wid][ni * 16 + lc] = psum[ni];
        }
    }
    __syncthreads();
    if (t < 128) {
        int wxq = t >> 6, cl = t & 63;
        float m = fmaxf(redm[wxq][cl], redm[2 + wxq][cl]);
        float sv = reds[wxq][cl] + reds[2 + wxq][cl];
        int b = i0 >> 11, rb = (i0 & 2047) >> 7;
        partmax[((size_t)b * 16 + rb) * 1024 + j0 + t] = m;
        partsum[((size_t)b * 16 + rb) * 1024 + j0 + t] = sv;
    }
}

// ======================= pooling reduce =======================
__global__ __launch_bounds__(256) void pool2_kernel(const float* __restrict__ partmax,
                                                    const float* __restrict__ partsum,
                                                    float* __restrict__ pooled)
{
    const int c = blockIdx.x * 256 + threadIdx.x;
    const int b = blockIdx.y;
    float m = -BIGF, s = 0.f;
    for (int rb = 0; rb < 16; ++rb) {
        m = fmaxf(m, partmax[((size_t)b * 16 + rb) * 1024 + c]);
        s += partsum[((size_t)b * 16 + rb) * 1024 + c];
    }
    pooled[(size_t)b * 2048 + c] = m;
    pooled[(size_t)b * 2048 + 1024 + c] = s * (1.f / 2048.f);
}

// ======================= tail FCs (split-K) =======================
__global__ __launch_bounds__(512) void fc1_partial(const float* __restrict__ pooled,
                                                   const float* __restrict__ Wa,
                                                   float* __restrict__ part)
{
    const int kk = blockIdx.x, b = blockIdx.y, c = threadIdx.x;
    __shared__ float sp[128];
    if (c < 128) sp[c] = pooled[(size_t)b * 2048 + kk * 128 + c];
    __syncthreads();
    const float* w = Wa + (size_t)kk * 128 * 512 + c;
    float acc = 0.f;
#pragma unroll 8
    for (int j = 0; j < 128; ++j) acc = fmaf(sp[j], w[(size_t)j * 512], acc);
    part[((size_t)b * 16 + kk) * 512 + c] = acc;
}

__global__ __launch_bounds__(512) void fc1_reduce(const float* __restrict__ part,
                                                  const float* __restrict__ g, const float* __restrict__ be,
                                                  const float* __restrict__ mu, const float* __restrict__ var,
                                                  float* __restrict__ t1)
{
    const int b = blockIdx.x, c = threadIdx.x;
    float acc = 0.f;
#pragma unroll
    for (int kk = 0; kk < 16; ++kk) acc += part[((size_t)b * 16 + kk) * 512 + c];
    float s = g[c] * rsqrtf(var[c] + 1e-5f);
    float y = acc * s + (be[c] - mu[c] * s);
    t1[(size_t)b * 512 + c] = (y >= 0.f) ? y : 0.2f * y;
}

__global__ __launch_bounds__(256) void fc2_partial(const float* __restrict__ t1,
                                                   const float* __restrict__ Wb,
                                                   float* __restrict__ part)
{
    const int kk = blockIdx.x, b = blockIdx.y, c = threadIdx.x;
    __shared__ float sp[128];
    if (c < 128) sp[c] = t1[(size_t)b * 512 + kk * 128 + c];
    __syncthreads();
    const float* w = Wb + (size_t)kk * 128 * 256 + c;
    float acc = 0.f;
#pragma unroll 8
    for (int j = 0; j < 128; ++j) acc = fmaf(sp[j], w[(size_t)j * 256], acc);
    part[((size_t)b * 4 + kk) * 256 + c] = acc;
}

__global__ __launch_bounds__(256) void fc2_reduce(const float* __restrict__ part,
                                                  const float* __restrict__ bias_b,
                                                  const float* __restrict__ g, const float* __restrict__ be,
                                                  const float* __restrict__ mu, const float* __restrict__ var,
                                                  float* __restrict__ t2)
{
    const int b = blockIdx.x, c = threadIdx.x;
    float acc = bias_b[c];
#pragma unroll
    for (int kk = 0; kk < 4; ++kk) acc += part[((size_t)b * 4 + kk) * 256 + c];
    float s = g[c] * rsqrtf(var[c] + 1e-5f);
    float y = acc * s + (be[c] - mu[c] * s);
    t2[(size_t)b * 256 + c] = (y >= 0.f) ? y : 0.2f * y;
}

__global__ __launch_bounds__(64) void fc3_kernel(const float* __restrict__ t2,
                                                 const float* __restrict__ Wc,
                                                 const float* __restrict__ bias_c,
                                                 float* __restrict__ out)
{
    const int b = blockIdx.x, c = threadIdx.x;
    __shared__ float sp[256];
    for (int k = c; k < 256; k += 64) sp[k] = t2[(size_t)b * 256 + k];
    __syncthreads();
    if (c < 40) {
        float acc = 0.f;
#pragma unroll 8
        for (int k = 0; k < 256; ++k) acc = fmaf(sp[k], Wc[(size_t)k * 40 + c], acc);
        out[(size_t)b * 40 + c] = acc + bias_c[c];
    }
}

// ======================= launch =======================
extern "C" void kernel_launch(void* const* d_in, const int* in_sizes, int n_in,
                              void* d_out, int out_size, void* d_ws, size_t ws_size,
                              hipStream_t stream)
{
    const float* pos = (const float*)d_in[0];
    const float* W1 = (const float*)d_in[1];
    const float* g1 = (const float*)d_in[2];  const float* be1 = (const float*)d_in[3];
    const float* mu1 = (const float*)d_in[4]; const float* va1 = (const float*)d_in[5];
    const float* W2 = (const float*)d_in[6];
    const float* g2 = (const float*)d_in[7];  const float* be2 = (const float*)d_in[8];
    const float* mu2 = (const float*)d_in[9]; const float* va2 = (const float*)d_in[10];
    const float* W3 = (const float*)d_in[11];
    const float* g3 = (const float*)d_in[12]; const float* be3 = (const float*)d_in[13];
    const float* mu3 = (const float*)d_in[14];const float* va3 = (const float*)d_in[15];
    const float* W4 = (const float*)d_in[16];
    const float* g4 = (const float*)d_in[17]; const float* be4 = (const float*)d_in[18];
    const float* mu4 = (const float*)d_in[19];const float* va4 = (const float*)d_in[20];
    const float* Wm = (const float*)d_in[21];
    const float* gm = (const float*)d_in[22]; const float* bem = (const float*)d_in[23];
    const float* mum = (const float*)d_in[24];const float* vam = (const float*)d_in[25];
    const float* Wa = (const float*)d_in[26];
    const float* ga = (const float*)d_in[27]; const float* bea = (const float*)d_in[28];
    const float* mua = (const float*)d_in[29];const float* vaa = (const float*)d_in[30];
    const float* Wb = (const float*)d_in[31];
    const float* gb = (const float*)d_in[32]; const float* beb = (const float*)d_in[33];
    const float* mub = (const float*)d_in[34];const float* vab = (const float*)d_in[35];
    const float* bias_b = (const float*)d_in[36];
    const float* Wc = (const float*)d_in[37];
    const float* bias_c = (const float*)d_in[38];

    char* ws = (char*)d_ws;
    size_t off = 0;
    auto alloc = [&](size_t bytes) -> void* {
        void* p = ws + off;
        off += (bytes + 255) & ~(size_t)255;
        return p;
    };
    float* xcat    = (float*)alloc((size_t)16384 * 512 * 4);
    float* sq      = (float*)alloc((size_t)16384 * 4);
    int*   idx     = (int*)  alloc((size_t)16384 * KNN * 4);
    float* apart   = (float*)alloc((size_t)16384 * 256 * 4);
    float* bpart   = (float*)alloc((size_t)16384 * 256 * 4);
    float* partmax = (float*)alloc((size_t)8 * 16 * 1024 * 4);
    float* partsum = (float*)alloc((size_t)8 * 16 * 1024 * 4);
    float* pooled  = (float*)alloc((size_t)8 * 2048 * 4);
    float* t1      = (float*)alloc((size_t)8 * 512 * 4);
    float* t2      = (float*)alloc((size_t)8 * 256 * 4);
    float* part1   = (float*)alloc((size_t)8 * 16 * 512 * 4);
    float* part2   = (float*)alloc((size_t)8 * 4 * 256 * 4);
    unsigned short* ah   = (unsigned short*)alloc((size_t)16384 * 512 * 2);
    unsigned short* al   = (unsigned short*)alloc((size_t)16384 * 512 * 2);
    unsigned short* wmtH = (unsigned short*)alloc((size_t)1024 * 512 * 2);
    unsigned short* wmtL = (unsigned short*)alloc((size_t)1024 * 512 * 2);

    struct LayerDesc {
        const float* xin; int lda; int F; int Fout;
        float* xout; const float* W;
        const float* g; const float* be; const float* mu; const float* va;
    };
    LayerDesc Ls[4] = {
        { pos,        3,   3,   64,  xcat + 0,   W1, g1, be1, mu1, va1 },
        { xcat + 0,   512, 64,  64,  xcat + 64,  W2, g2, be2, mu2, va2 },
        { xcat + 64,  512, 64,  128, xcat + 128, W3, g3, be3, mu3, va3 },
        { xcat + 128, 512, 128, 256, xcat + 256, W4, g4, be4, mu4, va4 },
    };

    for (int L = 0; L < 4; ++L) {
        const LayerDesc& ld = Ls[L];
        sq_kernel<<<64, 256, 0, stream>>>(ld.xin, ld.lda, ld.F, sq);
        if (ld.F == 3)
            distsel_kernel<3><<<dim3(32, 8), 512, 0, stream>>>(ld.xin, ld.lda, sq, idx);
        else if (ld.F == 64)
            distsel_kernel<64><<<dim3(32, 8), 512, 0, stream>>>(ld.xin, ld.lda, sq, idx);
        else
            distsel_kernel<128><<<dim3(32, 8), 512, 0, stream>>>(ld.xin, ld.lda, sq, idx);
        gemm64_kernel<<<dim3(256, ld.Fout / 64), 256, 0, stream>>>(
            ld.xin, ld.lda, ld.F, ld.W, ld.Fout, apart, ld.Fout);
        gemm64_kernel<<<dim3(256, ld.Fout / 64), 256, 0, stream>>>(
            ld.xin, ld.lda, ld.F, ld.W + (size_t)ld.F * ld.Fout, ld.Fout, bpart, ld.Fout);
        if (ld.Fout == 64)
            aggregate_kernel<64><<<1024, 256, 0, stream>>>(apart, bpart, idx,
                ld.g, ld.be, ld.mu, ld.va, ld.xout);
        else if (ld.Fout == 128)
            aggregate_kernel<128><<<2048, 256, 0, stream>>>(apart, bpart, idx,
                ld.g, ld.be, ld.mu, ld.va, ld.xout);
        else
            aggregate_kernel<256><<<4096, 256, 0, stream>>>(apart, bpart, idx,
                ld.g, ld.be, ld.mu, ld.va, ld.xout);
    }

    cvt_kernel<<<4096, 256, 0, stream>>>(xcat, ah, al);
    cvtT_kernel<<<dim3(32, 16), 256, 0, stream>>>(Wm, wmtH, wmtL);
    wm_mfma_pool<<<dim3(128, 8), 256, 0, stream>>>(ah, al, wmtH, wmtL,
                                                   gm, bem, mum, vam, partmax, partsum);
    pool2_kernel<<<dim3(4, 8), 256, 0, stream>>>(partmax, partsum, pooled);
    fc1_partial<<<dim3(16, 8), 512, 0, stream>>>(pooled, Wa, part1);
    fc1_reduce<<<8, 512, 0, stream>>>(part1, ga, bea, mua, vaa, t1);
    fc2_partial<<<dim3(4, 8), 256, 0, stream>>>(t1, Wb, part2);
    fc2_reduce<<<8, 256, 0, stream>>>(part2, bias_b, gb, beb, mub, vab, t2);
    fc3_kernel<<<8, 64, 0, stream>>>(t2, Wc, bias_c, (float*)d_out);
}

// Round 7
// 2228.413 us; speedup vs baseline: 1.8753x; 1.8753x over previous
//
#include <hip/hip_runtime.h>
#include <cstdint>
#include <cstddef>

#define NPTS 2048
#define BATCH 8
#define KNN 20
#define BIGF 3.402823466e38f

typedef short bf16x8 __attribute__((ext_vector_type(8)));
typedef float f32x4 __attribute__((ext_vector_type(4)));

__device__ __forceinline__ unsigned short f2bf(float v) {
    uint32_t u = __float_as_uint(v);
    uint32_t r = (u + 0x7FFFu + ((u >> 16) & 1u)) >> 16;
    return (unsigned short)r;
}
__device__ __forceinline__ float bf2f(unsigned short h) {
    return __uint_as_float(((uint32_t)h) << 16);
}
__device__ __forceinline__ uint32_t flipkey(float d) {
    uint32_t u = __float_as_uint(d);
    return (u & 0x80000000u) ? ~u : (u | 0x80000000u);
}
__device__ __forceinline__ uint64_t shfl_xor_u64w(uint64_t v, int m, int w) {
    int lo = __shfl_xor((int)(uint32_t)v, m, w);
    int hi = __shfl_xor((int)(uint32_t)(v >> 32), m, w);
    return ((uint64_t)(uint32_t)hi << 32) | (uint32_t)lo;
}
// branchless sorted insert into ascending 16-list (bubble-carry)
__device__ __forceinline__ void ins16(uint64_t (&tl)[16], uint64_t c) {
    if (c < tl[15]) {
        uint64_t carry = c;
#pragma unroll
        for (int k = 0; k < 16; ++k) {
            uint64_t tk = tl[k];
            bool lt = carry < tk;
            uint64_t mn = lt ? carry : tk;
            uint64_t mx = lt ? tk : carry;
            tl[k] = mn; carry = mx;
        }
    }
}

// ======================= sum of squares per point =======================
__global__ __launch_bounds__(256) void sq_kernel(const float* __restrict__ x, int lda, int F,
                                                 float* __restrict__ sq)
{
    int p = blockIdx.x * 256 + threadIdx.x;   // 0..16383
    const float* xp = x + (size_t)p * lda;
    float s = 0.f;
    for (int f = 0; f < F; ++f) { float v = xp[f]; s = fmaf(v, v, s); }
    sq[p] = s;
}

// ======================= FUSED dist + top-20 select (v2) =======================
// Block: 256 thr, 64 i-rows, 8 j-tiles of 256. GEMM = dist_kernel shape (acc[8][8],
// same fmaf order => bitwise-identical d2). Per tile: keys bounced via LDS d2t,
// then 4 threads/row stream into register-resident sorted top-16 (no barriers,
// no atomics). Final: 20-iter shfl-extract per row -> global idx.
template <int F>
__global__ __launch_bounds__(256) void distsel_kernel(const float* __restrict__ x, int lda,
                                                      const float* __restrict__ sq,
                                                      int* __restrict__ idx)
{
    constexpr int CF = ((F + 7) / 8) * 8;
    __shared__ float As[CF][68];                   // x_i panel, transposed: [f][row]
    __shared__ __align__(16) float Bs[8][260];     // x_j chunk: [f][col], 256 cols
    __shared__ __align__(16) uint32_t d2t[64][260];// key tile

    const int t  = threadIdx.x;
    const int tx = t & 31;          // 8 cols: tx*4+c (c<4), 128+tx*4+(c-4)
    const int ty = t >> 5;          // 8 rows: ty*8 + r
    const int b  = blockIdx.y;
    const int i0 = blockIdx.x * 64;
    const float* xb  = x + (size_t)b * NPTS * lda;
    const float* sqb = sq + (size_t)b * NPTS;

    // stage As transposed (coalesced global read by f)
    for (int e = t; e < 64 * CF; e += 256) {
        int row = e >> ((CF == 128) ? 7 : (CF == 64) ? 6 : 3);
        int f   = e & (CF - 1);
        float v = (F == CF || f < F) ? xb[(size_t)(i0 + row) * lda + f] : 0.f;
        As[f][row] = v;
    }
    float sreg[8];
#pragma unroll
    for (int r = 0; r < 8; ++r) sreg[r] = sqb[i0 + ty * 8 + r];
    __syncthreads();

    uint64_t tl[16];
#pragma unroll
    for (int q = 0; q < 16; ++q) tl[q] = ~0ull;
    const int srow = t >> 2;        // selector row 0..63
    const int slot = t & 3;

    for (int jt = 0; jt < 8; ++jt) {
        const int j0 = jt * 256;
        float acc[8][8];
#pragma unroll
        for (int r = 0; r < 8; ++r)
#pragma unroll
            for (int c = 0; c < 8; ++c) acc[r][c] = 0.f;

        for (int ch = 0; ch < CF / 8; ++ch) {
            const int k0 = ch * 8;
            // stage Bs: 256 cols x 8 f
#pragma unroll
            for (int q = 0; q < 8; ++q) {
                int e = t + q * 256;
                int col = e >> 3, f = e & 7;
                float v = 0.f;
                if (F % 8 == 0 || k0 + f < F)
                    v = xb[(size_t)(j0 + col) * lda + k0 + f];
                Bs[f][col] = v;
            }
            __syncthreads();
#pragma unroll
            for (int k = 0; k < 8; ++k) {
                float4 a0 = *reinterpret_cast<const float4*>(&As[k0 + k][ty * 8]);
                float4 a1 = *reinterpret_cast<const float4*>(&As[k0 + k][ty * 8 + 4]);
                float4 b0 = *reinterpret_cast<const float4*>(&Bs[k][tx * 4]);
                float4 b1 = *reinterpret_cast<const float4*>(&Bs[k][128 + tx * 4]);
                float av[8] = {a0.x, a0.y, a0.z, a0.w, a1.x, a1.y, a1.z, a1.w};
                float bv[8] = {b0.x, b0.y, b0.z, b0.w, b1.x, b1.y, b1.z, b1.w};
#pragma unroll
                for (int r = 0; r < 8; ++r)
#pragma unroll
                    for (int c = 0; c < 8; ++c) acc[r][c] = fmaf(av[r], bv[c], acc[r][c]);
            }
            __syncthreads();
        }

        // write key tile (same combine expression as dist_kernel)
#pragma unroll
        for (int r = 0; r < 8; ++r) {
            const int row = ty * 8 + r;
            const float si = sreg[r];
#pragma unroll
            for (int cg = 0; cg < 2; ++cg) {
                const int col = cg * 128 + tx * 4;
                float4 sj4 = *reinterpret_cast<const float4*>(&sqb[j0 + col]);
                uint4 kv;
                kv.x = flipkey(si + sj4.x - 2.f * acc[r][cg * 4 + 0]);
                kv.y = flipkey(si + sj4.y - 2.f * acc[r][cg * 4 + 1]);
                kv.z = flipkey(si + sj4.z - 2.f * acc[r][cg * 4 + 2]);
                kv.w = flipkey(si + sj4.w - 2.f * acc[r][cg * 4 + 3]);
                *reinterpret_cast<uint4*>(&d2t[row][col]) = kv;
            }
        }
        __syncthreads();

        // selector: 4 threads/row, 64 cols each (4-col blocks strided 16)
        const uint32_t hi15 = (uint32_t)(tl[15] >> 32);
#pragma unroll 1
        for (int kk = 0; kk < 16; ++kk) {
            const int colb = slot * 4 + kk * 16;
            uint4 kv = *reinterpret_cast<const uint4*>(&d2t[srow][colb]);
            uint32_t mn = min(min(kv.x, kv.y), min(kv.z, kv.w));
            if (mn <= (uint32_t)(tl[15] >> 32)) {
                const uint32_t jb = (uint32_t)(j0 + colb);
                ins16(tl, ((uint64_t)kv.x << 32) | (jb + 0));
                ins16(tl, ((uint64_t)kv.y << 32) | (jb + 1));
                ins16(tl, ((uint64_t)kv.z << 32) | (jb + 2));
                ins16(tl, ((uint64_t)kv.w << 32) | (jb + 3));
            }
        }
        (void)hi15;
        __syncthreads();   // before next tile's d2t overwrite (>=1 more sync in chunk loop anyway)
    }

    // merge: extract 20 smallest across the row's 4 sorted lists
    int* out = idx + ((size_t)b * NPTS + i0 + srow) * KNN;
    for (int it = 0; it < KNN; ++it) {
        uint64_t m = tl[0];
#pragma unroll
        for (int o = 1; o < 4; o <<= 1) {
            uint64_t ov = shfl_xor_u64w(m, o, 4);
            m = (ov < m) ? ov : m;
        }
        if (slot == (it & 3)) out[it] = (int)(uint32_t)m;
        bool win = (tl[0] == m);
#pragma unroll
        for (int k = 0; k < 15; ++k) tl[k] = win ? tl[k + 1] : tl[k];
        tl[15] = win ? ~0ull : tl[15];
    }
}

// ======================= generic small GEMM: C[M,Nc] = A[M,F] @ B[F,Nc] =======================
__global__ __launch_bounds__(256) void gemm64_kernel(const float* __restrict__ A, int lda, int F,
                                                     const float* __restrict__ Bw, int ldb,
                                                     float* __restrict__ C, int ldc)
{
    __shared__ float As[16][65];
    __shared__ float Bs[16][65];
    const int i0 = blockIdx.x * 64, j0 = blockIdx.y * 64;
    const int t = threadIdx.x, tx = t & 15, ty = t >> 4;
    float acc[4][4];
#pragma unroll
    for (int r = 0; r < 4; ++r)
#pragma unroll
        for (int c = 0; c < 4; ++c) acc[r][c] = 0.f;
    const int arow = t >> 2, akq = (t & 3) * 4;
    const int bk = t >> 4, bj = (t & 15) * 4;
    for (int k0 = 0; k0 < F; k0 += 16) {
#pragma unroll
        for (int q = 0; q < 4; ++q) {
            int kk = k0 + akq + q;
            As[akq + q][arow] = (kk < F) ? A[(size_t)(i0 + arow) * lda + kk] : 0.f;
        }
        {
            int kk = k0 + bk;
#pragma unroll
            for (int q = 0; q < 4; ++q)
                Bs[bk][bj + q] = (kk < F) ? Bw[(size_t)kk * ldb + j0 + bj + q] : 0.f;
        }
        __syncthreads();
#pragma unroll
        for (int k = 0; k < 16; ++k) {
            float a[4], bb[4];
#pragma unroll
            for (int r = 0; r < 4; ++r) a[r] = As[k][ty * 4 + r];
#pragma unroll
            for (int c = 0; c < 4; ++c) bb[c] = Bs[k][tx * 4 + c];
#pragma unroll
            for (int r = 0; r < 4; ++r)
#pragma unroll
                for (int c = 0; c < 4; ++c) acc[r][c] = fmaf(a[r], bb[c], acc[r][c]);
        }
        __syncthreads();
    }
#pragma unroll
    for (int r = 0; r < 4; ++r)
#pragma unroll
        for (int c = 0; c < 4; ++c)
            C[(size_t)(i0 + ty * 4 + r) * ldc + j0 + tx * 4 + c] = acc[r][c];
}

// ======================= EdgeConv aggregate (float4 lanes, multi-point blocks) =======================
template <int FOUT>
__global__ __launch_bounds__(256) void aggregate_kernel(const float* __restrict__ apart,
                                                        const float* __restrict__ bpart,
                                                        const int* __restrict__ idx,
                                                        const float* __restrict__ g,
                                                        const float* __restrict__ be,
                                                        const float* __restrict__ mu,
                                                        const float* __restrict__ var,
                                                        float* __restrict__ out)
{
    constexpr int G   = FOUT / 4;
    constexpr int PPB = 256 / G;
    const int t  = threadIdx.x;
    const int pi = t / G;
    const int fi = t % G;
    const int p  = blockIdx.x * PPB + pi;
    const int b  = p >> 11;
    const int* nb = idx + (size_t)p * KNN;
    const float4* bp4 = reinterpret_cast<const float4*>(bpart);
    const float4* bb  = bp4 + ((size_t)b << 11) * G;

    float4 m = {-BIGF, -BIGF, -BIGF, -BIGF};
#pragma unroll 4
    for (int k = 0; k < KNN; ++k) {
        int j = nb[k];
        float4 v = bb[(size_t)j * G + fi];
        m.x = fmaxf(m.x, v.x); m.y = fmaxf(m.y, v.y);
        m.z = fmaxf(m.z, v.z); m.w = fmaxf(m.w, v.w);
    }
    float4 av = reinterpret_cast<const float4*>(apart)[(size_t)p * G + fi];
    float4 bv = bp4[(size_t)p * G + fi];
    float4 gg = reinterpret_cast<const float4*>(g)[fi];
    float4 bee = reinterpret_cast<const float4*>(be)[fi];
    float4 muu = reinterpret_cast<const float4*>(mu)[fi];
    float4 vaa = reinterpret_cast<const float4*>(var)[fi];

    float4 r;
    {
        float s, sh, vv, y;
        s = gg.x * rsqrtf(vaa.x + 1e-5f); sh = bee.x - muu.x * s;
        vv = av.x - bv.x + m.x; y = vv * s + sh; r.x = (y >= 0.f) ? y : 0.2f * y;
        s = gg.y * rsqrtf(vaa.y + 1e-5f); sh = bee.y - muu.y * s;
        vv = av.y - bv.y + m.y; y = vv * s + sh; r.y = (y >= 0.f) ? y : 0.2f * y;
        s = gg.z * rsqrtf(vaa.z + 1e-5f); sh = bee.z - muu.z * s;
        vv = av.z - bv.z + m.z; y = vv * s + sh; r.z = (y >= 0.f) ? y : 0.2f * y;
        s = gg.w * rsqrtf(vaa.w + 1e-5f); sh = bee.w - muu.w * s;
        vv = av.w - bv.w + m.w; y = vv * s + sh; r.w = (y >= 0.f) ? y : 0.2f * y;
    }
    *reinterpret_cast<float4*>(out + (size_t)p * 512 + fi * 4) = r;
}

// ======================= split-bf16 converters =======================
__global__ __launch_bounds__(256) void cvt_kernel(const float* __restrict__ in,
                                                  unsigned short* __restrict__ hi,
                                                  unsigned short* __restrict__ lo)
{
    int i = blockIdx.x * 256 + threadIdx.x;
    const float4* p = reinterpret_cast<const float4*>(in) + (size_t)i * 2;
    float4 a = p[0], b = p[1];
    float v[8] = {a.x, a.y, a.z, a.w, b.x, b.y, b.z, b.w};
    uint32_t h[8], l[8];
#pragma unroll
    for (int q = 0; q < 8; ++q) {
        unsigned short hb = f2bf(v[q]);
        h[q] = hb;
        l[q] = f2bf(v[q] - bf2f(hb));
    }
    uint4 uh, ul;
    uh.x = h[0] | (h[1] << 16); uh.y = h[2] | (h[3] << 16);
    uh.z = h[4] | (h[5] << 16); uh.w = h[6] | (h[7] << 16);
    ul.x = l[0] | (l[1] << 16); ul.y = l[2] | (l[3] << 16);
    ul.z = l[4] | (l[5] << 16); ul.w = l[6] | (l[7] << 16);
    reinterpret_cast<uint4*>(hi)[i] = uh;
    reinterpret_cast<uint4*>(lo)[i] = ul;
}

__global__ __launch_bounds__(256) void cvtT_kernel(const float* __restrict__ Wm,
                                                   unsigned short* __restrict__ hiT,
                                                   unsigned short* __restrict__ loT)
{
    __shared__ float tile[32][33];
    const int n0 = blockIdx.x * 32;
    const int k0 = blockIdx.y * 32;
    const int t = threadIdx.x;
    const int c = t & 31, r = t >> 5;
#pragma unroll
    for (int rr = 0; rr < 4; ++rr)
        tile[r + rr * 8][c] = Wm[(size_t)(k0 + r + rr * 8) * 1024 + n0 + c];
    __syncthreads();
#pragma unroll
    for (int rr = 0; rr < 4; ++rr) {
        int nn = r + rr * 8, kk = c;
        float v = tile[kk][nn];
        unsigned short hb = f2bf(v);
        hiT[(size_t)(n0 + nn) * 512 + k0 + kk] = hb;
        loT[(size_t)(n0 + nn) * 512 + k0 + kk] = f2bf(v - bf2f(hb));
    }
}

// ======================= Wm via split-bf16 MFMA + BN + lrelu + pooling =======================
__global__ __launch_bounds__(256) void wm_mfma_pool(const unsigned short* __restrict__ AH,
                                                    const unsigned short* __restrict__ AL,
                                                    const unsigned short* __restrict__ BH,
                                                    const unsigned short* __restrict__ BL,
                                                    const float* __restrict__ g,
                                                    const float* __restrict__ be,
                                                    const float* __restrict__ mu,
                                                    const float* __restrict__ var,
                                                    float* __restrict__ partmax,
                                                    float* __restrict__ partsum)
{
    __shared__ unsigned short AsH[128][40], AsL[128][40], BsH[128][40], BsL[128][40];
    __shared__ float redm[4][64], reds[4][64];
    const int t = threadIdx.x;
    const int i0 = blockIdx.x * 128, j0 = blockIdx.y * 128;
    const int lane = t & 63, wid = t >> 6, wy = wid >> 1, wx = wid & 1;
    const int lc = lane & 15, kg = lane >> 4;

    f32x4 acc[4][4];
#pragma unroll
    for (int mi = 0; mi < 4; ++mi)
#pragma unroll
        for (int ni = 0; ni < 4; ++ni) acc[mi][ni] = (f32x4){0.f, 0.f, 0.f, 0.f};

    for (int k0 = 0; k0 < 512; k0 += 32) {
        __syncthreads();
#pragma unroll
        for (int q = 0; q < 2; ++q) {
            int c = t + q * 256;
            int row = c >> 2, ko = (c & 3) * 8;
            *reinterpret_cast<uint4*>(&AsH[row][ko]) =
                *reinterpret_cast<const uint4*>(&AH[(size_t)(i0 + row) * 512 + k0 + ko]);
            *reinterpret_cast<uint4*>(&AsL[row][ko]) =
                *reinterpret_cast<const uint4*>(&AL[(size_t)(i0 + row) * 512 + k0 + ko]);
            *reinterpret_cast<uint4*>(&BsH[row][ko]) =
                *reinterpret_cast<const uint4*>(&BH[(size_t)(j0 + row) * 512 + k0 + ko]);
            *reinterpret_cast<uint4*>(&BsL[row][ko]) =
                *reinterpret_cast<const uint4*>(&BL[(size_t)(j0 + row) * 512 + k0 + ko]);
        }
        __syncthreads();

        bf16x8 aH[4], aL[4], bH[4], bL[4];
#pragma unroll
        for (int mi = 0; mi < 4; ++mi) {
            int ar = wy * 64 + mi * 16 + lc;
            aH[mi] = *reinterpret_cast<const bf16x8*>(&AsH[ar][kg * 8]);
            aL[mi] = *reinterpret_cast<const bf16x8*>(&AsL[ar][kg * 8]);
        }
#pragma unroll
        for (int ni = 0; ni < 4; ++ni) {
            int br = wx * 64 + ni * 16 + lc;
            bH[ni] = *reinterpret_cast<const bf16x8*>(&BsH[br][kg * 8]);
            bL[ni] = *reinterpret_cast<const bf16x8*>(&BsL[br][kg * 8]);
        }
#pragma unroll
        for (int mi = 0; mi < 4; ++mi)
#pragma unroll
            for (int ni = 0; ni < 4; ++ni) {
                acc[mi][ni] = __builtin_amdgcn_mfma_f32_16x16x32_bf16(aH[mi], bH[ni], acc[mi][ni], 0, 0, 0);
                acc[mi][ni] = __builtin_amdgcn_mfma_f32_16x16x32_bf16(aH[mi], bL[ni], acc[mi][ni], 0, 0, 0);
                acc[mi][ni] = __builtin_amdgcn_mfma_f32_16x16x32_bf16(aL[mi], bH[ni], acc[mi][ni], 0, 0, 0);
            }
    }

    float pmax[4], psum[4];
#pragma unroll
    for (int ni = 0; ni < 4; ++ni) {
        int j = j0 + wx * 64 + ni * 16 + lc;
        float s = g[j] * rsqrtf(var[j] + 1e-5f);
        float sh = be[j] - mu[j] * s;
        float pm = -BIGF, ps = 0.f;
#pragma unroll
        for (int mi = 0; mi < 4; ++mi)
#pragma unroll
            for (int r = 0; r < 4; ++r) {
                float y = fmaf(acc[mi][ni][r], s, sh);
                y = (y >= 0.f) ? y : 0.2f * y;
                pm = fmaxf(pm, y);
                ps += y;
            }
        pmax[ni] = pm; psum[ni] = ps;
    }
#pragma unroll
    for (int ni = 0; ni < 4; ++ni) {
        pmax[ni] = fmaxf(pmax[ni], __shfl_xor(pmax[ni], 16, 64));
        pmax[ni] = fmaxf(pmax[ni], __shfl_xor(pmax[ni], 32, 64));
        psum[ni] += __shfl_xor(psum[ni], 16, 64);
        psum[ni] += __shfl_xor(psum[ni], 32, 64);
    }
    if (lane < 16) {
#pragma unroll
        for (int ni = 0; ni < 4; ++ni) {
            redm[wid][ni * 16 + lc] = pmax[ni];
            reds[wid][ni * 16 + lc] = psum[ni];
        }
    }
    __syncthreads();
    if (t < 128) {
        int wxq = t >> 6, cl = t & 63;
        float m = fmaxf(redm[wxq][cl], redm[2 + wxq][cl]);
        float sv = reds[wxq][cl] + reds[2 + wxq][cl];
        int b = i0 >> 11, rb = (i0 & 2047) >> 7;
        partmax[((size_t)b * 16 + rb) * 1024 + j0 + t] = m;
        partsum[((size_t)b * 16 + rb) * 1024 + j0 + t] = sv;
    }
}

// ======================= pooling reduce =======================
__global__ __launch_bounds__(256) void pool2_kernel(const float* __restrict__ partmax,
                                                    const float* __restrict__ partsum,
                                                    float* __restrict__ pooled)
{
    const int c = blockIdx.x * 256 + threadIdx.x;
    const int b = blockIdx.y;
    float m = -BIGF, s = 0.f;
    for (int rb = 0; rb < 16; ++rb) {
        m = fmaxf(m, partmax[((size_t)b * 16 + rb) * 1024 + c]);
        s += partsum[((size_t)b * 16 + rb) * 1024 + c];
    }
    pooled[(size_t)b * 2048 + c] = m;
    pooled[(size_t)b * 2048 + 1024 + c] = s * (1.f / 2048.f);
}

// ======================= tail FCs (split-K) =======================
__global__ __launch_bounds__(512) void fc1_partial(const float* __restrict__ pooled,
                                                   const float* __restrict__ Wa,
                                                   float* __restrict__ part)
{
    const int kk = blockIdx.x, b = blockIdx.y, c = threadIdx.x;
    __shared__ float sp[128];
    if (c < 128) sp[c] = pooled[(size_t)b * 2048 + kk * 128 + c];
    __syncthreads();
    const float* w = Wa + (size_t)kk * 128 * 512 + c;
    float acc = 0.f;
#pragma unroll 8
    for (int j = 0; j < 128; ++j) acc = fmaf(sp[j], w[(size_t)j * 512], acc);
    part[((size_t)b * 16 + kk) * 512 + c] = acc;
}

__global__ __launch_bounds__(512) void fc1_reduce(const float* __restrict__ part,
                                                  const float* __restrict__ g, const float* __restrict__ be,
                                                  const float* __restrict__ mu, const float* __restrict__ var,
                                                  float* __restrict__ t1)
{
    const int b = blockIdx.x, c = threadIdx.x;
    float acc = 0.f;
#pragma unroll
    for (int kk = 0; kk < 16; ++kk) acc += part[((size_t)b * 16 + kk) * 512 + c];
    float s = g[c] * rsqrtf(var[c] + 1e-5f);
    float y = acc * s + (be[c] - mu[c] * s);
    t1[(size_t)b * 512 + c] = (y >= 0.f) ? y : 0.2f * y;
}

__global__ __launch_bounds__(256) void fc2_partial(const float* __restrict__ t1,
                                                   const float* __restrict__ Wb,
                                                   float* __restrict__ part)
{
    const int kk = blockIdx.x, b = blockIdx.y, c = threadIdx.x;
    __shared__ float sp[128];
    if (c < 128) sp[c] = t1[(size_t)b * 512 + kk * 128 + c];
    __syncthreads();
    const float* w = Wb + (size_t)kk * 128 * 256 + c;
    float acc = 0.f;
#pragma unroll 8
    for (int j = 0; j < 128; ++j) acc = fmaf(sp[j], w[(size_t)j * 256], acc);
    part[((size_t)b * 4 + kk) * 256 + c] = acc;
}

__global__ __launch_bounds__(256) void fc2_reduce(const float* __restrict__ part,
                                                  const float* __restrict__ bias_b,
                                                  const float* __restrict__ g, const float* __restrict__ be,
                                                  const float* __restrict__ mu, const float* __restrict__ var,
                                                  float* __restrict__ t2)
{
    const int b = blockIdx.x, c = threadIdx.x;
    float acc = bias_b[c];
#pragma unroll
    for (int kk = 0; kk < 4; ++kk) acc += part[((size_t)b * 4 + kk) * 256 + c];
    float s = g[c] * rsqrtf(var[c] + 1e-5f);
    float y = acc * s + (be[c] - mu[c] * s);
    t2[(size_t)b * 256 + c] = (y >= 0.f) ? y : 0.2f * y;
}

__global__ __launch_bounds__(64) void fc3_kernel(const float* __restrict__ t2,
                                                 const float* __restrict__ Wc,
                                                 const float* __restrict__ bias_c,
                                                 float* __restrict__ out)
{
    const int b = blockIdx.x, c = threadIdx.x;
    __shared__ float sp[256];
    for (int k = c; k < 256; k += 64) sp[k] = t2[(size_t)b * 256 + k];
    __syncthreads();
    if (c < 40) {
        float acc = 0.f;
#pragma unroll 8
        for (int k = 0; k < 256; ++k) acc = fmaf(sp[k], Wc[(size_t)k * 40 + c], acc);
        out[(size_t)b * 40 + c] = acc + bias_c[c];
    }
}

// ======================= launch =======================
extern "C" void kernel_launch(void* const* d_in, const int* in_sizes, int n_in,
                              void* d_out, int out_size, void* d_ws, size_t ws_size,
                              hipStream_t stream)
{
    const float* pos = (const float*)d_in[0];
    const float* W1 = (const float*)d_in[1];
    const float* g1 = (const float*)d_in[2];  const float* be1 = (const float*)d_in[3];
    const float* mu1 = (const float*)d_in[4]; const float* va1 = (const float*)d_in[5];
    const float* W2 = (const float*)d_in[6];
    const float* g2 = (const float*)d_in[7];  const float* be2 = (const float*)d_in[8];
    const float* mu2 = (const float*)d_in[9]; const float* va2 = (const float*)d_in[10];
    const float* W3 = (const float*)d_in[11];
    const float* g3 = (const float*)d_in[12]; const float* be3 = (const float*)d_in[13];
    const float* mu3 = (const float*)d_in[14];const float* va3 = (const float*)d_in[15];
    const float* W4 = (const float*)d_in[16];
    const float* g4 = (const float*)d_in[17]; const float* be4 = (const float*)d_in[18];
    const float* mu4 = (const float*)d_in[19];const float* va4 = (const float*)d_in[20];
    const float* Wm = (const float*)d_in[21];
    const float* gm = (const float*)d_in[22]; const float* bem = (const float*)d_in[23];
    const float* mum = (const float*)d_in[24];const float* vam = (const float*)d_in[25];
    const float* Wa = (const float*)d_in[26];
    const float* ga = (const float*)d_in[27]; const float* bea = (const float*)d_in[28];
    const float* mua = (const float*)d_in[29];const float* vaa = (const float*)d_in[30];
    const float* Wb = (const float*)d_in[31];
    const float* gb = (const float*)d_in[32]; const float* beb = (const float*)d_in[33];
    const float* mub = (const float*)d_in[34];const float* vab = (const float*)d_in[35];
    const float* bias_b = (const float*)d_in[36];
    const float* Wc = (const float*)d_in[37];
    const float* bias_c = (const float*)d_in[38];

    char* ws = (char*)d_ws;
    size_t off = 0;
    auto alloc = [&](size_t bytes) -> void* {
        void* p = ws + off;
        off += (bytes + 255) & ~(size_t)255;
        return p;
    };
    float* xcat    = (float*)alloc((size_t)16384 * 512 * 4);
    float* sq      = (float*)alloc((size_t)16384 * 4);
    int*   idx     = (int*)  alloc((size_t)16384 * KNN * 4);
    float* apart   = (float*)alloc((size_t)16384 * 256 * 4);
    float* bpart   = (float*)alloc((size_t)16384 * 256 * 4);
    float* partmax = (float*)alloc((size_t)8 * 16 * 1024 * 4);
    float* partsum = (float*)alloc((size_t)8 * 16 * 1024 * 4);
    float* pooled  = (float*)alloc((size_t)8 * 2048 * 4);
    float* t1      = (float*)alloc((size_t)8 * 512 * 4);
    float* t2      = (float*)alloc((size_t)8 * 256 * 4);
    float* part1   = (float*)alloc((size_t)8 * 16 * 512 * 4);
    float* part2   = (float*)alloc((size_t)8 * 4 * 256 * 4);
    unsigned short* ah   = (unsigned short*)alloc((size_t)16384 * 512 * 2);
    unsigned short* al   = (unsigned short*)alloc((size_t)16384 * 512 * 2);
    unsigned short* wmtH = (unsigned short*)alloc((size_t)1024 * 512 * 2);
    unsigned short* wmtL = (unsigned short*)alloc((size_t)1024 * 512 * 2);

    struct LayerDesc {
        const float* xin; int lda; int F; int Fout;
        float* xout; const float* W;
        const float* g; const float* be; const float* mu; const float* va;
    };
    LayerDesc Ls[4] = {
        { pos,        3,   3,   64,  xcat + 0,   W1, g1, be1, mu1, va1 },
        { xcat + 0,   512, 64,  64,  xcat + 64,  W2, g2, be2, mu2, va2 },
        { xcat + 64,  512, 64,  128, xcat + 128, W3, g3, be3, mu3, va3 },
        { xcat + 128, 512, 128, 256, xcat + 256, W4, g4, be4, mu4, va4 },
    };

    for (int L = 0; L < 4; ++L) {
        const LayerDesc& ld = Ls[L];
        sq_kernel<<<64, 256, 0, stream>>>(ld.xin, ld.lda, ld.F, sq);
        if (ld.F == 3)
            distsel_kernel<3><<<dim3(32, 8), 256, 0, stream>>>(ld.xin, ld.lda, sq, idx);
        else if (ld.F == 64)
            distsel_kernel<64><<<dim3(32, 8), 256, 0, stream>>>(ld.xin, ld.lda, sq, idx);
        else
            distsel_kernel<128><<<dim3(32, 8), 256, 0, stream>>>(ld.xin, ld.lda, sq, idx);
        gemm64_kernel<<<dim3(256, ld.Fout / 64), 256, 0, stream>>>(
            ld.xin, ld.lda, ld.F, ld.W, ld.Fout, apart, ld.Fout);
        gemm64_kernel<<<dim3(256, ld.Fout / 64), 256, 0, stream>>>(
            ld.xin, ld.lda, ld.F, ld.W + (size_t)ld.F * ld.Fout, ld.Fout, bpart, ld.Fout);
        if (ld.Fout == 64)
            aggregate_kernel<64><<<1024, 256, 0, stream>>>(apart, bpart, idx,
                ld.g, ld.be, ld.mu, ld.va, ld.xout);
        else if (ld.Fout == 128)
            aggregate_kernel<128><<<2048, 256, 0, stream>>>(apart, bpart, idx,
                ld.g, ld.be, ld.mu, ld.va, ld.xout);
        else
            aggregate_kernel<256><<<4096, 256, 0, stream>>>(apart, bpart, idx,
                ld.g, ld.be, ld.mu, ld.va, ld.xout);
    }

    cvt_kernel<<<4096, 256, 0, stream>>>(xcat, ah, al);
    cvtT_kernel<<<dim3(32, 16), 256, 0, stream>>>(Wm, wmtH, wmtL);
    wm_mfma_pool<<<dim3(128, 8), 256, 0, stream>>>(ah, al, wmtH, wmtL,
                                                   gm, bem, mum, vam, partmax, partsum);
    pool2_kernel<<<dim3(4, 8), 256, 0, stream>>>(partmax, partsum, pooled);
    fc1_partial<<<dim3(16, 8), 512, 0, stream>>>(pooled, Wa, part1);
    fc1_reduce<<<8, 512, 0, stream>>>(part1, ga, bea, mua, vaa, t1);
    fc2_partial<<<dim3(4, 8), 256, 0, stream>>>(t1, Wb, part2);
    fc2_reduce<<<8, 256, 0, stream>>>(part2, bias_b, gb, beb, mub, vab, t2);
    fc3_kernel<<<8, 64, 0, stream>>>(t2, Wc, bias_c, (float*)d_out);
}

// Round 8
// 1450.835 us; speedup vs baseline: 2.8804x; 1.5360x over previous
//
#include <hip/hip_runtime.h>
#include <cstdint>
#include <cstddef>

#define NPTS 2048
#define BATCH 8
#define KNN 20
#define BIGF 3.402823466e38f

typedef short bf16x8 __attribute__((ext_vector_type(8)));
typedef float f32x4 __attribute__((ext_vector_type(4)));

__device__ __forceinline__ unsigned short f2bf(float v) {
    uint32_t u = __float_as_uint(v);
    uint32_t r = (u + 0x7FFFu + ((u >> 16) & 1u)) >> 16;
    return (unsigned short)r;
}
__device__ __forceinline__ float bf2f(unsigned short h) {
    return __uint_as_float(((uint32_t)h) << 16);
}
__device__ __forceinline__ uint32_t flipkey(float d) {
    uint32_t u = __float_as_uint(d);
    return (u & 0x80000000u) ? ~u : (u | 0x80000000u);
}
__device__ __forceinline__ uint64_t shfl_xor_u64w(uint64_t v, int m, int w) {
    int lo = __shfl_xor((int)(uint32_t)v, m, w);
    int hi = __shfl_xor((int)(uint32_t)(v >> 32), m, w);
    return ((uint64_t)(uint32_t)hi << 32) | (uint32_t)lo;
}
// branchless sorted insert into ascending 16-list (bubble-carry), guarded
__device__ __forceinline__ void ins16(uint64_t (&tl)[16], uint64_t c) {
    if (c < tl[15]) {
        uint64_t carry = c;
#pragma unroll
        for (int k = 0; k < 16; ++k) {
            uint64_t tk = tl[k];
            bool lt = carry < tk;
            uint64_t mn = lt ? carry : tk;
            uint64_t mx = lt ? tk : carry;
            tl[k] = mn; carry = mx;
        }
    }
}

// ======================= sum of squares per point =======================
__global__ __launch_bounds__(256) void sq_kernel(const float* __restrict__ x, int lda, int F,
                                                 float* __restrict__ sq)
{
    int p = blockIdx.x * 256 + threadIdx.x;   // 0..16383
    const float* xp = x + (size_t)p * lda;
    float s = 0.f;
    for (int f = 0; f < F; ++f) { float v = xp[f]; s = fmaf(v, v, s); }
    sq[p] = s;
}

// ======================= FUSED dist + top-20 select (v3) =======================
// Block: 256 thr, 32 i-rows, 8 j-tiles of 256. LDS ~59.5KB -> 2 blocks/CU.
// d2t XOR-swizzled (col ^= 4*(row&7)) -> 2-way (free) on both write and read.
// Select: 8 threads/row, register sorted top-16 each, final width-8 shfl extract.
// GEMM fmaf order == dist_kernel => bitwise-identical d2 keys.
template <int F>
__global__ __launch_bounds__(256) void distsel_kernel(const float* __restrict__ x, int lda,
                                                      const float* __restrict__ sq,
                                                      int* __restrict__ idx)
{
    constexpr int CF = ((F + 7) / 8) * 8;     // 8 / 64 / 128 (powers of two)
    __shared__ float As[CF][36];                    // x_i panel transposed [f][row]
    __shared__ __align__(16) float Bs[8][260];      // x_j chunk [f][col]
    __shared__ __align__(16) uint32_t d2t[32][256]; // swizzled key tile

    const int t  = threadIdx.x;
    const int tx = t & 31;           // 8 cols: cg*128 + tx*4 + c
    const int ty = t >> 5;           // 4 rows: ty*4 + r
    const int b  = blockIdx.y;
    const int i0 = blockIdx.x * 32;
    const float* xb  = x + (size_t)b * NPTS * lda;
    const float* sqb = sq + (size_t)b * NPTS;

    // stage As transposed; coalesced global (f fastest), 2-way LDS write
    for (int e = t; e < 32 * CF; e += 256) {
        int f   = e & (CF - 1);
        int row = e / CF;
        float v = (F == CF || f < F) ? xb[(size_t)(i0 + row) * lda + f] : 0.f;
        As[f][row] = v;
    }
    float sreg[4];
#pragma unroll
    for (int r = 0; r < 4; ++r) sreg[r] = sqb[i0 + ty * 4 + r];
    __syncthreads();

    uint64_t tl[16];
#pragma unroll
    for (int q = 0; q < 16; ++q) tl[q] = ~0ull;
    const int srow = t >> 3;         // select row 0..31
    const int slot = t & 7;          // 8 threads/row
    const int rswz = 4 * (srow & 7);

    for (int jt = 0; jt < 8; ++jt) {
        const int j0 = jt * 256;
        float acc[4][8];
#pragma unroll
        for (int r = 0; r < 4; ++r)
#pragma unroll
            for (int c = 0; c < 8; ++c) acc[r][c] = 0.f;

        for (int ch = 0; ch < CF / 8; ++ch) {
            const int k0 = ch * 8;
#pragma unroll
            for (int q = 0; q < 8; ++q) {
                int e = t + q * 256;
                int col = e >> 3, f = e & 7;
                float v = 0.f;
                if (F % 8 == 0 || k0 + f < F)
                    v = xb[(size_t)(j0 + col) * lda + k0 + f];
                Bs[f][col] = v;
            }
            __syncthreads();
#pragma unroll
            for (int k = 0; k < 8; ++k) {
                float4 a4 = *reinterpret_cast<const float4*>(&As[k0 + k][ty * 4]);
                float4 b0 = *reinterpret_cast<const float4*>(&Bs[k][tx * 4]);
                float4 b1 = *reinterpret_cast<const float4*>(&Bs[k][128 + tx * 4]);
                float av[4] = {a4.x, a4.y, a4.z, a4.w};
                float bv[8] = {b0.x, b0.y, b0.z, b0.w, b1.x, b1.y, b1.z, b1.w};
#pragma unroll
                for (int r = 0; r < 4; ++r)
#pragma unroll
                    for (int c = 0; c < 8; ++c) acc[r][c] = fmaf(av[r], bv[c], acc[r][c]);
            }
            __syncthreads();
        }

        // write swizzled key tile (same combine math as dist_kernel)
#pragma unroll
        for (int r = 0; r < 4; ++r) {
            const int row = ty * 4 + r;
            const float si = sreg[r];
            const int wswz = 4 * (row & 7);
#pragma unroll
            for (int cg = 0; cg < 2; ++cg) {
                const int col = cg * 128 + tx * 4;
                float4 sj4 = *reinterpret_cast<const float4*>(&sqb[j0 + col]);
                uint4 kv;
                kv.x = flipkey(si + sj4.x - 2.f * acc[r][cg * 4 + 0]);
                kv.y = flipkey(si + sj4.y - 2.f * acc[r][cg * 4 + 1]);
                kv.z = flipkey(si + sj4.z - 2.f * acc[r][cg * 4 + 2]);
                kv.w = flipkey(si + sj4.w - 2.f * acc[r][cg * 4 + 3]);
                *reinterpret_cast<uint4*>(&d2t[row][col ^ wswz]) = kv;
            }
        }
        __syncthreads();

        // select: 8 threads/row, 32 cols each (4-col blocks strided 32)
#pragma unroll 2
        for (int kk = 0; kk < 8; ++kk) {
            const int colb = slot * 4 + kk * 32;
            uint4 kv = *reinterpret_cast<const uint4*>(&d2t[srow][colb ^ rswz]);
            uint32_t mn = min(min(kv.x, kv.y), min(kv.z, kv.w));
            if (mn <= (uint32_t)(tl[15] >> 32)) {
                const uint32_t jb = (uint32_t)(j0 + colb);
                ins16(tl, ((uint64_t)kv.x << 32) | (jb + 0));
                ins16(tl, ((uint64_t)kv.y << 32) | (jb + 1));
                ins16(tl, ((uint64_t)kv.z << 32) | (jb + 2));
                ins16(tl, ((uint64_t)kv.w << 32) | (jb + 3));
            }
        }
        __syncthreads();   // d2t consumed before next tile overwrites it
    }

    // merge: 20 smallest across the row's 8 sorted lists (width-8 shfl)
    int* out = idx + ((size_t)b * NPTS + i0 + srow) * KNN;
    for (int it = 0; it < KNN; ++it) {
        uint64_t m = tl[0];
#pragma unroll
        for (int o = 1; o < 8; o <<= 1) {
            uint64_t ov = shfl_xor_u64w(m, o, 8);
            m = (ov < m) ? ov : m;
        }
        if (slot == (it & 7)) out[it] = (int)(uint32_t)m;
        bool win = (tl[0] == m);
#pragma unroll
        for (int k = 0; k < 15; ++k) tl[k] = win ? tl[k + 1] : tl[k];
        tl[15] = win ? ~0ull : tl[15];
    }
}

// ======================= generic small GEMM: C[M,Nc] = A[M,F] @ B[F,Nc] =======================
__global__ __launch_bounds__(256) void gemm64_kernel(const float* __restrict__ A, int lda, int F,
                                                     const float* __restrict__ Bw, int ldb,
                                                     float* __restrict__ C, int ldc)
{
    __shared__ float As[16][65];
    __shared__ float Bs[16][65];
    const int i0 = blockIdx.x * 64, j0 = blockIdx.y * 64;
    const int t = threadIdx.x, tx = t & 15, ty = t >> 4;
    float acc[4][4];
#pragma unroll
    for (int r = 0; r < 4; ++r)
#pragma unroll
        for (int c = 0; c < 4; ++c) acc[r][c] = 0.f;
    const int arow = t >> 2, akq = (t & 3) * 4;
    const int bk = t >> 4, bj = (t & 15) * 4;
    for (int k0 = 0; k0 < F; k0 += 16) {
#pragma unroll
        for (int q = 0; q < 4; ++q) {
            int kk = k0 + akq + q;
            As[akq + q][arow] = (kk < F) ? A[(size_t)(i0 + arow) * lda + kk] : 0.f;
        }
        {
            int kk = k0 + bk;
#pragma unroll
            for (int q = 0; q < 4; ++q)
                Bs[bk][bj + q] = (kk < F) ? Bw[(size_t)kk * ldb + j0 + bj + q] : 0.f;
        }
        __syncthreads();
#pragma unroll
        for (int k = 0; k < 16; ++k) {
            float a[4], bb[4];
#pragma unroll
            for (int r = 0; r < 4; ++r) a[r] = As[k][ty * 4 + r];
#pragma unroll
            for (int c = 0; c < 4; ++c) bb[c] = Bs[k][tx * 4 + c];
#pragma unroll
            for (int r = 0; r < 4; ++r)
#pragma unroll
                for (int c = 0; c < 4; ++c) acc[r][c] = fmaf(a[r], bb[c], acc[r][c]);
        }
        __syncthreads();
    }
#pragma unroll
    for (int r = 0; r < 4; ++r)
#pragma unroll
        for (int c = 0; c < 4; ++c)
            C[(size_t)(i0 + ty * 4 + r) * ldc + j0 + tx * 4 + c] = acc[r][c];
}

// ======================= EdgeConv aggregate (float4 lanes, multi-point blocks) =======================
template <int FOUT>
__global__ __launch_bounds__(256) void aggregate_kernel(const float* __restrict__ apart,
                                                        const float* __restrict__ bpart,
                                                        const int* __restrict__ idx,
                                                        const float* __restrict__ g,
                                                        const float* __restrict__ be,
                                                        const float* __restrict__ mu,
                                                        const float* __restrict__ var,
                                                        float* __restrict__ out)
{
    constexpr int G   = FOUT / 4;
    constexpr int PPB = 256 / G;
    const int t  = threadIdx.x;
    const int pi = t / G;
    const int fi = t % G;
    const int p  = blockIdx.x * PPB + pi;
    const int b  = p >> 11;
    const int* nb = idx + (size_t)p * KNN;
    const float4* bp4 = reinterpret_cast<const float4*>(bpart);
    const float4* bb  = bp4 + ((size_t)b << 11) * G;

    float4 m = {-BIGF, -BIGF, -BIGF, -BIGF};
#pragma unroll 4
    for (int k = 0; k < KNN; ++k) {
        int j = nb[k];
        float4 v = bb[(size_t)j * G + fi];
        m.x = fmaxf(m.x, v.x); m.y = fmaxf(m.y, v.y);
        m.z = fmaxf(m.z, v.z); m.w = fmaxf(m.w, v.w);
    }
    float4 av = reinterpret_cast<const float4*>(apart)[(size_t)p * G + fi];
    float4 bv = bp4[(size_t)p * G + fi];
    float4 gg = reinterpret_cast<const float4*>(g)[fi];
    float4 bee = reinterpret_cast<const float4*>(be)[fi];
    float4 muu = reinterpret_cast<const float4*>(mu)[fi];
    float4 vaa = reinterpret_cast<const float4*>(var)[fi];

    float4 r;
    {
        float s, sh, vv, y;
        s = gg.x * rsqrtf(vaa.x + 1e-5f); sh = bee.x - muu.x * s;
        vv = av.x - bv.x + m.x; y = vv * s + sh; r.x = (y >= 0.f) ? y : 0.2f * y;
        s = gg.y * rsqrtf(vaa.y + 1e-5f); sh = bee.y - muu.y * s;
        vv = av.y - bv.y + m.y; y = vv * s + sh; r.y = (y >= 0.f) ? y : 0.2f * y;
        s = gg.z * rsqrtf(vaa.z + 1e-5f); sh = bee.z - muu.z * s;
        vv = av.z - bv.z + m.z; y = vv * s + sh; r.z = (y >= 0.f) ? y : 0.2f * y;
        s = gg.w * rsqrtf(vaa.w + 1e-5f); sh = bee.w - muu.w * s;
        vv = av.w - bv.w + m.w; y = vv * s + sh; r.w = (y >= 0.f) ? y : 0.2f * y;
    }
    *reinterpret_cast<float4*>(out + (size_t)p * 512 + fi * 4) = r;
}

// ======================= split-bf16 converters =======================
__global__ __launch_bounds__(256) void cvt_kernel(const float* __restrict__ in,
                                                  unsigned short* __restrict__ hi,
                                                  unsigned short* __restrict__ lo)
{
    int i = blockIdx.x * 256 + threadIdx.x;
    const float4* p = reinterpret_cast<const float4*>(in) + (size_t)i * 2;
    float4 a = p[0], b = p[1];
    float v[8] = {a.x, a.y, a.z, a.w, b.x, b.y, b.z, b.w};
    uint32_t h[8], l[8];
#pragma unroll
    for (int q = 0; q < 8; ++q) {
        unsigned short hb = f2bf(v[q]);
        h[q] = hb;
        l[q] = f2bf(v[q] - bf2f(hb));
    }
    uint4 uh, ul;
    uh.x = h[0] | (h[1] << 16); uh.y = h[2] | (h[3] << 16);
    uh.z = h[4] | (h[5] << 16); uh.w = h[6] | (h[7] << 16);
    ul.x = l[0] | (l[1] << 16); ul.y = l[2] | (l[3] << 16);
    ul.z = l[4] | (l[5] << 16); ul.w = l[6] | (l[7] << 16);
    reinterpret_cast<uint4*>(hi)[i] = uh;
    reinterpret_cast<uint4*>(lo)[i] = ul;
}

__global__ __launch_bounds__(256) void cvtT_kernel(const float* __restrict__ Wm,
                                                   unsigned short* __restrict__ hiT,
                                                   unsigned short* __restrict__ loT)
{
    __shared__ float tile[32][33];
    const int n0 = blockIdx.x * 32;
    const int k0 = blockIdx.y * 32;
    const int t = threadIdx.x;
    const int c = t & 31, r = t >> 5;
#pragma unroll
    for (int rr = 0; rr < 4; ++rr)
        tile[r + rr * 8][c] = Wm[(size_t)(k0 + r + rr * 8) * 1024 + n0 + c];
    __syncthreads();
#pragma unroll
    for (int rr = 0; rr < 4; ++rr) {
        int nn = r + rr * 8, kk = c;
        float v = tile[kk][nn];
        unsigned short hb = f2bf(v);
        hiT[(size_t)(n0 + nn) * 512 + k0 + kk] = hb;
        loT[(size_t)(n0 + nn) * 512 + k0 + kk] = f2bf(v - bf2f(hb));
    }
}

// ======================= Wm via split-bf16 MFMA + BN + lrelu + pooling =======================
__global__ __launch_bounds__(256) void wm_mfma_pool(const unsigned short* __restrict__ AH,
                                                    const unsigned short* __restrict__ AL,
                                                    const unsigned short* __restrict__ BH,
                                                    const unsigned short* __restrict__ BL,
                                                    const float* __restrict__ g,
                                                    const float* __restrict__ be,
                                                    const float* __restrict__ mu,
                                                    const float* __restrict__ var,
                                                    float* __restrict__ partmax,
                                                    float* __restrict__ partsum)
{
    __shared__ unsigned short AsH[128][40], AsL[128][40], BsH[128][40], BsL[128][40];
    __shared__ float redm[4][64], reds[4][64];
    const int t = threadIdx.x;
    const int i0 = blockIdx.x * 128, j0 = blockIdx.y * 128;
    const int lane = t & 63, wid = t >> 6, wy = wid >> 1, wx = wid & 1;
    const int lc = lane & 15, kg = lane >> 4;

    f32x4 acc[4][4];
#pragma unroll
    for (int mi = 0; mi < 4; ++mi)
#pragma unroll
        for (int ni = 0; ni < 4; ++ni) acc[mi][ni] = (f32x4){0.f, 0.f, 0.f, 0.f};

    for (int k0 = 0; k0 < 512; k0 += 32) {
        __syncthreads();
#pragma unroll
        for (int q = 0; q < 2; ++q) {
            int c = t + q * 256;
            int row = c >> 2, ko = (c & 3) * 8;
            *reinterpret_cast<uint4*>(&AsH[row][ko]) =
                *reinterpret_cast<const uint4*>(&AH[(size_t)(i0 + row) * 512 + k0 + ko]);
            *reinterpret_cast<uint4*>(&AsL[row][ko]) =
                *reinterpret_cast<const uint4*>(&AL[(size_t)(i0 + row) * 512 + k0 + ko]);
            *reinterpret_cast<uint4*>(&BsH[row][ko]) =
                *reinterpret_cast<const uint4*>(&BH[(size_t)(j0 + row) * 512 + k0 + ko]);
            *reinterpret_cast<uint4*>(&BsL[row][ko]) =
                *reinterpret_cast<const uint4*>(&BL[(size_t)(j0 + row) * 512 + k0 + ko]);
        }
        __syncthreads();

        bf16x8 aH[4], aL[4], bH[4], bL[4];
#pragma unroll
        for (int mi = 0; mi < 4; ++mi) {
            int ar = wy * 64 + mi * 16 + lc;
            aH[mi] = *reinterpret_cast<const bf16x8*>(&AsH[ar][kg * 8]);
            aL[mi] = *reinterpret_cast<const bf16x8*>(&AsL[ar][kg * 8]);
        }
#pragma unroll
        for (int ni = 0; ni < 4; ++ni) {
            int br = wx * 64 + ni * 16 + lc;
            bH[ni] = *reinterpret_cast<const bf16x8*>(&BsH[br][kg * 8]);
            bL[ni] = *reinterpret_cast<const bf16x8*>(&BsL[br][kg * 8]);
        }
#pragma unroll
        for (int mi = 0; mi < 4; ++mi)
#pragma unroll
            for (int ni = 0; ni < 4; ++ni) {
                acc[mi][ni] = __builtin_amdgcn_mfma_f32_16x16x32_bf16(aH[mi], bH[ni], acc[mi][ni], 0, 0, 0);
                acc[mi][ni] = __builtin_amdgcn_mfma_f32_16x16x32_bf16(aH[mi], bL[ni], acc[mi][ni], 0, 0, 0);
                acc[mi][ni] = __builtin_amdgcn_mfma_f32_16x16x32_bf16(aL[mi], bH[ni], acc[mi][ni], 0, 0, 0);
            }
    }

    float pmax[4], psum[4];
#pragma unroll
    for (int ni = 0; ni < 4; ++ni) {
        int j = j0 + wx * 64 + ni * 16 + lc;
        float s = g[j] * rsqrtf(var[j] + 1e-5f);
        float sh = be[j] - mu[j] * s;
        float pm = -BIGF, ps = 0.f;
#pragma unroll
        for (int mi = 0; mi < 4; ++mi)
#pragma unroll
            for (int r = 0; r < 4; ++r) {
                float y = fmaf(acc[mi][ni][r], s, sh);
                y = (y >= 0.f) ? y : 0.2f * y;
                pm = fmaxf(pm, y);
                ps += y;
            }
        pmax[ni] = pm; psum[ni] = ps;
    }
#pragma unroll
    for (int ni = 0; ni < 4; ++ni) {
        pmax[ni] = fmaxf(pmax[ni], __shfl_xor(pmax[ni], 16, 64));
        pmax[ni] = fmaxf(pmax[ni], __shfl_xor(pmax[ni], 32, 64));
        psum[ni] += __shfl_xor(psum[ni], 16, 64);
        psum[ni] += __shfl_xor(psum[ni], 32, 64);
    }
    if (lane < 16) {
#pragma unroll
        for (int ni = 0; ni < 4; ++ni) {
            redm[wid][ni * 16 + lc] = pmax[ni];
            reds[wid][ni * 16 + lc] = psum[ni];
        }
    }
    __syncthreads();
    if (t < 128) {
        int wxq = t >> 6, cl = t & 63;
        float m = fmaxf(redm[wxq][cl], redm[2 + wxq][cl]);
        float sv = reds[wxq][cl] + reds[2 + wxq][cl];
        int b = i0 >> 11, rb = (i0 & 2047) >> 7;
        partmax[((size_t)b * 16 + rb) * 1024 + j0 + t] = m;
        partsum[((size_t)b * 16 + rb) * 1024 + j0 + t] = sv;
    }
}

// ======================= pooling reduce =======================
__global__ __launch_bounds__(256) void pool2_kernel(const float* __restrict__ partmax,
                                                    const float* __restrict__ partsum,
                                                    float* __restrict__ pooled)
{
    const int c = blockIdx.x * 256 + threadIdx.x;
    const int b = blockIdx.y;
    float m = -BIGF, s = 0.f;
    for (int rb = 0; rb < 16; ++rb) {
        m = fmaxf(m, partmax[((size_t)b * 16 + rb) * 1024 + c]);
        s += partsum[((size_t)b * 16 + rb) * 1024 + c];
    }
    pooled[(size_t)b * 2048 + c] = m;
    pooled[(size_t)b * 2048 + 1024 + c] = s * (1.f / 2048.f);
}

// ======================= tail FCs (split-K) =======================
__global__ __launch_bounds__(512) void fc1_partial(const float* __restrict__ pooled,
                                                   const float* __restrict__ Wa,
                                                   float* __restrict__ part)
{
    const int kk = blockIdx.x, b = blockIdx.y, c = threadIdx.x;
    __shared__ float sp[128];
    if (c < 128) sp[c] = pooled[(size_t)b * 2048 + kk * 128 + c];
    __syncthreads();
    const float* w = Wa + (size_t)kk * 128 * 512 + c;
    float acc = 0.f;
#pragma unroll 8
    for (int j = 0; j < 128; ++j) acc = fmaf(sp[j], w[(size_t)j * 512], acc);
    part[((size_t)b * 16 + kk) * 512 + c] = acc;
}

__global__ __launch_bounds__(512) void fc1_reduce(const float* __restrict__ part,
                                                  const float* __restrict__ g, const float* __restrict__ be,
                                                  const float* __restrict__ mu, const float* __restrict__ var,
                                                  float* __restrict__ t1)
{
    const int b = blockIdx.x, c = threadIdx.x;
    float acc = 0.f;
#pragma unroll
    for (int kk = 0; kk < 16; ++kk) acc += part[((size_t)b * 16 + kk) * 512 + c];
    float s = g[c] * rsqrtf(var[c] + 1e-5f);
    float y = acc * s + (be[c] - mu[c] * s);
    t1[(size_t)b * 512 + c] = (y >= 0.f) ? y : 0.2f * y;
}

__global__ __launch_bounds__(256) void fc2_partial(const float* __restrict__ t1,
                                                   const float* __restrict__ Wb,
                                                   float* __restrict__ part)
{
    const int kk = blockIdx.x, b = blockIdx.y, c = threadIdx.x;
    __shared__ float sp[128];
    if (c < 128) sp[c] = t1[(size_t)b * 512 + kk * 128 + c];
    __syncthreads();
    const float* w = Wb + (size_t)kk * 128 * 256 + c;
    float acc = 0.f;
#pragma unroll 8
    for (int j = 0; j < 128; ++j) acc = fmaf(sp[j], w[(size_t)j * 256], acc);
    part[((size_t)b * 4 + kk) * 256 + c] = acc;
}

__global__ __launch_bounds__(256) void fc2_reduce(const float* __restrict__ part,
                                                  const float* __restrict__ bias_b,
                                                  const float* __restrict__ g, const float* __restrict__ be,
                                                  const float* __restrict__ mu, const float* __restrict__ var,
                                                  float* __restrict__ t2)
{
    const int b = blockIdx.x, c = threadIdx.x;
    float acc = bias_b[c];
#pragma unroll
    for (int kk = 0; kk < 4; ++kk) acc += part[((size_t)b * 4 + kk) * 256 + c];
    float s = g[c] * rsqrtf(var[c] + 1e-5f);
    float y = acc * s + (be[c] - mu[c] * s);
    t2[(size_t)b * 256 + c] = (y >= 0.f) ? y : 0.2f * y;
}

__global__ __launch_bounds__(64) void fc3_kernel(const float* __restrict__ t2,
                                                 const float* __restrict__ Wc,
                                                 const float* __restrict__ bias_c,
                                                 float* __restrict__ out)
{
    const int b = blockIdx.x, c = threadIdx.x;
    __shared__ float sp[256];
    for (int k = c; k < 256; k += 64) sp[k] = t2[(size_t)b * 256 + k];
    __syncthreads();
    if (c < 40) {
        float acc = 0.f;
#pragma unroll 8
        for (int k = 0; k < 256; ++k) acc = fmaf(sp[k], Wc[(size_t)k * 40 + c], acc);
        out[(size_t)b * 40 + c] = acc + bias_c[c];
    }
}

// ======================= launch =======================
extern "C" void kernel_launch(void* const* d_in, const int* in_sizes, int n_in,
                              void* d_out, int out_size, void* d_ws, size_t ws_size,
                              hipStream_t stream)
{
    const float* pos = (const float*)d_in[0];
    const float* W1 = (const float*)d_in[1];
    const float* g1 = (const float*)d_in[2];  const float* be1 = (const float*)d_in[3];
    const float* mu1 = (const float*)d_in[4]; const float* va1 = (const float*)d_in[5];
    const float* W2 = (const float*)d_in[6];
    const float* g2 = (const float*)d_in[7];  const float* be2 = (const float*)d_in[8];
    const float* mu2 = (const float*)d_in[9]; const float* va2 = (const float*)d_in[10];
    const float* W3 = (const float*)d_in[11];
    const float* g3 = (const float*)d_in[12]; const float* be3 = (const float*)d_in[13];
    const float* mu3 = (const float*)d_in[14];const float* va3 = (const float*)d_in[15];
    const float* W4 = (const float*)d_in[16];
    const float* g4 = (const float*)d_in[17]; const float* be4 = (const float*)d_in[18];
    const float* mu4 = (const float*)d_in[19];const float* va4 = (const float*)d_in[20];
    const float* Wm = (const float*)d_in[21];
    const float* gm = (const float*)d_in[22]; const float* bem = (const float*)d_in[23];
    const float* mum = (const float*)d_in[24];const float* vam = (const float*)d_in[25];
    const float* Wa = (const float*)d_in[26];
    const float* ga = (const float*)d_in[27]; const float* bea = (const float*)d_in[28];
    const float* mua = (const float*)d_in[29];const float* vaa = (const float*)d_in[30];
    const float* Wb = (const float*)d_in[31];
    const float* gb = (const float*)d_in[32]; const float* beb = (const float*)d_in[33];
    const float* mub = (const float*)d_in[34];const float* vab = (const float*)d_in[35];
    const float* bias_b = (const float*)d_in[36];
    const float* Wc = (const float*)d_in[37];
    const float* bias_c = (const float*)d_in[38];

    char* ws = (char*)d_ws;
    size_t off = 0;
    auto alloc = [&](size_t bytes) -> void* {
        void* p = ws + off;
        off += (bytes + 255) & ~(size_t)255;
        return p;
    };
    float* xcat    = (float*)alloc((size_t)16384 * 512 * 4);
    float* sq      = (float*)alloc((size_t)16384 * 4);
    int*   idx     = (int*)  alloc((size_t)16384 * KNN * 4);
    float* apart   = (float*)alloc((size_t)16384 * 256 * 4);
    float* bpart   = (float*)alloc((size_t)16384 * 256 * 4);
    float* partmax = (float*)alloc((size_t)8 * 16 * 1024 * 4);
    float* partsum = (float*)alloc((size_t)8 * 16 * 1024 * 4);
    float* pooled  = (float*)alloc((size_t)8 * 2048 * 4);
    float* t1      = (float*)alloc((size_t)8 * 512 * 4);
    float* t2      = (float*)alloc((size_t)8 * 256 * 4);
    float* part1   = (float*)alloc((size_t)8 * 16 * 512 * 4);
    float* part2   = (float*)alloc((size_t)8 * 4 * 256 * 4);
    unsigned short* ah   = (unsigned short*)alloc((size_t)16384 * 512 * 2);
    unsigned short* al   = (unsigned short*)alloc((size_t)16384 * 512 * 2);
    unsigned short* wmtH = (unsigned short*)alloc((size_t)1024 * 512 * 2);
    unsigned short* wmtL = (unsigned short*)alloc((size_t)1024 * 512 * 2);

    struct LayerDesc {
        const float* xin; int lda; int F; int Fout;
        float* xout; const float* W;
        const float* g; const float* be; const float* mu; const float* va;
    };
    LayerDesc Ls[4] = {
        { pos,        3,   3,   64,  xcat + 0,   W1, g1, be1, mu1, va1 },
        { xcat + 0,   512, 64,  64,  xcat + 64,  W2, g2, be2, mu2, va2 },
        { xcat + 64,  512, 64,  128, xcat + 128, W3, g3, be3, mu3, va3 },
        { xcat + 128, 512, 128, 256, xcat + 256, W4, g4, be4, mu4, va4 },
    };

    for (int L = 0; L < 4; ++L) {
        const LayerDesc& ld = Ls[L];
        sq_kernel<<<64, 256, 0, stream>>>(ld.xin, ld.lda, ld.F, sq);
        if (ld.F == 3)
            distsel_kernel<3><<<dim3(64, 8), 256, 0, stream>>>(ld.xin, ld.lda, sq, idx);
        else if (ld.F == 64)
            distsel_kernel<64><<<dim3(64, 8), 256, 0, stream>>>(ld.xin, ld.lda, sq, idx);
        else
            distsel_kernel<128><<<dim3(64, 8), 256, 0, stream>>>(ld.xin, ld.lda, sq, idx);
        gemm64_kernel<<<dim3(256, ld.Fout / 64), 256, 0, stream>>>(
            ld.xin, ld.lda, ld.F, ld.W, ld.Fout, apart, ld.Fout);
        gemm64_kernel<<<dim3(256, ld.Fout / 64), 256, 0, stream>>>(
            ld.xin, ld.lda, ld.F, ld.W + (size_t)ld.F * ld.Fout, ld.Fout, bpart, ld.Fout);
        if (ld.Fout == 64)
            aggregate_kernel<64><<<1024, 256, 0, stream>>>(apart, bpart, idx,
                ld.g, ld.be, ld.mu, ld.va, ld.xout);
        else if (ld.Fout == 128)
            aggregate_kernel<128><<<2048, 256, 0, stream>>>(apart, bpart, idx,
                ld.g, ld.be, ld.mu, ld.va, ld.xout);
        else
            aggregate_kernel<256><<<4096, 256, 0, stream>>>(apart, bpart, idx,
                ld.g, ld.be, ld.mu, ld.va, ld.xout);
    }

    cvt_kernel<<<4096, 256, 0, stream>>>(xcat, ah, al);
    cvtT_kernel<<<dim3(32, 16), 256, 0, stream>>>(Wm, wmtH, wmtL);
    wm_mfma_pool<<<dim3(128, 8), 256, 0, stream>>>(ah, al, wmtH, wmtL,
                                                   gm, bem, mum, vam, partmax, partsum);
    pool2_kernel<<<dim3(4, 8), 256, 0, stream>>>(partmax, partsum, pooled);
    fc1_partial<<<dim3(16, 8), 512, 0, stream>>>(pooled, Wa, part1);
    fc1_reduce<<<8, 512, 0, stream>>>(part1, ga, bea, mua, vaa, t1);
    fc2_partial<<<dim3(4, 8), 256, 0, stream>>>(t1, Wb, part2);
    fc2_reduce<<<8, 256, 0, stream>>>(part2, bias_b, gb, beb, mub, vab, t2);
    fc3_kernel<<<8, 64, 0, stream>>>(t2, Wc, bias_c, (float*)d_out);
}

// Round 9
// 1002.011 us; speedup vs baseline: 4.1706x; 1.4479x over previous
//
#include <hip/hip_runtime.h>
#include <cstdint>
#include <cstddef>

#define NPTS 2048
#define BATCH 8
#define KNN 20
#define BIGF 3.402823466e38f

typedef short bf16x8 __attribute__((ext_vector_type(8)));
typedef float f32x4 __attribute__((ext_vector_type(4)));

__device__ __forceinline__ unsigned short f2bf(float v) {
    uint32_t u = __float_as_uint(v);
    uint32_t r = (u + 0x7FFFu + ((u >> 16) & 1u)) >> 16;
    return (unsigned short)r;
}
__device__ __forceinline__ float bf2f(unsigned short h) {
    return __uint_as_float(((uint32_t)h) << 16);
}
__device__ __forceinline__ uint32_t flipkey(float d) {
    uint32_t u = __float_as_uint(d);
    return (u & 0x80000000u) ? ~u : (u | 0x80000000u);
}
__device__ __forceinline__ uint64_t shfl_xor_u64(uint64_t v, int m) {
    int lo = __shfl_xor((int)(uint32_t)v, m, 64);
    int hi = __shfl_xor((int)(uint32_t)(v >> 32), m, 64);
    return ((uint64_t)(uint32_t)hi << 32) | (uint32_t)lo;
}

// ======================= sum of squares per point =======================
__global__ __launch_bounds__(256) void sq_kernel(const float* __restrict__ x, int lda, int F,
                                                 float* __restrict__ sq)
{
    int p = blockIdx.x * 256 + threadIdx.x;   // 0..16383
    const float* xp = x + (size_t)p * lda;
    float s = 0.f;
    for (int f = 0; f < F; ++f) { float v = xp[f]; s = fmaf(v, v, s); }
    sq[p] = s;
}

// ======================= pairwise distance GEMM -> u32 flip-keys =======================
// d2 values bitwise-identical to R5's dist_kernel; stored as order-preserving u32 keys.
// With CB=4, the 67MB key chunk stays L3-resident for the following select.
__global__ __launch_bounds__(256) void distk_kernel(const float* __restrict__ x, int lda,
                                                    const float* __restrict__ sq,
                                                    uint32_t* __restrict__ d2k, int F, int b0)
{
    __shared__ __align__(16) float As[8][132];
    __shared__ __align__(16) float Bs[8][132];
    const int b  = b0 + blockIdx.z;
    const int i0 = blockIdx.x * 128;
    const int j0 = blockIdx.y * 128;
    const float* xb  = x + (size_t)b * NPTS * lda;
    const float* sqb = sq + (size_t)b * NPTS;
    const int t  = threadIdx.x;
    const int tx = t & 15, ty = t >> 4;
    const int lrow = t >> 1, lkq = (t & 1) * 4;

    float acc[8][8];
#pragma unroll
    for (int r = 0; r < 8; ++r)
#pragma unroll
        for (int c = 0; c < 8; ++c) acc[r][c] = 0.f;

    for (int k0 = 0; k0 < F; k0 += 8) {
        const float* sa = xb + (size_t)(i0 + lrow) * lda + k0 + lkq;
        const float* sb = xb + (size_t)(j0 + lrow) * lda + k0 + lkq;
        if (k0 + 8 <= F) {
            float4 a4 = *reinterpret_cast<const float4*>(sa);
            float4 b4 = *reinterpret_cast<const float4*>(sb);
            As[lkq + 0][lrow] = a4.x; As[lkq + 1][lrow] = a4.y;
            As[lkq + 2][lrow] = a4.z; As[lkq + 3][lrow] = a4.w;
            Bs[lkq + 0][lrow] = b4.x; Bs[lkq + 1][lrow] = b4.y;
            Bs[lkq + 2][lrow] = b4.z; Bs[lkq + 3][lrow] = b4.w;
        } else {
#pragma unroll
            for (int q = 0; q < 4; ++q) {
                int kk = k0 + lkq + q;
                As[lkq + q][lrow] = (kk < F) ? sa[q] : 0.f;
                Bs[lkq + q][lrow] = (kk < F) ? sb[q] : 0.f;
            }
        }
        __syncthreads();
#pragma unroll
        for (int k = 0; k < 8; ++k) {
            float4 a0 = *reinterpret_cast<const float4*>(&As[k][ty * 4]);
            float4 a1 = *reinterpret_cast<const float4*>(&As[k][64 + ty * 4]);
            float4 c0 = *reinterpret_cast<const float4*>(&Bs[k][tx * 4]);
            float4 c1 = *reinterpret_cast<const float4*>(&Bs[k][64 + tx * 4]);
            float av[8] = {a0.x, a0.y, a0.z, a0.w, a1.x, a1.y, a1.z, a1.w};
            float bv[8] = {c0.x, c0.y, c0.z, c0.w, c1.x, c1.y, c1.z, c1.w};
#pragma unroll
            for (int r = 0; r < 8; ++r)
#pragma unroll
                for (int c = 0; c < 8; ++c) acc[r][c] = fmaf(av[r], bv[c], acc[r][c]);
        }
        __syncthreads();
    }

    uint32_t* db = d2k + (size_t)blockIdx.z * NPTS * NPTS;
#pragma unroll
    for (int r = 0; r < 8; ++r) {
        int i = i0 + ((r < 4) ? (ty * 4 + r) : (64 + ty * 4 + r - 4));
        float si = sqb[i];
#pragma unroll
        for (int cq = 0; cq < 2; ++cq) {
            int j = j0 + (cq ? 64 : 0) + tx * 4;
            uint4 o;
            o.x = flipkey(si + sqb[j + 0] - 2.f * acc[r][cq * 4 + 0]);
            o.y = flipkey(si + sqb[j + 1] - 2.f * acc[r][cq * 4 + 1]);
            o.z = flipkey(si + sqb[j + 2] - 2.f * acc[r][cq * 4 + 2]);
            o.w = flipkey(si + sqb[j + 3] - 2.f * acc[r][cq * 4 + 3]);
            *reinterpret_cast<uint4*>(&db[(size_t)i * NPTS + j]) = o;
        }
    }
}

// ======================= top-20: one wave per row, sorted local top-4 (R4-proven) =======================
__global__ __launch_bounds__(256) void select_kernel(const uint32_t* __restrict__ d2k,
                                                     int* __restrict__ idx, int b0)
{
    const int t    = threadIdx.x;
    const int lane = t & 63;
    const int wid  = t >> 6;
    const int row_id = blockIdx.x * 4 + wid;
    const int bz = row_id >> 11;
    const int i  = row_id & 2047;
    const uint32_t* row = d2k + ((size_t)bz * NPTS + i) * NPTS;

    uint32_t key[32];
#pragma unroll
    for (int s = 0; s < 8; ++s) {
        uint4 kv = *reinterpret_cast<const uint4*>(&row[s * 256 + lane * 4]);
        key[s * 4 + 0] = kv.x; key[s * 4 + 1] = kv.y;
        key[s * 4 + 2] = kv.z; key[s * 4 + 3] = kv.w;
    }

    const uint64_t MAXV = ~0ull;
    uint64_t t1 = MAXV, t2 = MAXV, t3 = MAXV, t4 = MAXV;

#pragma unroll
    for (int s = 0; s < 8; ++s)
#pragma unroll
        for (int q = 0; q < 4; ++q) {
            uint64_t c = ((uint64_t)key[s * 4 + q] << 32) | (uint32_t)(s * 256 + lane * 4 + q);
            if (c < t4) {
                if (c < t2) {
                    t4 = t3; t3 = t2;
                    if (c < t1) { t2 = t1; t1 = c; } else t2 = c;
                } else {
                    if (c < t3) { t4 = t3; t3 = c; } else t4 = c;
                }
            }
        }

    uint64_t keep = 0;
    for (int it = 0; it < KNN; ++it) {
        uint64_t w = t1;
#pragma unroll
        for (int o = 1; o < 64; o <<= 1) {
            uint64_t ov = shfl_xor_u64(w, o);
            w = (ov < w) ? ov : w;
        }
        keep = (lane == it) ? w : keep;
        if (t1 == w) {
            t1 = t2; t2 = t3; t3 = t4; t4 = MAXV;
            if (t1 == MAXV) {          // rare refill: this lane already supplied 4
#pragma unroll
                for (int s = 0; s < 8; ++s)
#pragma unroll
                    for (int q = 0; q < 4; ++q) {
                        uint64_t c = ((uint64_t)key[s * 4 + q] << 32) |
                                     (uint32_t)(s * 256 + lane * 4 + q);
                        if (c > w && c < t4) {
                            if (c < t2) {
                                t4 = t3; t3 = t2;
                                if (c < t1) { t2 = t1; t1 = c; } else t2 = c;
                            } else {
                                if (c < t3) { t4 = t3; t3 = c; } else t4 = c;
                            }
                        }
                    }
            }
        }
    }

    int* out = idx + ((size_t)(b0 + bz) * NPTS + i) * KNN;
    if (lane < KNN) out[lane] = (int)(uint32_t)keep;
}

// ======================= dual small GEMM: apart & bpart in one dispatch =======================
// grid (256, Fout/64, 2): z=0 -> A@W_top -> apart, z=1 -> A@W_bot -> bpart
__global__ __launch_bounds__(256) void gemm64_kernel(const float* __restrict__ A, int lda, int F,
                                                     const float* __restrict__ Wfull, int Fout,
                                                     float* __restrict__ apart,
                                                     float* __restrict__ bpart)
{
    __shared__ float As[16][65];
    __shared__ float Bs[16][65];
    const int i0 = blockIdx.x * 64, j0 = blockIdx.y * 64;
    const int half = blockIdx.z;
    const float* Bw = Wfull + (size_t)(half ? F : 0) * Fout;
    float* C = half ? bpart : apart;
    const int t = threadIdx.x, tx = t & 15, ty = t >> 4;
    float acc[4][4];
#pragma unroll
    for (int r = 0; r < 4; ++r)
#pragma unroll
        for (int c = 0; c < 4; ++c) acc[r][c] = 0.f;
    const int arow = t >> 2, akq = (t & 3) * 4;
    const int bk = t >> 4, bj = (t & 15) * 4;
    for (int k0 = 0; k0 < F; k0 += 16) {
#pragma unroll
        for (int q = 0; q < 4; ++q) {
            int kk = k0 + akq + q;
            As[akq + q][arow] = (kk < F) ? A[(size_t)(i0 + arow) * lda + kk] : 0.f;
        }
        {
            int kk = k0 + bk;
#pragma unroll
            for (int q = 0; q < 4; ++q)
                Bs[bk][bj + q] = (kk < F) ? Bw[(size_t)kk * Fout + j0 + bj + q] : 0.f;
        }
        __syncthreads();
#pragma unroll
        for (int k = 0; k < 16; ++k) {
            float a[4], bb[4];
#pragma unroll
            for (int r = 0; r < 4; ++r) a[r] = As[k][ty * 4 + r];
#pragma unroll
            for (int c = 0; c < 4; ++c) bb[c] = Bs[k][tx * 4 + c];
#pragma unroll
            for (int r = 0; r < 4; ++r)
#pragma unroll
                for (int c = 0; c < 4; ++c) acc[r][c] = fmaf(a[r], bb[c], acc[r][c]);
        }
        __syncthreads();
    }
#pragma unroll
    for (int r = 0; r < 4; ++r)
#pragma unroll
        for (int c = 0; c < 4; ++c)
            C[(size_t)(i0 + ty * 4 + r) * Fout + j0 + tx * 4 + c] = acc[r][c];
}

// ======================= EdgeConv aggregate (float4 lanes, multi-point blocks) =======================
template <int FOUT>
__global__ __launch_bounds__(256) void aggregate_kernel(const float* __restrict__ apart,
                                                        const float* __restrict__ bpart,
                                                        const int* __restrict__ idx,
                                                        const float* __restrict__ g,
                                                        const float* __restrict__ be,
                                                        const float* __restrict__ mu,
                                                        const float* __restrict__ var,
                                                        float* __restrict__ out)
{
    constexpr int G   = FOUT / 4;
    constexpr int PPB = 256 / G;
    const int t  = threadIdx.x;
    const int pi = t / G;
    const int fi = t % G;
    const int p  = blockIdx.x * PPB + pi;
    const int b  = p >> 11;
    const int* nb = idx + (size_t)p * KNN;
    const float4* bp4 = reinterpret_cast<const float4*>(bpart);
    const float4* bb  = bp4 + ((size_t)b << 11) * G;

    float4 m = {-BIGF, -BIGF, -BIGF, -BIGF};
#pragma unroll 4
    for (int k = 0; k < KNN; ++k) {
        int j = nb[k];
        float4 v = bb[(size_t)j * G + fi];
        m.x = fmaxf(m.x, v.x); m.y = fmaxf(m.y, v.y);
        m.z = fmaxf(m.z, v.z); m.w = fmaxf(m.w, v.w);
    }
    float4 av = reinterpret_cast<const float4*>(apart)[(size_t)p * G + fi];
    float4 bv = bp4[(size_t)p * G + fi];
    float4 gg = reinterpret_cast<const float4*>(g)[fi];
    float4 bee = reinterpret_cast<const float4*>(be)[fi];
    float4 muu = reinterpret_cast<const float4*>(mu)[fi];
    float4 vaa = reinterpret_cast<const float4*>(var)[fi];

    float4 r;
    {
        float s, sh, vv, y;
        s = gg.x * rsqrtf(vaa.x + 1e-5f); sh = bee.x - muu.x * s;
        vv = av.x - bv.x + m.x; y = vv * s + sh; r.x = (y >= 0.f) ? y : 0.2f * y;
        s = gg.y * rsqrtf(vaa.y + 1e-5f); sh = bee.y - muu.y * s;
        vv = av.y - bv.y + m.y; y = vv * s + sh; r.y = (y >= 0.f) ? y : 0.2f * y;
        s = gg.z * rsqrtf(vaa.z + 1e-5f); sh = bee.z - muu.z * s;
        vv = av.z - bv.z + m.z; y = vv * s + sh; r.z = (y >= 0.f) ? y : 0.2f * y;
        s = gg.w * rsqrtf(vaa.w + 1e-5f); sh = bee.w - muu.w * s;
        vv = av.w - bv.w + m.w; y = vv * s + sh; r.w = (y >= 0.f) ? y : 0.2f * y;
    }
    *reinterpret_cast<float4*>(out + (size_t)p * 512 + fi * 4) = r;
}

// ======================= split-bf16 converters =======================
__global__ __launch_bounds__(256) void cvt_kernel(const float* __restrict__ in,
                                                  unsigned short* __restrict__ hi,
                                                  unsigned short* __restrict__ lo)
{
    int i = blockIdx.x * 256 + threadIdx.x;
    const float4* p = reinterpret_cast<const float4*>(in) + (size_t)i * 2;
    float4 a = p[0], b = p[1];
    float v[8] = {a.x, a.y, a.z, a.w, b.x, b.y, b.z, b.w};
    uint32_t h[8], l[8];
#pragma unroll
    for (int q = 0; q < 8; ++q) {
        unsigned short hb = f2bf(v[q]);
        h[q] = hb;
        l[q] = f2bf(v[q] - bf2f(hb));
    }
    uint4 uh, ul;
    uh.x = h[0] | (h[1] << 16); uh.y = h[2] | (h[3] << 16);
    uh.z = h[4] | (h[5] << 16); uh.w = h[6] | (h[7] << 16);
    ul.x = l[0] | (l[1] << 16); ul.y = l[2] | (l[3] << 16);
    ul.z = l[4] | (l[5] << 16); ul.w = l[6] | (l[7] << 16);
    reinterpret_cast<uint4*>(hi)[i] = uh;
    reinterpret_cast<uint4*>(lo)[i] = ul;
}

__global__ __launch_bounds__(256) void cvtT_kernel(const float* __restrict__ Wm,
                                                   unsigned short* __restrict__ hiT,
                                                   unsigned short* __restrict__ loT)
{
    __shared__ float tile[32][33];
    const int n0 = blockIdx.x * 32;
    const int k0 = blockIdx.y * 32;
    const int t = threadIdx.x;
    const int c = t & 31, r = t >> 5;
#pragma unroll
    for (int rr = 0; rr < 4; ++rr)
        tile[r + rr * 8][c] = Wm[(size_t)(k0 + r + rr * 8) * 1024 + n0 + c];
    __syncthreads();
#pragma unroll
    for (int rr = 0; rr < 4; ++rr) {
        int nn = r + rr * 8, kk = c;
        float v = tile[kk][nn];
        unsigned short hb = f2bf(v);
        hiT[(size_t)(n0 + nn) * 512 + k0 + kk] = hb;
        loT[(size_t)(n0 + nn) * 512 + k0 + kk] = f2bf(v - bf2f(hb));
    }
}

// ======================= Wm via split-bf16 MFMA + BN + lrelu + pooling =======================
__global__ __launch_bounds__(256) void wm_mfma_pool(const unsigned short* __restrict__ AH,
                                                    const unsigned short* __restrict__ AL,
                                                    const unsigned short* __restrict__ BH,
                                                    const unsigned short* __restrict__ BL,
                                                    const float* __restrict__ g,
                                                    const float* __restrict__ be,
                                                    const float* __restrict__ mu,
                                                    const float* __restrict__ var,
                                                    float* __restrict__ partmax,
                                                    float* __restrict__ partsum)
{
    __shared__ unsigned short AsH[128][40], AsL[128][40], BsH[128][40], BsL[128][40];
    __shared__ float redm[4][64], reds[4][64];
    const int t = threadIdx.x;
    const int i0 = blockIdx.x * 128, j0 = blockIdx.y * 128;
    const int lane = t & 63, wid = t >> 6, wy = wid >> 1, wx = wid & 1;
    const int lc = lane & 15, kg = lane >> 4;

    f32x4 acc[4][4];
#pragma unroll
    for (int mi = 0; mi < 4; ++mi)
#pragma unroll
        for (int ni = 0; ni < 4; ++ni) acc[mi][ni] = (f32x4){0.f, 0.f, 0.f, 0.f};

    for (int k0 = 0; k0 < 512; k0 += 32) {
        __syncthreads();
#pragma unroll
        for (int q = 0; q < 2; ++q) {
            int c = t + q * 256;
            int row = c >> 2, ko = (c & 3) * 8;
            *reinterpret_cast<uint4*>(&AsH[row][ko]) =
                *reinterpret_cast<const uint4*>(&AH[(size_t)(i0 + row) * 512 + k0 + ko]);
            *reinterpret_cast<uint4*>(&AsL[row][ko]) =
                *reinterpret_cast<const uint4*>(&AL[(size_t)(i0 + row) * 512 + k0 + ko]);
            *reinterpret_cast<uint4*>(&BsH[row][ko]) =
                *reinterpret_cast<const uint4*>(&BH[(size_t)(j0 + row) * 512 + k0 + ko]);
            *reinterpret_cast<uint4*>(&BsL[row][ko]) =
                *reinterpret_cast<const uint4*>(&BL[(size_t)(j0 + row) * 512 + k0 + ko]);
        }
        __syncthreads();

        bf16x8 aH[4], aL[4], bH[4], bL[4];
#pragma unroll
        for (int mi = 0; mi < 4; ++mi) {
            int ar = wy * 64 + mi * 16 + lc;
            aH[mi] = *reinterpret_cast<const bf16x8*>(&AsH[ar][kg * 8]);
            aL[mi] = *reinterpret_cast<const bf16x8*>(&AsL[ar][kg * 8]);
        }
#pragma unroll
        for (int ni = 0; ni < 4; ++ni) {
            int br = wx * 64 + ni * 16 + lc;
            bH[ni] = *reinterpret_cast<const bf16x8*>(&BsH[br][kg * 8]);
            bL[ni] = *reinterpret_cast<const bf16x8*>(&BsL[br][kg * 8]);
        }
#pragma unroll
        for (int mi = 0; mi < 4; ++mi)
#pragma unroll
            for (int ni = 0; ni < 4; ++ni) {
                acc[mi][ni] = __builtin_amdgcn_mfma_f32_16x16x32_bf16(aH[mi], bH[ni], acc[mi][ni], 0, 0, 0);
                acc[mi][ni] = __builtin_amdgcn_mfma_f32_16x16x32_bf16(aH[mi], bL[ni], acc[mi][ni], 0, 0, 0);
                acc[mi][ni] = __builtin_amdgcn_mfma_f32_16x16x32_bf16(aL[mi], bH[ni], acc[mi][ni], 0, 0, 0);
            }
    }

    float pmax[4], psum[4];
#pragma unroll
    for (int ni = 0; ni < 4; ++ni) {
        int j = j0 + wx * 64 + ni * 16 + lc;
        float s = g[j] * rsqrtf(var[j] + 1e-5f);
        float sh = be[j] - mu[j] * s;
        float pm = -BIGF, ps = 0.f;
#pragma unroll
        for (int mi = 0; mi < 4; ++mi)
#pragma unroll
            for (int r = 0; r < 4; ++r) {
                float y = fmaf(acc[mi][ni][r], s, sh);
                y = (y >= 0.f) ? y : 0.2f * y;
                pm = fmaxf(pm, y);
                ps += y;
            }
        pmax[ni] = pm; psum[ni] = ps;
    }
#pragma unroll
    for (int ni = 0; ni < 4; ++ni) {
        pmax[ni] = fmaxf(pmax[ni], __shfl_xor(pmax[ni], 16, 64));
        pmax[ni] = fmaxf(pmax[ni], __shfl_xor(pmax[ni], 32, 64));
        psum[ni] += __shfl_xor(psum[ni], 16, 64);
        psum[ni] += __shfl_xor(psum[ni], 32, 64);
    }
    if (lane < 16) {
#pragma unroll
        for (int ni = 0; ni < 4; ++ni) {
            redm[wid][ni * 16 + lc] = pmax[ni];
            reds[wid][ni * 16 + lc] = psum[ni];
        }
    }
    __syncthreads();
    if (t < 128) {
        int wxq = t >> 6, cl = t & 63;
        float m = fmaxf(redm[wxq][cl], redm[2 + wxq][cl]);
        float sv = reds[wxq][cl] + reds[2 + wxq][cl];
        int b = i0 >> 11, rb = (i0 & 2047) >> 7;
        partmax[((size_t)b * 16 + rb) * 1024 + j0 + t] = m;
        partsum[((size_t)b * 16 + rb) * 1024 + j0 + t] = sv;
    }
}

// ======================= pooling reduce =======================
__global__ __launch_bounds__(256) void pool2_kernel(const float* __restrict__ partmax,
                                                    const float* __restrict__ partsum,
                                                    float* __restrict__ pooled)
{
    const int c = blockIdx.x * 256 + threadIdx.x;
    const int b = blockIdx.y;
    float m = -BIGF, s = 0.f;
    for (int rb = 0; rb < 16; ++rb) {
        m = fmaxf(m, partmax[((size_t)b * 16 + rb) * 1024 + c]);
        s += partsum[((size_t)b * 16 + rb) * 1024 + c];
    }
    pooled[(size_t)b * 2048 + c] = m;
    pooled[(size_t)b * 2048 + 1024 + c] = s * (1.f / 2048.f);
}

// ======================= tail FCs (split-K) =======================
__global__ __launch_bounds__(512) void fc1_partial(const float* __restrict__ pooled,
                                                   const float* __restrict__ Wa,
                                                   float* __restrict__ part)
{
    const int kk = blockIdx.x, b = blockIdx.y, c = threadIdx.x;
    __shared__ float sp[128];
    if (c < 128) sp[c] = pooled[(size_t)b * 2048 + kk * 128 + c];
    __syncthreads();
    const float* w = Wa + (size_t)kk * 128 * 512 + c;
    float acc = 0.f;
#pragma unroll 8
    for (int j = 0; j < 128; ++j) acc = fmaf(sp[j], w[(size_t)j * 512], acc);
    part[((size_t)b * 16 + kk) * 512 + c] = acc;
}

__global__ __launch_bounds__(512) void fc1_reduce(const float* __restrict__ part,
                                                  const float* __restrict__ g, const float* __restrict__ be,
                                                  const float* __restrict__ mu, const float* __restrict__ var,
                                                  float* __restrict__ t1)
{
    const int b = blockIdx.x, c = threadIdx.x;
    float acc = 0.f;
#pragma unroll
    for (int kk = 0; kk < 16; ++kk) acc += part[((size_t)b * 16 + kk) * 512 + c];
    float s = g[c] * rsqrtf(var[c] + 1e-5f);
    float y = acc * s + (be[c] - mu[c] * s);
    t1[(size_t)b * 512 + c] = (y >= 0.f) ? y : 0.2f * y;
}

__global__ __launch_bounds__(256) void fc2_partial(const float* __restrict__ t1,
                                                   const float* __restrict__ Wb,
                                                   float* __restrict__ part)
{
    const int kk = blockIdx.x, b = blockIdx.y, c = threadIdx.x;
    __shared__ float sp[128];
    if (c < 128) sp[c] = t1[(size_t)b * 512 + kk * 128 + c];
    __syncthreads();
    const float* w = Wb + (size_t)kk * 128 * 256 + c;
    float acc = 0.f;
#pragma unroll 8
    for (int j = 0; j < 128; ++j) acc = fmaf(sp[j], w[(size_t)j * 256], acc);
    part[((size_t)b * 4 + kk) * 256 + c] = acc;
}

__global__ __launch_bounds__(256) void fc2_reduce(const float* __restrict__ part,
                                                  const float* __restrict__ bias_b,
                                                  const float* __restrict__ g, const float* __restrict__ be,
                                                  const float* __restrict__ mu, const float* __restrict__ var,
                                                  float* __restrict__ t2)
{
    const int b = blockIdx.x, c = threadIdx.x;
    float acc = bias_b[c];
#pragma unroll
    for (int kk = 0; kk < 4; ++kk) acc += part[((size_t)b * 4 + kk) * 256 + c];
    float s = g[c] * rsqrtf(var[c] + 1e-5f);
    float y = acc * s + (be[c] - mu[c] * s);
    t2[(size_t)b * 256 + c] = (y >= 0.f) ? y : 0.2f * y;
}

__global__ __launch_bounds__(64) void fc3_kernel(const float* __restrict__ t2,
                                                 const float* __restrict__ Wc,
                                                 const float* __restrict__ bias_c,
                                                 float* __restrict__ out)
{
    const int b = blockIdx.x, c = threadIdx.x;
    __shared__ float sp[256];
    for (int k = c; k < 256; k += 64) sp[k] = t2[(size_t)b * 256 + k];
    __syncthreads();
    if (c < 40) {
        float acc = 0.f;
#pragma unroll 8
        for (int k = 0; k < 256; ++k) acc = fmaf(sp[k], Wc[(size_t)k * 40 + c], acc);
        out[(size_t)b * 40 + c] = acc + bias_c[c];
    }
}

// ======================= launch =======================
extern "C" void kernel_launch(void* const* d_in, const int* in_sizes, int n_in,
                              void* d_out, int out_size, void* d_ws, size_t ws_size,
                              hipStream_t stream)
{
    const float* pos = (const float*)d_in[0];
    const float* W1 = (const float*)d_in[1];
    const float* g1 = (const float*)d_in[2];  const float* be1 = (const float*)d_in[3];
    const float* mu1 = (const float*)d_in[4]; const float* va1 = (const float*)d_in[5];
    const float* W2 = (const float*)d_in[6];
    const float* g2 = (const float*)d_in[7];  const float* be2 = (const float*)d_in[8];
    const float* mu2 = (const float*)d_in[9]; const float* va2 = (const float*)d_in[10];
    const float* W3 = (const float*)d_in[11];
    const float* g3 = (const float*)d_in[12]; const float* be3 = (const float*)d_in[13];
    const float* mu3 = (const float*)d_in[14];const float* va3 = (const float*)d_in[15];
    const float* W4 = (const float*)d_in[16];
    const float* g4 = (const float*)d_in[17]; const float* be4 = (const float*)d_in[18];
    const float* mu4 = (const float*)d_in[19];const float* va4 = (const float*)d_in[20];
    const float* Wm = (const float*)d_in[21];
    const float* gm = (const float*)d_in[22]; const float* bem = (const float*)d_in[23];
    const float* mum = (const float*)d_in[24];const float* vam = (const float*)d_in[25];
    const float* Wa = (const float*)d_in[26];
    const float* ga = (const float*)d_in[27]; const float* bea = (const float*)d_in[28];
    const float* mua = (const float*)d_in[29];const float* vaa = (const float*)d_in[30];
    const float* Wb = (const float*)d_in[31];
    const float* gb = (const float*)d_in[32]; const float* beb = (const float*)d_in[33];
    const float* mub = (const float*)d_in[34];const float* vab = (const float*)d_in[35];
    const float* bias_b = (const float*)d_in[36];
    const float* Wc = (const float*)d_in[37];
    const float* bias_c = (const float*)d_in[38];

    char* ws = (char*)d_ws;
    size_t off = 0;
    auto alloc = [&](size_t bytes) -> void* {
        void* p = ws + off;
        off += (bytes + 255) & ~(size_t)255;
        return p;
    };
    float* xcat    = (float*)alloc((size_t)16384 * 512 * 4);
    float* sq      = (float*)alloc((size_t)16384 * 4);
    int*   idx     = (int*)  alloc((size_t)16384 * KNN * 4);
    float* apart   = (float*)alloc((size_t)16384 * 256 * 4);
    float* bpart   = (float*)alloc((size_t)16384 * 256 * 4);
    float* partmax = (float*)alloc((size_t)8 * 16 * 1024 * 4);
    float* partsum = (float*)alloc((size_t)8 * 16 * 1024 * 4);
    float* pooled  = (float*)alloc((size_t)8 * 2048 * 4);
    float* t1      = (float*)alloc((size_t)8 * 512 * 4);
    float* t2      = (float*)alloc((size_t)8 * 256 * 4);
    float* part1   = (float*)alloc((size_t)8 * 16 * 512 * 4);
    float* part2   = (float*)alloc((size_t)8 * 4 * 256 * 4);
    unsigned short* ah   = (unsigned short*)alloc((size_t)16384 * 512 * 2);
    unsigned short* al   = (unsigned short*)alloc((size_t)16384 * 512 * 2);
    unsigned short* wmtH = (unsigned short*)alloc((size_t)1024 * 512 * 2);
    unsigned short* wmtL = (unsigned short*)alloc((size_t)1024 * 512 * 2);
    const size_t fixed = off;
    const size_t per_b = (size_t)NPTS * NPTS * 4;

    // CB=4 preferred: 67MB key chunk stays Infinity-Cache-resident between distk and select.
    int CB; uint32_t* d2k;
    if      (ws_size >= fixed + 4 * per_b) { CB = 4; d2k = (uint32_t*)(ws + fixed); }
    else if (ws_size >= fixed + 2 * per_b) { CB = 2; d2k = (uint32_t*)(ws + fixed); }
    else { CB = 2; d2k = (uint32_t*)apart; }  // apart+bpart contiguous, dead during dist/select

    struct LayerDesc {
        const float* xin; int lda; int F; int Fout;
        float* xout; const float* W;
        const float* g; const float* be; const float* mu; const float* va;
    };
    LayerDesc Ls[4] = {
        { pos,        3,   3,   64,  xcat + 0,   W1, g1, be1, mu1, va1 },
        { xcat + 0,   512, 64,  64,  xcat + 64,  W2, g2, be2, mu2, va2 },
        { xcat + 64,  512, 64,  128, xcat + 128, W3, g3, be3, mu3, va3 },
        { xcat + 128, 512, 128, 256, xcat + 256, W4, g4, be4, mu4, va4 },
    };

    for (int L = 0; L < 4; ++L) {
        const LayerDesc& ld = Ls[L];
        sq_kernel<<<64, 256, 0, stream>>>(ld.xin, ld.lda, ld.F, sq);
        for (int b0 = 0; b0 < BATCH; b0 += CB) {
            int cb = (BATCH - b0 < CB) ? (BATCH - b0) : CB;
            distk_kernel<<<dim3(16, 16, cb), 256, 0, stream>>>(ld.xin, ld.lda, sq, d2k, ld.F, b0);
            select_kernel<<<512 * cb, 256, 0, stream>>>(d2k, idx, b0);
        }
        gemm64_kernel<<<dim3(256, ld.Fout / 64, 2), 256, 0, stream>>>(
            ld.xin, ld.lda, ld.F, ld.W, ld.Fout, apart, bpart);
        if (ld.Fout == 64)
            aggregate_kernel<64><<<1024, 256, 0, stream>>>(apart, bpart, idx,
                ld.g, ld.be, ld.mu, ld.va, ld.xout);
        else if (ld.Fout == 128)
            aggregate_kernel<128><<<2048, 256, 0, stream>>>(apart, bpart, idx,
                ld.g, ld.be, ld.mu, ld.va, ld.xout);
        else
            aggregate_kernel<256><<<4096, 256, 0, stream>>>(apart, bpart, idx,
                ld.g, ld.be, ld.mu, ld.va, ld.xout);
    }

    cvt_kernel<<<4096, 256, 0, stream>>>(xcat, ah, al);
    cvtT_kernel<<<dim3(32, 16), 256, 0, stream>>>(Wm, wmtH, wmtL);
    wm_mfma_pool<<<dim3(128, 8), 256, 0, stream>>>(ah, al, wmtH, wmtL,
                                                   gm, bem, mum, vam, partmax, partsum);
    pool2_kernel<<<dim3(4, 8), 256, 0, stream>>>(partmax, partsum, pooled);
    fc1_partial<<<dim3(16, 8), 512, 0, stream>>>(pooled, Wa, part1);
    fc1_reduce<<<8, 512, 0, stream>>>(part1, ga, bea, mua, vaa, t1);
    fc2_partial<<<dim3(4, 8), 256, 0, stream>>>(t1, Wb, part2);
    fc2_reduce<<<8, 256, 0, stream>>>(part2, bias_b, gb, beb, mub, vab, t2);
    fc3_kernel<<<8, 64, 0, stream>>>(t2, Wc, bias_c, (float*)d_out);
}

// Round 10
// 856.735 us; speedup vs baseline: 4.8778x; 1.1696x over previous
//
#include <hip/hip_runtime.h>
#include <cstdint>
#include <cstddef>

#define NPTS 2048
#define BATCH 8
#define KNN 20
#define BIGF 3.402823466e38f

typedef short bf16x8 __attribute__((ext_vector_type(8)));
typedef float f32x4 __attribute__((ext_vector_type(4)));

__device__ __forceinline__ unsigned short f2bf(float v) {
    uint32_t u = __float_as_uint(v);
    uint32_t r = (u + 0x7FFFu + ((u >> 16) & 1u)) >> 16;
    return (unsigned short)r;
}
__device__ __forceinline__ float bf2f(unsigned short h) {
    return __uint_as_float(((uint32_t)h) << 16);
}
__device__ __forceinline__ uint32_t flipkey(float d) {
    uint32_t u = __float_as_uint(d);
    return (u & 0x80000000u) ? ~u : (u | 0x80000000u);
}
// exact d2 key: combine MUST be identical in distk and select-recompute
__device__ __forceinline__ uint32_t d2key(float acc, float si, float sj) {
    return flipkey(fmaf(-2.f, acc, si + sj));
}
__device__ __forceinline__ uint64_t shfl_xor_u64(uint64_t v, int m) {
    int lo = __shfl_xor((int)(uint32_t)v, m, 64);
    int hi = __shfl_xor((int)(uint32_t)(v >> 32), m, 64);
    return ((uint64_t)(uint32_t)hi << 32) | (uint32_t)lo;
}

// ======================= sum of squares per point =======================
__global__ __launch_bounds__(256) void sq_kernel(const float* __restrict__ x, int lda, int F,
                                                 float* __restrict__ sq)
{
    int p = blockIdx.x * 256 + threadIdx.x;   // 0..16383
    const float* xp = x + (size_t)p * lda;
    float s = 0.f;
    for (int f = 0; f < F; ++f) { float v = xp[f]; s = fmaf(v, v, s); }
    sq[p] = s;
}

// ======================= pairwise distance GEMM -> u16 truncated keys =======================
// Writes top-16 bits of the order-preserving flip-key (monotone truncation).
// fmaf order identical to R5's dist; combine via d2key() shared with select's recompute.
__global__ __launch_bounds__(256) void distk_kernel(const float* __restrict__ x, int lda,
                                                    const float* __restrict__ sq,
                                                    unsigned short* __restrict__ d2u16,
                                                    int F, int b0)
{
    __shared__ __align__(16) float As[8][132];
    __shared__ __align__(16) float Bs[8][132];
    const int b  = b0 + blockIdx.z;
    const int i0 = blockIdx.x * 128;
    const int j0 = blockIdx.y * 128;
    const float* xb  = x + (size_t)b * NPTS * lda;
    const float* sqb = sq + (size_t)b * NPTS;
    const int t  = threadIdx.x;
    const int tx = t & 15, ty = t >> 4;
    const int lrow = t >> 1, lkq = (t & 1) * 4;

    float acc[8][8];
#pragma unroll
    for (int r = 0; r < 8; ++r)
#pragma unroll
        for (int c = 0; c < 8; ++c) acc[r][c] = 0.f;

    for (int k0 = 0; k0 < F; k0 += 8) {
        const float* sa = xb + (size_t)(i0 + lrow) * lda + k0 + lkq;
        const float* sb = xb + (size_t)(j0 + lrow) * lda + k0 + lkq;
        if (k0 + 8 <= F) {
            float4 a4 = *reinterpret_cast<const float4*>(sa);
            float4 b4 = *reinterpret_cast<const float4*>(sb);
            As[lkq + 0][lrow] = a4.x; As[lkq + 1][lrow] = a4.y;
            As[lkq + 2][lrow] = a4.z; As[lkq + 3][lrow] = a4.w;
            Bs[lkq + 0][lrow] = b4.x; Bs[lkq + 1][lrow] = b4.y;
            Bs[lkq + 2][lrow] = b4.z; Bs[lkq + 3][lrow] = b4.w;
        } else {
#pragma unroll
            for (int q = 0; q < 4; ++q) {
                int kk = k0 + lkq + q;
                As[lkq + q][lrow] = (kk < F) ? sa[q] : 0.f;
                Bs[lkq + q][lrow] = (kk < F) ? sb[q] : 0.f;
            }
        }
        __syncthreads();
#pragma unroll
        for (int k = 0; k < 8; ++k) {
            float4 a0 = *reinterpret_cast<const float4*>(&As[k][ty * 4]);
            float4 a1 = *reinterpret_cast<const float4*>(&As[k][64 + ty * 4]);
            float4 c0 = *reinterpret_cast<const float4*>(&Bs[k][tx * 4]);
            float4 c1 = *reinterpret_cast<const float4*>(&Bs[k][64 + tx * 4]);
            float av[8] = {a0.x, a0.y, a0.z, a0.w, a1.x, a1.y, a1.z, a1.w};
            float bv[8] = {c0.x, c0.y, c0.z, c0.w, c1.x, c1.y, c1.z, c1.w};
#pragma unroll
            for (int r = 0; r < 8; ++r)
#pragma unroll
                for (int c = 0; c < 8; ++c) acc[r][c] = fmaf(av[r], bv[c], acc[r][c]);
        }
        __syncthreads();
    }

    unsigned short* db = d2u16 + (size_t)blockIdx.z * NPTS * NPTS;
#pragma unroll
    for (int r = 0; r < 8; ++r) {
        int i = i0 + ((r < 4) ? (ty * 4 + r) : (64 + ty * 4 + r - 4));
        float si = sqb[i];
#pragma unroll
        for (int cq = 0; cq < 2; ++cq) {
            int j = j0 + (cq ? 64 : 0) + tx * 4;
            ushort4 o;
            o.x = (unsigned short)(d2key(acc[r][cq * 4 + 0], si, sqb[j + 0]) >> 16);
            o.y = (unsigned short)(d2key(acc[r][cq * 4 + 1], si, sqb[j + 1]) >> 16);
            o.z = (unsigned short)(d2key(acc[r][cq * 4 + 2], si, sqb[j + 2]) >> 16);
            o.w = (unsigned short)(d2key(acc[r][cq * 4 + 3], si, sqb[j + 3]) >> 16);
            *reinterpret_cast<ushort4*>(&db[(size_t)i * NPTS + j]) = o;
        }
    }
}

// ======================= top-20 from u16 keys + exact tie re-rank =======================
// One wave per row. Top-20 by (key16, j) via register sorted top-4 + wave-min extraction.
// Keys < thr16 are certainly in the true set (monotone truncation). Ties at thr16 are
// re-ranked by exact f32 d2 (identical fmaf chain) when needed.
template <int F>
__global__ __launch_bounds__(256) void select_kernel(const unsigned short* __restrict__ d2u16,
                                                     const float* __restrict__ x, int lda,
                                                     const float* __restrict__ sq,
                                                     int* __restrict__ idx, int b0)
{
    const int t    = threadIdx.x;
    const int lane = t & 63;
    const int wid  = t >> 6;
    const int row_id = blockIdx.x * 4 + wid;
    const int bz = row_id >> 11;
    const int i  = row_id & 2047;
    const unsigned short* row = d2u16 + ((size_t)bz * NPTS + i) * NPTS;

    uint32_t cand[32];
#pragma unroll
    for (int s = 0; s < 4; ++s) {
        uint4 kv = *reinterpret_cast<const uint4*>(&row[s * 512 + lane * 8]);
        uint32_t cb = (uint32_t)(s * 512 + lane * 8);
        cand[s * 8 + 0] = ((kv.x & 0xFFFFu) << 16) | (cb + 0);
        cand[s * 8 + 1] = (kv.x & 0xFFFF0000u)      | (cb + 1);
        cand[s * 8 + 2] = ((kv.y & 0xFFFFu) << 16) | (cb + 2);
        cand[s * 8 + 3] = (kv.y & 0xFFFF0000u)      | (cb + 3);
        cand[s * 8 + 4] = ((kv.z & 0xFFFFu) << 16) | (cb + 4);
        cand[s * 8 + 5] = (kv.z & 0xFFFF0000u)      | (cb + 5);
        cand[s * 8 + 6] = ((kv.w & 0xFFFFu) << 16) | (cb + 6);
        cand[s * 8 + 7] = (kv.w & 0xFFFF0000u)      | (cb + 7);
    }

    const uint32_t MAXV = 0xFFFFFFFFu;
    uint32_t t1 = MAXV, t2 = MAXV, t3 = MAXV, t4 = MAXV;
#pragma unroll
    for (int s = 0; s < 32; ++s) {
        uint32_t c = cand[s];
        if (c < t4) {
            if (c < t2) {
                t4 = t3; t3 = t2;
                if (c < t1) { t2 = t1; t1 = c; } else t2 = c;
            } else {
                if (c < t3) { t4 = t3; t3 = c; } else t4 = c;
            }
        }
    }

    uint32_t keep = 0, last = 0;
    for (int it = 0; it < KNN; ++it) {
        uint32_t w = t1;
#pragma unroll
        for (int o = 1; o < 64; o <<= 1)
            w = min(w, (uint32_t)__shfl_xor((int)w, o, 64));
        keep = (lane == it) ? w : keep;
        last = w;
        if (t1 == w) {
            t1 = t2; t2 = t3; t3 = t4; t4 = MAXV;
            if (t1 == MAXV) {          // rare refill
#pragma unroll
                for (int s = 0; s < 32; ++s) {
                    uint32_t c = cand[s];
                    if (c > w && c < t4) {
                        if (c < t2) {
                            t4 = t3; t3 = t2;
                            if (c < t1) { t2 = t1; t1 = c; } else t2 = c;
                        } else {
                            if (c < t3) { t4 = t3; t3 = c; } else t4 = c;
                        }
                    }
                }
            }
        }
    }

    int* out = idx + ((size_t)(b0 + bz) * NPTS + i) * KNN;
    const uint32_t thr16 = last >> 16;

    int cnt = 0;
#pragma unroll
    for (int s = 0; s < 32; ++s) cnt += ((cand[s] >> 16) == thr16) ? 1 : 0;
#pragma unroll
    for (int o = 1; o < 64; o <<= 1) cnt += __shfl_xor(cnt, o, 64);

    unsigned long long bm = __ballot(lane < KNN && (keep >> 16) < thr16);
    const int sel_lt = (int)__popcll(bm);
    const int m = KNN - sel_lt;
    const bool fast = (cnt == m);

    if (lane < KNN && (fast || (keep >> 16) < thr16))
        out[lane] = (int)(keep & 0xFFFFu);
    if (fast) return;

    // exact re-rank of the tie bucket
    const float* xb  = x + (size_t)(b0 + bz) * NPTS * lda;
    const float* sqb = sq + (size_t)(b0 + bz) * NPTS;
    const float si = sqb[i];
    const float* xi = xb + (size_t)i * lda;

    uint64_t tc[4]; int ntc = 0; bool ovf = false;
#pragma unroll
    for (int s = 0; s < 32; ++s) {
        if ((cand[s] >> 16) == thr16) {
            if (ntc < 4) {
                int j = (int)(cand[s] & 0xFFFFu);
                const float* xj = xb + (size_t)j * lda;
                float dot = 0.f;
#pragma unroll
                for (int k = 0; k < F; ++k) dot = fmaf(xi[k], xj[k], dot);
                uint32_t fk = d2key(dot, si, sqb[j]);
                tc[ntc++] = ((uint64_t)fk << 32) | (uint32_t)j;
            } else ovf = true;
        }
    }
    if (__ballot(ovf)) {               // pathological: recompute inline per iteration
        uint64_t last_ex = 0;
        for (int q = 0; q < m; ++q) {
            uint64_t lm = ~0ull;
            for (int s = 0; s < 32; ++s) {
                if ((cand[s] >> 16) == thr16) {
                    int j = (int)(cand[s] & 0xFFFFu);
                    const float* xj = xb + (size_t)j * lda;
                    float dot = 0.f;
                    for (int k = 0; k < F; ++k) dot = fmaf(xi[k], xj[k], dot);
                    uint64_t e = ((uint64_t)d2key(dot, si, sqb[j]) << 32) | (uint32_t)j;
                    if (e > last_ex && e < lm) lm = e;
                }
            }
#pragma unroll
            for (int o = 1; o < 64; o <<= 1) {
                uint64_t ov = shfl_xor_u64(lm, o);
                lm = (ov < lm) ? ov : lm;
            }
            if (lane == 0) out[sel_lt + q] = (int)(lm & 0xFFFFu);
            last_ex = lm;
        }
        return;
    }
    uint64_t last_ex = 0;
    for (int q = 0; q < m; ++q) {
        uint64_t lm = ~0ull;
#pragma unroll
        for (int u = 0; u < 4; ++u)
            if (u < ntc && tc[u] > last_ex && tc[u] < lm) lm = tc[u];
#pragma unroll
        for (int o = 1; o < 64; o <<= 1) {
            uint64_t ov = shfl_xor_u64(lm, o);
            lm = (ov < lm) ? ov : lm;
        }
        if (lane == 0) out[sel_lt + q] = (int)(lm & 0xFFFFu);
        last_ex = lm;
    }
}

// ======================= dual small GEMM: apart & bpart in one dispatch =======================
// As stride 68 (write pattern exact 2-way = free); Bs stays 65 (2-way on both sides).
__global__ __launch_bounds__(256) void gemm64_kernel(const float* __restrict__ A, int lda, int F,
                                                     const float* __restrict__ Wfull, int Fout,
                                                     float* __restrict__ apart,
                                                     float* __restrict__ bpart)
{
    __shared__ float As[16][68];
    __shared__ float Bs[16][65];
    const int i0 = blockIdx.x * 64, j0 = blockIdx.y * 64;
    const int half = blockIdx.z;
    const float* Bw = Wfull + (size_t)(half ? F : 0) * Fout;
    float* C = half ? bpart : apart;
    const int t = threadIdx.x, tx = t & 15, ty = t >> 4;
    float acc[4][4];
#pragma unroll
    for (int r = 0; r < 4; ++r)
#pragma unroll
        for (int c = 0; c < 4; ++c) acc[r][c] = 0.f;
    const int arow = t >> 2, akq = (t & 3) * 4;
    const int bk = t >> 4, bj = (t & 15) * 4;
    for (int k0 = 0; k0 < F; k0 += 16) {
#pragma unroll
        for (int q = 0; q < 4; ++q) {
            int kk = k0 + akq + q;
            As[akq + q][arow] = (kk < F) ? A[(size_t)(i0 + arow) * lda + kk] : 0.f;
        }
        {
            int kk = k0 + bk;
#pragma unroll
            for (int q = 0; q < 4; ++q)
                Bs[bk][bj + q] = (kk < F) ? Bw[(size_t)kk * Fout + j0 + bj + q] : 0.f;
        }
        __syncthreads();
#pragma unroll
        for (int k = 0; k < 16; ++k) {
            float a[4], bb[4];
#pragma unroll
            for (int r = 0; r < 4; ++r) a[r] = As[k][ty * 4 + r];
#pragma unroll
            for (int c = 0; c < 4; ++c) bb[c] = Bs[k][tx * 4 + c];
#pragma unroll
            for (int r = 0; r < 4; ++r)
#pragma unroll
                for (int c = 0; c < 4; ++c) acc[r][c] = fmaf(a[r], bb[c], acc[r][c]);
        }
        __syncthreads();
    }
#pragma unroll
    for (int r = 0; r < 4; ++r)
#pragma unroll
        for (int c = 0; c < 4; ++c)
            C[(size_t)(i0 + ty * 4 + r) * Fout + j0 + tx * 4 + c] = acc[r][c];
}

// ======================= EdgeConv aggregate (float4 lanes, multi-point blocks) =======================
template <int FOUT>
__global__ __launch_bounds__(256) void aggregate_kernel(const float* __restrict__ apart,
                                                        const float* __restrict__ bpart,
                                                        const int* __restrict__ idx,
                                                        const float* __restrict__ g,
                                                        const float* __restrict__ be,
                                                        const float* __restrict__ mu,
                                                        const float* __restrict__ var,
                                                        float* __restrict__ out)
{
    constexpr int G   = FOUT / 4;
    constexpr int PPB = 256 / G;
    const int t  = threadIdx.x;
    const int pi = t / G;
    const int fi = t % G;
    const int p  = blockIdx.x * PPB + pi;
    const int b  = p >> 11;
    const int* nb = idx + (size_t)p * KNN;
    const float4* bp4 = reinterpret_cast<const float4*>(bpart);
    const float4* bb  = bp4 + ((size_t)b << 11) * G;

    float4 m = {-BIGF, -BIGF, -BIGF, -BIGF};
#pragma unroll 4
    for (int k = 0; k < KNN; ++k) {
        int j = nb[k];
        float4 v = bb[(size_t)j * G + fi];
        m.x = fmaxf(m.x, v.x); m.y = fmaxf(m.y, v.y);
        m.z = fmaxf(m.z, v.z); m.w = fmaxf(m.w, v.w);
    }
    float4 av = reinterpret_cast<const float4*>(apart)[(size_t)p * G + fi];
    float4 bv = bp4[(size_t)p * G + fi];
    float4 gg = reinterpret_cast<const float4*>(g)[fi];
    float4 bee = reinterpret_cast<const float4*>(be)[fi];
    float4 muu = reinterpret_cast<const float4*>(mu)[fi];
    float4 vaa = reinterpret_cast<const float4*>(var)[fi];

    float4 r;
    {
        float s, sh, vv, y;
        s = gg.x * rsqrtf(vaa.x + 1e-5f); sh = bee.x - muu.x * s;
        vv = av.x - bv.x + m.x; y = vv * s + sh; r.x = (y >= 0.f) ? y : 0.2f * y;
        s = gg.y * rsqrtf(vaa.y + 1e-5f); sh = bee.y - muu.y * s;
        vv = av.y - bv.y + m.y; y = vv * s + sh; r.y = (y >= 0.f) ? y : 0.2f * y;
        s = gg.z * rsqrtf(vaa.z + 1e-5f); sh = bee.z - muu.z * s;
        vv = av.z - bv.z + m.z; y = vv * s + sh; r.z = (y >= 0.f) ? y : 0.2f * y;
        s = gg.w * rsqrtf(vaa.w + 1e-5f); sh = bee.w - muu.w * s;
        vv = av.w - bv.w + m.w; y = vv * s + sh; r.w = (y >= 0.f) ? y : 0.2f * y;
    }
    *reinterpret_cast<float4*>(out + (size_t)p * 512 + fi * 4) = r;
}

// ======================= split-bf16 converters =======================
__global__ __launch_bounds__(256) void cvt_kernel(const float* __restrict__ in,
                                                  unsigned short* __restrict__ hi,
                                                  unsigned short* __restrict__ lo)
{
    int i = blockIdx.x * 256 + threadIdx.x;
    const float4* p = reinterpret_cast<const float4*>(in) + (size_t)i * 2;
    float4 a = p[0], b = p[1];
    float v[8] = {a.x, a.y, a.z, a.w, b.x, b.y, b.z, b.w};
    uint32_t h[8], l[8];
#pragma unroll
    for (int q = 0; q < 8; ++q) {
        unsigned short hb = f2bf(v[q]);
        h[q] = hb;
        l[q] = f2bf(v[q] - bf2f(hb));
    }
    uint4 uh, ul;
    uh.x = h[0] | (h[1] << 16); uh.y = h[2] | (h[3] << 16);
    uh.z = h[4] | (h[5] << 16); uh.w = h[6] | (h[7] << 16);
    ul.x = l[0] | (l[1] << 16); ul.y = l[2] | (l[3] << 16);
    ul.z = l[4] | (l[5] << 16); ul.w = l[6] | (l[7] << 16);
    reinterpret_cast<uint4*>(hi)[i] = uh;
    reinterpret_cast<uint4*>(lo)[i] = ul;
}

__global__ __launch_bounds__(256) void cvtT_kernel(const float* __restrict__ Wm,
                                                   unsigned short* __restrict__ hiT,
                                                   unsigned short* __restrict__ loT)
{
    __shared__ float tile[32][33];
    const int n0 = blockIdx.x * 32;
    const int k0 = blockIdx.y * 32;
    const int t = threadIdx.x;
    const int c = t & 31, r = t >> 5;
#pragma unroll
    for (int rr = 0; rr < 4; ++rr)
        tile[r + rr * 8][c] = Wm[(size_t)(k0 + r + rr * 8) * 1024 + n0 + c];
    __syncthreads();
#pragma unroll
    for (int rr = 0; rr < 4; ++rr) {
        int nn = r + rr * 8, kk = c;
        float v = tile[kk][nn];
        unsigned short hb = f2bf(v);
        hiT[(size_t)(n0 + nn) * 512 + k0 + kk] = hb;
        loT[(size_t)(n0 + nn) * 512 + k0 + kk] = f2bf(v - bf2f(hb));
    }
}

// ======================= Wm via split-bf16 MFMA + BN + lrelu + pooling =======================
__global__ __launch_bounds__(256) void wm_mfma_pool(const unsigned short* __restrict__ AH,
                                                    const unsigned short* __restrict__ AL,
                                                    const unsigned short* __restrict__ BH,
                                                    const unsigned short* __restrict__ BL,
                                                    const float* __restrict__ g,
                                                    const float* __restrict__ be,
                                                    const float* __restrict__ mu,
                                                    const float* __restrict__ var,
                                                    float* __restrict__ partmax,
                                                    float* __restrict__ partsum)
{
    __shared__ unsigned short AsH[128][40], AsL[128][40], BsH[128][40], BsL[128][40];
    __shared__ float redm[4][64], reds[4][64];
    const int t = threadIdx.x;
    const int i0 = blockIdx.x * 128, j0 = blockIdx.y * 128;
    const int lane = t & 63, wid = t >> 6, wy = wid >> 1, wx = wid & 1;
    const int lc = lane & 15, kg = lane >> 4;

    f32x4 acc[4][4];
#pragma unroll
    for (int mi = 0; mi < 4; ++mi)
#pragma unroll
        for (int ni = 0; ni < 4; ++ni) acc[mi][ni] = (f32x4){0.f, 0.f, 0.f, 0.f};

    for (int k0 = 0; k0 < 512; k0 += 32) {
        __syncthreads();
#pragma unroll
        for (int q = 0; q < 2; ++q) {
            int c = t + q * 256;
            int row = c >> 2, ko = (c & 3) * 8;
            *reinterpret_cast<uint4*>(&AsH[row][ko]) =
                *reinterpret_cast<const uint4*>(&AH[(size_t)(i0 + row) * 512 + k0 + ko]);
            *reinterpret_cast<uint4*>(&AsL[row][ko]) =
                *reinterpret_cast<const uint4*>(&AL[(size_t)(i0 + row) * 512 + k0 + ko]);
            *reinterpret_cast<uint4*>(&BsH[row][ko]) =
                *reinterpret_cast<const uint4*>(&BH[(size_t)(j0 + row) * 512 + k0 + ko]);
            *reinterpret_cast<uint4*>(&BsL[row][ko]) =
                *reinterpret_cast<const uint4*>(&BL[(size_t)(j0 + row) * 512 + k0 + ko]);
        }
        __syncthreads();

        bf16x8 aH[4], aL[4], bH[4], bL[4];
#pragma unroll
        for (int mi = 0; mi < 4; ++mi) {
            int ar = wy * 64 + mi * 16 + lc;
            aH[mi] = *reinterpret_cast<const bf16x8*>(&AsH[ar][kg * 8]);
            aL[mi] = *reinterpret_cast<const bf16x8*>(&AsL[ar][kg * 8]);
        }
#pragma unroll
        for (int ni = 0; ni < 4; ++ni) {
            int br = wx * 64 + ni * 16 + lc;
            bH[ni] = *reinterpret_cast<const bf16x8*>(&BsH[br][kg * 8]);
            bL[ni] = *reinterpret_cast<const bf16x8*>(&BsL[br][kg * 8]);
        }
#pragma unroll
        for (int mi = 0; mi < 4; ++mi)
#pragma unroll
            for (int ni = 0; ni < 4; ++ni) {
                acc[mi][ni] = __builtin_amdgcn_mfma_f32_16x16x32_bf16(aH[mi], bH[ni], acc[mi][ni], 0, 0, 0);
                acc[mi][ni] = __builtin_amdgcn_mfma_f32_16x16x32_bf16(aH[mi], bL[ni], acc[mi][ni], 0, 0, 0);
                acc[mi][ni] = __builtin_amdgcn_mfma_f32_16x16x32_bf16(aL[mi], bH[ni], acc[mi][ni], 0, 0, 0);
            }
    }

    float pmax[4], psum[4];
#pragma unroll
    for (int ni = 0; ni < 4; ++ni) {
        int j = j0 + wx * 64 + ni * 16 + lc;
        float s = g[j] * rsqrtf(var[j] + 1e-5f);
        float sh = be[j] - mu[j] * s;
        float pm = -BIGF, ps = 0.f;
#pragma unroll
        for (int mi = 0; mi < 4; ++mi)
#pragma unroll
            for (int r = 0; r < 4; ++r) {
                float y = fmaf(acc[mi][ni][r], s, sh);
                y = (y >= 0.f) ? y : 0.2f * y;
                pm = fmaxf(pm, y);
                ps += y;
            }
        pmax[ni] = pm; psum[ni] = ps;
    }
#pragma unroll
    for (int ni = 0; ni < 4; ++ni) {
        pmax[ni] = fmaxf(pmax[ni], __shfl_xor(pmax[ni], 16, 64));
        pmax[ni] = fmaxf(pmax[ni], __shfl_xor(pmax[ni], 32, 64));
        psum[ni] += __shfl_xor(psum[ni], 16, 64);
        psum[ni] += __shfl_xor(psum[ni], 32, 64);
    }
    if (lane < 16) {
#pragma unroll
        for (int ni = 0; ni < 4; ++ni) {
            redm[wid][ni * 16 + lc] = pmax[ni];
            reds[wid][ni * 16 + lc] = psum[ni];
        }
    }
    __syncthreads();
    if (t < 128) {
        int wxq = t >> 6, cl = t & 63;
        float m = fmaxf(redm[wxq][cl], redm[2 + wxq][cl]);
        float sv = reds[wxq][cl] + reds[2 + wxq][cl];
        int b = i0 >> 11, rb = (i0 & 2047) >> 7;
        partmax[((size_t)b * 16 + rb) * 1024 + j0 + t] = m;
        partsum[((size_t)b * 16 + rb) * 1024 + j0 + t] = sv;
    }
}

// ======================= pooling reduce =======================
__global__ __launch_bounds__(256) void pool2_kernel(const float* __restrict__ partmax,
                                                    const float* __restrict__ partsum,
                                                    float* __restrict__ pooled)
{
    const int c = blockIdx.x * 256 + threadIdx.x;
    const int b = blockIdx.y;
    float m = -BIGF, s = 0.f;
    for (int rb = 0; rb < 16; ++rb) {
        m = fmaxf(m, partmax[((size_t)b * 16 + rb) * 1024 + c]);
        s += partsum[((size_t)b * 16 + rb) * 1024 + c];
    }
    pooled[(size_t)b * 2048 + c] = m;
    pooled[(size_t)b * 2048 + 1024 + c] = s * (1.f / 2048.f);
}

// ======================= tail FCs (split-K) =======================
__global__ __launch_bounds__(512) void fc1_partial(const float* __restrict__ pooled,
                                                   const float* __restrict__ Wa,
                                                   float* __restrict__ part)
{
    const int kk = blockIdx.x, b = blockIdx.y, c = threadIdx.x;
    __shared__ float sp[128];
    if (c < 128) sp[c] = pooled[(size_t)b * 2048 + kk * 128 + c];
    __syncthreads();
    const float* w = Wa + (size_t)kk * 128 * 512 + c;
    float acc = 0.f;
#pragma unroll 8
    for (int j = 0; j < 128; ++j) acc = fmaf(sp[j], w[(size_t)j * 512], acc);
    part[((size_t)b * 16 + kk) * 512 + c] = acc;
}

__global__ __launch_bounds__(512) void fc1_reduce(const float* __restrict__ part,
                                                  const float* __restrict__ g, const float* __restrict__ be,
                                                  const float* __restrict__ mu, const float* __restrict__ var,
                                                  float* __restrict__ t1)
{
    const int b = blockIdx.x, c = threadIdx.x;
    float acc = 0.f;
#pragma unroll
    for (int kk = 0; kk < 16; ++kk) acc += part[((size_t)b * 16 + kk) * 512 + c];
    float s = g[c] * rsqrtf(var[c] + 1e-5f);
    float y = acc * s + (be[c] - mu[c] * s);
    t1[(size_t)b * 512 + c] = (y >= 0.f) ? y : 0.2f * y;
}

__global__ __launch_bounds__(256) void fc2_partial(const float* __restrict__ t1,
                                                   const float* __restrict__ Wb,
                                                   float* __restrict__ part)
{
    const int kk = blockIdx.x, b = blockIdx.y, c = threadIdx.x;
    __shared__ float sp[128];
    if (c < 128) sp[c] = t1[(size_t)b * 512 + kk * 128 + c];
    __syncthreads();
    const float* w = Wb + (size_t)kk * 128 * 256 + c;
    float acc = 0.f;
#pragma unroll 8
    for (int j = 0; j < 128; ++j) acc = fmaf(sp[j], w[(size_t)j * 256], acc);
    part[((size_t)b * 4 + kk) * 256 + c] = acc;
}

__global__ __launch_bounds__(256) void fc2_reduce(const float* __restrict__ part,
                                                  const float* __restrict__ bias_b,
                                                  const float* __restrict__ g, const float* __restrict__ be,
                                                  const float* __restrict__ mu, const float* __restrict__ var,
                                                  float* __restrict__ t2)
{
    const int b = blockIdx.x, c = threadIdx.x;
    float acc = bias_b[c];
#pragma unroll
    for (int kk = 0; kk < 4; ++kk) acc += part[((size_t)b * 4 + kk) * 256 + c];
    float s = g[c] * rsqrtf(var[c] + 1e-5f);
    float y = acc * s + (be[c] - mu[c] * s);
    t2[(size_t)b * 256 + c] = (y >= 0.f) ? y : 0.2f * y;
}

__global__ __launch_bounds__(64) void fc3_kernel(const float* __restrict__ t2,
                                                 const float* __restrict__ Wc,
                                                 const float* __restrict__ bias_c,
                                                 float* __restrict__ out)
{
    const int b = blockIdx.x, c = threadIdx.x;
    __shared__ float sp[256];
    for (int k = c; k < 256; k += 64) sp[k] = t2[(size_t)b * 256 + k];
    __syncthreads();
    if (c < 40) {
        float acc = 0.f;
#pragma unroll 8
        for (int k = 0; k < 256; ++k) acc = fmaf(sp[k], Wc[(size_t)k * 40 + c], acc);
        out[(size_t)b * 40 + c] = acc + bias_c[c];
    }
}

// ======================= launch =======================
extern "C" void kernel_launch(void* const* d_in, const int* in_sizes, int n_in,
                              void* d_out, int out_size, void* d_ws, size_t ws_size,
                              hipStream_t stream)
{
    const float* pos = (const float*)d_in[0];
    const float* W1 = (const float*)d_in[1];
    const float* g1 = (const float*)d_in[2];  const float* be1 = (const float*)d_in[3];
    const float* mu1 = (const float*)d_in[4]; const float* va1 = (const float*)d_in[5];
    const float* W2 = (const float*)d_in[6];
    const float* g2 = (const float*)d_in[7];  const float* be2 = (const float*)d_in[8];
    const float* mu2 = (const float*)d_in[9]; const float* va2 = (const float*)d_in[10];
    const float* W3 = (const float*)d_in[11];
    const float* g3 = (const float*)d_in[12]; const float* be3 = (const float*)d_in[13];
    const float* mu3 = (const float*)d_in[14];const float* va3 = (const float*)d_in[15];
    const float* W4 = (const float*)d_in[16];
    const float* g4 = (const float*)d_in[17]; const float* be4 = (const float*)d_in[18];
    const float* mu4 = (const float*)d_in[19];const float* va4 = (const float*)d_in[20];
    const float* Wm = (const float*)d_in[21];
    const float* gm = (const float*)d_in[22]; const float* bem = (const float*)d_in[23];
    const float* mum = (const float*)d_in[24];const float* vam = (const float*)d_in[25];
    const float* Wa = (const float*)d_in[26];
    const float* ga = (const float*)d_in[27]; const float* bea = (const float*)d_in[28];
    const float* mua = (const float*)d_in[29];const float* vaa = (const float*)d_in[30];
    const float* Wb = (const float*)d_in[31];
    const float* gb = (const float*)d_in[32]; const float* beb = (const float*)d_in[33];
    const float* mub = (const float*)d_in[34];const float* vab = (const float*)d_in[35];
    const float* bias_b = (const float*)d_in[36];
    const float* Wc = (const float*)d_in[37];
    const float* bias_c = (const float*)d_in[38];

    char* ws = (char*)d_ws;
    size_t off = 0;
    auto alloc = [&](size_t bytes) -> void* {
        void* p = ws + off;
        off += (bytes + 255) & ~(size_t)255;
        return p;
    };
    float* xcat    = (float*)alloc((size_t)16384 * 512 * 4);
    float* sq      = (float*)alloc((size_t)16384 * 4);
    int*   idx     = (int*)  alloc((size_t)16384 * KNN * 4);
    float* apart   = (float*)alloc((size_t)16384 * 256 * 4);
    float* bpart   = (float*)alloc((size_t)16384 * 256 * 4);
    float* partmax = (float*)alloc((size_t)8 * 16 * 1024 * 4);
    float* partsum = (float*)alloc((size_t)8 * 16 * 1024 * 4);
    float* pooled  = (float*)alloc((size_t)8 * 2048 * 4);
    float* t1      = (float*)alloc((size_t)8 * 512 * 4);
    float* t2      = (float*)alloc((size_t)8 * 256 * 4);
    float* part1   = (float*)alloc((size_t)8 * 16 * 512 * 4);
    float* part2   = (float*)alloc((size_t)8 * 4 * 256 * 4);
    unsigned short* ah   = (unsigned short*)alloc((size_t)16384 * 512 * 2);
    unsigned short* al   = (unsigned short*)alloc((size_t)16384 * 512 * 2);
    unsigned short* wmtH = (unsigned short*)alloc((size_t)1024 * 512 * 2);
    unsigned short* wmtL = (unsigned short*)alloc((size_t)1024 * 512 * 2);
    const size_t fixed = off;
    const size_t per_b16 = (size_t)NPTS * NPTS * 2;   // 8.39 MB per batch (u16 keys)

    int CB; unsigned short* d2u16;
    if      (ws_size >= fixed + 8 * per_b16) { CB = 8; d2u16 = (unsigned short*)(ws + fixed); }
    else if (ws_size >= fixed + 4 * per_b16) { CB = 4; d2u16 = (unsigned short*)(ws + fixed); }
    else { CB = 4; d2u16 = (unsigned short*)apart; }  // apart+bpart = 33.55MB, dead in this phase

    struct LayerDesc {
        const float* xin; int lda; int F; int Fout;
        float* xout; const float* W;
        const float* g; const float* be; const float* mu; const float* va;
    };
    LayerDesc Ls[4] = {
        { pos,        3,   3,   64,  xcat + 0,   W1, g1, be1, mu1, va1 },
        { xcat + 0,   512, 64,  64,  xcat + 64,  W2, g2, be2, mu2, va2 },
        { xcat + 64,  512, 64,  128, xcat + 128, W3, g3, be3, mu3, va3 },
        { xcat + 128, 512, 128, 256, xcat + 256, W4, g4, be4, mu4, va4 },
    };

    for (int L = 0; L < 4; ++L) {
        const LayerDesc& ld = Ls[L];
        sq_kernel<<<64, 256, 0, stream>>>(ld.xin, ld.lda, ld.F, sq);
        for (int b0 = 0; b0 < BATCH; b0 += CB) {
            int cb = (BATCH - b0 < CB) ? (BATCH - b0) : CB;
            distk_kernel<<<dim3(16, 16, cb), 256, 0, stream>>>(ld.xin, ld.lda, sq, d2u16, ld.F, b0);
            if (ld.F == 3)
                select_kernel<3><<<512 * cb, 256, 0, stream>>>(d2u16, ld.xin, ld.lda, sq, idx, b0);
            else if (ld.F == 64)
                select_kernel<64><<<512 * cb, 256, 0, stream>>>(d2u16, ld.xin, ld.lda, sq, idx, b0);
            else
                select_kernel<128><<<512 * cb, 256, 0, stream>>>(d2u16, ld.xin, ld.lda, sq, idx, b0);
        }
        gemm64_kernel<<<dim3(256, ld.Fout / 64, 2), 256, 0, stream>>>(
            ld.xin, ld.lda, ld.F, ld.W, ld.Fout, apart, bpart);
        if (ld.Fout == 64)
            aggregate_kernel<64><<<1024, 256, 0, stream>>>(apart, bpart, idx,
                ld.g, ld.be, ld.mu, ld.va, ld.xout);
        else if (ld.Fout == 128)
            aggregate_kernel<128><<<2048, 256, 0, stream>>>(apart, bpart, idx,
                ld.g, ld.be, ld.mu, ld.va, ld.xout);
        else
            aggregate_kernel<256><<<4096, 256, 0, stream>>>(apart, bpart, idx,
                ld.g, ld.be, ld.mu, ld.va, ld.xout);
    }

    cvt_kernel<<<4096, 256, 0, stream>>>(xcat, ah, al);
    cvtT_kernel<<<dim3(32, 16), 256, 0, stream>>>(Wm, wmtH, wmtL);
    wm_mfma_pool<<<dim3(128, 8), 256, 0, stream>>>(ah, al, wmtH, wmtL,
                                                   gm, bem, mum, vam, partmax, partsum);
    pool2_kernel<<<dim3(4, 8), 256, 0, stream>>>(partmax, partsum, pooled);
    fc1_partial<<<dim3(16, 8), 512, 0, stream>>>(pooled, Wa, part1);
    fc1_reduce<<<8, 512, 0, stream>>>(part1, ga, bea, mua, vaa, t1);
    fc2_partial<<<dim3(4, 8), 256, 0, stream>>>(t1, Wb, part2);
    fc2_reduce<<<8, 256, 0, stream>>>(part2, bias_b, gb, beb, mub, vab, t2);
    fc3_kernel<<<8, 64, 0, stream>>>(t2, Wc, bias_c, (float*)d_out);
}

// Round 12
// 802.796 us; speedup vs baseline: 5.2055x; 1.0672x over previous
//
#include <hip/hip_runtime.h>
#include <cstdint>
#include <cstddef>

#define NPTS 2048
#define BATCH 8
#define KNN 20
#define BIGF 3.402823466e38f

typedef short bf16x8 __attribute__((ext_vector_type(8)));
typedef float f32x4 __attribute__((ext_vector_type(4)));

__device__ __forceinline__ unsigned short f2bf(float v) {
    uint32_t u = __float_as_uint(v);
    uint32_t r = (u + 0x7FFFu + ((u >> 16) & 1u)) >> 16;
    return (unsigned short)r;
}
__device__ __forceinline__ float bf2f(unsigned short h) {
    return __uint_as_float(((uint32_t)h) << 16);
}
__device__ __forceinline__ uint32_t flipkey(float d) {
    uint32_t u = __float_as_uint(d);
    return (u & 0x80000000u) ? ~u : (u | 0x80000000u);
}
// exact d2 key: combine MUST be identical in distk and select-recompute
__device__ __forceinline__ uint32_t d2key(float acc, float si, float sj) {
    return flipkey(fmaf(-2.f, acc, si + sj));
}
__device__ __forceinline__ uint64_t shfl_xor_u64(uint64_t v, int m) {
    int lo = __shfl_xor((int)(uint32_t)v, m, 64);
    int hi = __shfl_xor((int)(uint32_t)(v >> 32), m, 64);
    return ((uint64_t)(uint32_t)hi << 32) | (uint32_t)lo;
}

// ======================= sum of squares per point =======================
__global__ __launch_bounds__(256) void sq_kernel(const float* __restrict__ x, int lda, int F,
                                                 float* __restrict__ sq)
{
    int p = blockIdx.x * 256 + threadIdx.x;   // 0..16383
    const float* xp = x + (size_t)p * lda;
    float s = 0.f;
    for (int f = 0; f < F; ++f) { float v = xp[f]; s = fmaf(v, v, s); }
    sq[p] = s;
}

// ======================= symmetric distance GEMM -> u16 truncated keys =======================
// Upper-triangle tiles only (keys are bitwise-symmetric: commutative fmaf chain).
// Direct tile stored as before (full-line ushort4 rows); mirrored tile via LDS bounce
// with contiguous transposed row stores. 47% less GEMM work than full grid.
__global__ __launch_bounds__(256) void distk_sym(const float* __restrict__ x, int lda,
                                                 const float* __restrict__ sq,
                                                 unsigned short* __restrict__ d2u16,
                                                 int F, int b0)
{
    __shared__ __align__(16) float As[8][132];
    __shared__ __align__(16) float Bs[8][132];
    __shared__ unsigned short tb[128][130];   // stride 130 u16: transpose reads ~2-way

    // decode upper-triangle tile id -> (ti, tj), ti <= tj
    int tid = blockIdx.x;
    int ti = 0;
    while (tid >= 16 - ti) { tid -= 16 - ti; ++ti; }
    const int tj = ti + tid;
    const int i0 = ti * 128;
    const int j0 = tj * 128;

    const int b  = b0 + blockIdx.y;
    const float* xb  = x + (size_t)b * NPTS * lda;
    const float* sqb = sq + (size_t)b * NPTS;
    const int t  = threadIdx.x;
    const int tx = t & 15, ty = t >> 4;
    const int lrow = t >> 1, lkq = (t & 1) * 4;

    float acc[8][8];
#pragma unroll
    for (int r = 0; r < 8; ++r)
#pragma unroll
        for (int c = 0; c < 8; ++c) acc[r][c] = 0.f;

    for (int k0 = 0; k0 < F; k0 += 8) {
        const float* sa = xb + (size_t)(i0 + lrow) * lda + k0 + lkq;
        const float* sb = xb + (size_t)(j0 + lrow) * lda + k0 + lkq;
        if (k0 + 8 <= F) {
            float4 a4 = *reinterpret_cast<const float4*>(sa);
            float4 b4 = *reinterpret_cast<const float4*>(sb);
            As[lkq + 0][lrow] = a4.x; As[lkq + 1][lrow] = a4.y;
            As[lkq + 2][lrow] = a4.z; As[lkq + 3][lrow] = a4.w;
            Bs[lkq + 0][lrow] = b4.x; Bs[lkq + 1][lrow] = b4.y;
            Bs[lkq + 2][lrow] = b4.z; Bs[lkq + 3][lrow] = b4.w;
        } else {
#pragma unroll
            for (int q = 0; q < 4; ++q) {
                int kk = k0 + lkq + q;
                As[lkq + q][lrow] = (kk < F) ? sa[q] : 0.f;
                Bs[lkq + q][lrow] = (kk < F) ? sb[q] : 0.f;
            }
        }
        __syncthreads();
#pragma unroll
        for (int k = 0; k < 8; ++k) {
            float4 a0 = *reinterpret_cast<const float4*>(&As[k][ty * 4]);
            float4 a1 = *reinterpret_cast<const float4*>(&As[k][64 + ty * 4]);
            float4 c0 = *reinterpret_cast<const float4*>(&Bs[k][tx * 4]);
            float4 c1 = *reinterpret_cast<const float4*>(&Bs[k][64 + tx * 4]);
            float av[8] = {a0.x, a0.y, a0.z, a0.w, a1.x, a1.y, a1.z, a1.w};
            float bv[8] = {c0.x, c0.y, c0.z, c0.w, c1.x, c1.y, c1.z, c1.w};
#pragma unroll
            for (int r = 0; r < 8; ++r)
#pragma unroll
                for (int c = 0; c < 8; ++c) acc[r][c] = fmaf(av[r], bv[c], acc[r][c]);
        }
        __syncthreads();
    }

    unsigned short* db = d2u16 + (size_t)blockIdx.y * NPTS * NPTS;
    const bool mirror = (ti != tj);
#pragma unroll
    for (int r = 0; r < 8; ++r) {
        int il = (r < 4) ? (ty * 4 + r) : (64 + ty * 4 + r - 4);
        int i = i0 + il;
        float si = sqb[i];
#pragma unroll
        for (int cq = 0; cq < 2; ++cq) {
            int jl = (cq ? 64 : 0) + tx * 4;
            int j = j0 + jl;
            ushort4 o;
            o.x = (unsigned short)(d2key(acc[r][cq * 4 + 0], si, sqb[j + 0]) >> 16);
            o.y = (unsigned short)(d2key(acc[r][cq * 4 + 1], si, sqb[j + 1]) >> 16);
            o.z = (unsigned short)(d2key(acc[r][cq * 4 + 2], si, sqb[j + 2]) >> 16);
            o.w = (unsigned short)(d2key(acc[r][cq * 4 + 3], si, sqb[j + 3]) >> 16);
            *reinterpret_cast<ushort4*>(&db[(size_t)i * NPTS + j]) = o;
            if (mirror) {
                ushort2 p0; p0.x = o.x; p0.y = o.y;
                ushort2 p1; p1.x = o.z; p1.y = o.w;
                *reinterpret_cast<ushort2*>(&tb[il][jl])     = p0;
                *reinterpret_cast<ushort2*>(&tb[il][jl + 2]) = p1;
            }
        }
    }
    if (mirror) {
        __syncthreads();
        const int lane = t & 63, w = t >> 6;
        for (int jj = w; jj < 128; jj += 4) {
            ushort2 v;
            v.x = tb[2 * lane + 0][jj];
            v.y = tb[2 * lane + 1][jj];
            *reinterpret_cast<ushort2*>(&db[(size_t)(j0 + jj) * NPTS + i0 + 2 * lane]) = v;
        }
    }
}

// ======================= top-20 from u16 keys + exact tie re-rank =======================
template <int F>
__global__ __launch_bounds__(256) void select_kernel(const unsigned short* __restrict__ d2u16,
                                                     const float* __restrict__ x, int lda,
                                                     const float* __restrict__ sq,
                                                     int* __restrict__ idx, int b0)
{
    const int t    = threadIdx.x;
    const int lane = t & 63;
    const int wid  = t >> 6;
    const int row_id = blockIdx.x * 4 + wid;
    const int bz = row_id >> 11;
    const int i  = row_id & 2047;
    const unsigned short* row = d2u16 + ((size_t)bz * NPTS + i) * NPTS;

    uint32_t cand[32];
#pragma unroll
    for (int s = 0; s < 4; ++s) {
        uint4 kv = *reinterpret_cast<const uint4*>(&row[s * 512 + lane * 8]);
        uint32_t cb = (uint32_t)(s * 512 + lane * 8);
        cand[s * 8 + 0] = ((kv.x & 0xFFFFu) << 16) | (cb + 0);
        cand[s * 8 + 1] = (kv.x & 0xFFFF0000u)      | (cb + 1);
        cand[s * 8 + 2] = ((kv.y & 0xFFFFu) << 16) | (cb + 2);
        cand[s * 8 + 3] = (kv.y & 0xFFFF0000u)      | (cb + 3);
        cand[s * 8 + 4] = ((kv.z & 0xFFFFu) << 16) | (cb + 4);
        cand[s * 8 + 5] = (kv.z & 0xFFFF0000u)      | (cb + 5);
        cand[s * 8 + 6] = ((kv.w & 0xFFFFu) << 16) | (cb + 6);
        cand[s * 8 + 7] = (kv.w & 0xFFFF0000u)      | (cb + 7);
    }

    const uint32_t MAXV = 0xFFFFFFFFu;
    uint32_t t1 = MAXV, t2 = MAXV, t3 = MAXV, t4 = MAXV;
#pragma unroll
    for (int s = 0; s < 32; ++s) {
        uint32_t c = cand[s];
        if (c < t4) {
            if (c < t2) {
                t4 = t3; t3 = t2;
                if (c < t1) { t2 = t1; t1 = c; } else t2 = c;
            } else {
                if (c < t3) { t4 = t3; t3 = c; } else t4 = c;
            }
        }
    }

    uint32_t keep = 0, last = 0;
    for (int it = 0; it < KNN; ++it) {
        uint32_t w = t1;
#pragma unroll
        for (int o = 1; o < 64; o <<= 1)
            w = min(w, (uint32_t)__shfl_xor((int)w, o, 64));
        keep = (lane == it) ? w : keep;
        last = w;
        if (t1 == w) {
            t1 = t2; t2 = t3; t3 = t4; t4 = MAXV;
            if (t1 == MAXV) {          // rare refill
#pragma unroll
                for (int s = 0; s < 32; ++s) {
                    uint32_t c = cand[s];
                    if (c > w && c < t4) {
                        if (c < t2) {
                            t4 = t3; t3 = t2;
                            if (c < t1) { t2 = t1; t1 = c; } else t2 = c;
                        } else {
                            if (c < t3) { t4 = t3; t3 = c; } else t4 = c;
                        }
                    }
                }
            }
        }
    }

    int* out = idx + ((size_t)(b0 + bz) * NPTS + i) * KNN;
    const uint32_t thr16 = last >> 16;

    int cnt = 0;
#pragma unroll
    for (int s = 0; s < 32; ++s) cnt += ((cand[s] >> 16) == thr16) ? 1 : 0;
#pragma unroll
    for (int o = 1; o < 64; o <<= 1) cnt += __shfl_xor(cnt, o, 64);

    unsigned long long bm = __ballot(lane < KNN && (keep >> 16) < thr16);
    const int sel_lt = (int)__popcll(bm);
    const int m = KNN - sel_lt;
    const bool fast = (cnt == m);

    if (lane < KNN && (fast || (keep >> 16) < thr16))
        out[lane] = (int)(keep & 0xFFFFu);
    if (fast) return;

    // exact re-rank of the tie bucket
    const float* xb  = x + (size_t)(b0 + bz) * NPTS * lda;
    const float* sqb = sq + (size_t)(b0 + bz) * NPTS;
    const float si = sqb[i];
    const float* xi = xb + (size_t)i * lda;

    uint64_t tc[4]; int ntc = 0; bool ovf = false;
#pragma unroll
    for (int s = 0; s < 32; ++s) {
        if ((cand[s] >> 16) == thr16) {
            if (ntc < 4) {
                int j = (int)(cand[s] & 0xFFFFu);
                const float* xj = xb + (size_t)j * lda;
                float dot = 0.f;
#pragma unroll
                for (int k = 0; k < F; ++k) dot = fmaf(xi[k], xj[k], dot);
                uint32_t fk = d2key(dot, si, sqb[j]);
                tc[ntc++] = ((uint64_t)fk << 32) | (uint32_t)j;
            } else ovf = true;
        }
    }
    if (__ballot(ovf)) {               // pathological: recompute inline per iteration
        uint64_t last_ex = 0;
        for (int q = 0; q < m; ++q) {
            uint64_t lm = ~0ull;
            for (int s = 0; s < 32; ++s) {
                if ((cand[s] >> 16) == thr16) {
                    int j = (int)(cand[s] & 0xFFFFu);
                    const float* xj = xb + (size_t)j * lda;
                    float dot = 0.f;
                    for (int k = 0; k < F; ++k) dot = fmaf(xi[k], xj[k], dot);
                    uint64_t e = ((uint64_t)d2key(dot, si, sqb[j]) << 32) | (uint32_t)j;
                    if (e > last_ex && e < lm) lm = e;
                }
            }
#pragma unroll
            for (int o = 1; o < 64; o <<= 1) {
                uint64_t ov = shfl_xor_u64(lm, o);
                lm = (ov < lm) ? ov : lm;
            }
            if (lane == 0) out[sel_lt + q] = (int)(lm & 0xFFFFu);
            last_ex = lm;
        }
        return;
    }
    uint64_t last_ex = 0;
    for (int q = 0; q < m; ++q) {
        uint64_t lm = ~0ull;
#pragma unroll
        for (int u = 0; u < 4; ++u)
            if (u < ntc && tc[u] > last_ex && tc[u] < lm) lm = tc[u];
#pragma unroll
        for (int o = 1; o < 64; o <<= 1) {
            uint64_t ov = shfl_xor_u64(lm, o);
            lm = (ov < lm) ? ov : lm;
        }
        if (lane == 0) out[sel_lt + q] = (int)(lm & 0xFFFFu);
        last_ex = lm;
    }
}

// ======================= dual small GEMM: apart & bpart in one dispatch =======================
__global__ __launch_bounds__(256) void gemm64_kernel(const float* __restrict__ A, int lda, int F,
                                                     const float* __restrict__ Wfull, int Fout,
                                                     float* __restrict__ apart,
                                                     float* __restrict__ bpart)
{
    __shared__ float As[16][68];
    __shared__ float Bs[16][65];
    const int i0 = blockIdx.x * 64, j0 = blockIdx.y * 64;
    const int half = blockIdx.z;
    const float* Bw = Wfull + (size_t)(half ? F : 0) * Fout;
    float* C = half ? bpart : apart;
    const int t = threadIdx.x, tx = t & 15, ty = t >> 4;
    float acc[4][4];
#pragma unroll
    for (int r = 0; r < 4; ++r)
#pragma unroll
        for (int c = 0; c < 4; ++c) acc[r][c] = 0.f;
    const int arow = t >> 2, akq = (t & 3) * 4;
    const int bk = t >> 4, bj = (t & 15) * 4;
    for (int k0 = 0; k0 < F; k0 += 16) {
#pragma unroll
        for (int q = 0; q < 4; ++q) {
            int kk = k0 + akq + q;
            As[akq + q][arow] = (kk < F) ? A[(size_t)(i0 + arow) * lda + kk] : 0.f;
        }
        {
            int kk = k0 + bk;
#pragma unroll
            for (int q = 0; q < 4; ++q)
                Bs[bk][bj + q] = (kk < F) ? Bw[(size_t)kk * Fout + j0 + bj + q] : 0.f;
        }
        __syncthreads();
#pragma unroll
        for (int k = 0; k < 16; ++k) {
            float a[4], bb[4];
#pragma unroll
            for (int r = 0; r < 4; ++r) a[r] = As[k][ty * 4 + r];
#pragma unroll
            for (int c = 0; c < 4; ++c) bb[c] = Bs[k][tx * 4 + c];
#pragma unroll
            for (int r = 0; r < 4; ++r)
#pragma unroll
                for (int c = 0; c < 4; ++c) acc[r][c] = fmaf(a[r], bb[c], acc[r][c]);
        }
        __syncthreads();
    }
#pragma unroll
    for (int r = 0; r < 4; ++r)
#pragma unroll
        for (int c = 0; c < 4; ++c)
            C[(size_t)(i0 + ty * 4 + r) * Fout + j0 + tx * 4 + c] = acc[r][c];
}

// ======================= EdgeConv aggregate (float4 lanes, multi-point blocks) =======================
template <int FOUT>
__global__ __launch_bounds__(256) void aggregate_kernel(const float* __restrict__ apart,
                                                        const float* __restrict__ bpart,
                                                        const int* __restrict__ idx,
                                                        const float* __restrict__ g,
                                                        const float* __restrict__ be,
                                                        const float* __restrict__ mu,
                                                        const float* __restrict__ var,
                                                        float* __restrict__ out)
{
    constexpr int G   = FOUT / 4;
    constexpr int PPB = 256 / G;
    const int t  = threadIdx.x;
    const int pi = t / G;
    const int fi = t % G;
    const int p  = blockIdx.x * PPB + pi;
    const int b  = p >> 11;
    const int* nb = idx + (size_t)p * KNN;
    const float4* bp4 = reinterpret_cast<const float4*>(bpart);
    const float4* bb  = bp4 + ((size_t)b << 11) * G;

    float4 m = {-BIGF, -BIGF, -BIGF, -BIGF};
#pragma unroll 4
    for (int k = 0; k < KNN; ++k) {
        int j = nb[k];
        float4 v = bb[(size_t)j * G + fi];
        m.x = fmaxf(m.x, v.x); m.y = fmaxf(m.y, v.y);
        m.z = fmaxf(m.z, v.z); m.w = fmaxf(m.w, v.w);
    }
    float4 av = reinterpret_cast<const float4*>(apart)[(size_t)p * G + fi];
    float4 bv = bp4[(size_t)p * G + fi];
    float4 gg = reinterpret_cast<const float4*>(g)[fi];
    float4 bee = reinterpret_cast<const float4*>(be)[fi];
    float4 muu = reinterpret_cast<const float4*>(mu)[fi];
    float4 vaa = reinterpret_cast<const float4*>(var)[fi];

    float4 r;
    {
        float s, sh, vv, y;
        s = gg.x * rsqrtf(vaa.x + 1e-5f); sh = bee.x - muu.x * s;
        vv = av.x - bv.x + m.x; y = vv * s + sh; r.x = (y >= 0.f) ? y : 0.2f * y;
        s = gg.y * rsqrtf(vaa.y + 1e-5f); sh = bee.y - muu.y * s;
        vv = av.y - bv.y + m.y; y = vv * s + sh; r.y = (y >= 0.f) ? y : 0.2f * y;
        s = gg.z * rsqrtf(vaa.z + 1e-5f); sh = bee.z - muu.z * s;
        vv = av.z - bv.z + m.z; y = vv * s + sh; r.z = (y >= 0.f) ? y : 0.2f * y;
        s = gg.w * rsqrtf(vaa.w + 1e-5f); sh = bee.w - muu.w * s;
        vv = av.w - bv.w + m.w; y = vv * s + sh; r.w = (y >= 0.f) ? y : 0.2f * y;
    }
    *reinterpret_cast<float4*>(out + (size_t)p * 512 + fi * 4) = r;
}

// ======================= split-bf16 converters =======================
__global__ __launch_bounds__(256) void cvt_kernel(const float* __restrict__ in,
                                                  unsigned short* __restrict__ hi,
                                                  unsigned short* __restrict__ lo)
{
    int i = blockIdx.x * 256 + threadIdx.x;
    const float4* p = reinterpret_cast<const float4*>(in) + (size_t)i * 2;
    float4 a = p[0], b = p[1];
    float v[8] = {a.x, a.y, a.z, a.w, b.x, b.y, b.z, b.w};
    uint32_t h[8], l[8];
#pragma unroll
    for (int q = 0; q < 8; ++q) {
        unsigned short hb = f2bf(v[q]);
        h[q] = hb;
        l[q] = f2bf(v[q] - bf2f(hb));
    }
    uint4 uh, ul;
    uh.x = h[0] | (h[1] << 16); uh.y = h[2] | (h[3] << 16);
    uh.z = h[4] | (h[5] << 16); uh.w = h[6] | (h[7] << 16);
    ul.x = l[0] | (l[1] << 16); ul.y = l[2] | (l[3] << 16);
    ul.z = l[4] | (l[5] << 16); ul.w = l[6] | (l[7] << 16);
    reinterpret_cast<uint4*>(hi)[i] = uh;
    reinterpret_cast<uint4*>(lo)[i] = ul;
}

__global__ __launch_bounds__(256) void cvtT_kernel(const float* __restrict__ Wm,
                                                   unsigned short* __restrict__ hiT,
                                                   unsigned short* __restrict__ loT)
{
    __shared__ float tile[32][33];
    const int n0 = blockIdx.x * 32;
    const int k0 = blockIdx.y * 32;
    const int t = threadIdx.x;
    const int c = t & 31, r = t >> 5;
#pragma unroll
    for (int rr = 0; rr < 4; ++rr)
        tile[r + rr * 8][c] = Wm[(size_t)(k0 + r + rr * 8) * 1024 + n0 + c];
    __syncthreads();
#pragma unroll
    for (int rr = 0; rr < 4; ++rr) {
        int nn = r + rr * 8, kk = c;
        float v = tile[kk][nn];
        unsigned short hb = f2bf(v);
        hiT[(size_t)(n0 + nn) * 512 + k0 + kk] = hb;
        loT[(size_t)(n0 + nn) * 512 + k0 + kk] = f2bf(v - bf2f(hb));
    }
}

// ======================= Wm via split-bf16 MFMA + BN + lrelu + pooling =======================
__global__ __launch_bounds__(256) void wm_mfma_pool(const unsigned short* __restrict__ AH,
                                                    const unsigned short* __restrict__ AL,
                                                    const unsigned short* __restrict__ BH,
                                                    const unsigned short* __restrict__ BL,
                                                    const float* __restrict__ g,
                                                    const float* __restrict__ be,
                                                    const float* __restrict__ mu,
                                                    const float* __restrict__ var,
                                                    float* __restrict__ partmax,
                                                    float* __restrict__ partsum)
{
    __shared__ unsigned short AsH[128][40], AsL[128][40], BsH[128][40], BsL[128][40];
    __shared__ float redm[4][64], reds[4][64];
    const int t = threadIdx.x;
    const int i0 = blockIdx.x * 128, j0 = blockIdx.y * 128;
    const int lane = t & 63, wid = t >> 6, wy = wid >> 1, wx = wid & 1;
    const int lc = lane & 15, kg = lane >> 4;

    f32x4 acc[4][4];
#pragma unroll
    for (int mi = 0; mi < 4; ++mi)
#pragma unroll
        for (int ni = 0; ni < 4; ++ni) acc[mi][ni] = (f32x4){0.f, 0.f, 0.f, 0.f};

    for (int k0 = 0; k0 < 512; k0 += 32) {
        __syncthreads();
#pragma unroll
        for (int q = 0; q < 2; ++q) {
            int c = t + q * 256;
            int row = c >> 2, ko = (c & 3) * 8;
            *reinterpret_cast<uint4*>(&AsH[row][ko]) =
                *reinterpret_cast<const uint4*>(&AH[(size_t)(i0 + row) * 512 + k0 + ko]);
            *reinterpret_cast<uint4*>(&AsL[row][ko]) =
                *reinterpret_cast<const uint4*>(&AL[(size_t)(i0 + row) * 512 + k0 + ko]);
            *reinterpret_cast<uint4*>(&BsH[row][ko]) =
                *reinterpret_cast<const uint4*>(&BH[(size_t)(j0 + row) * 512 + k0 + ko]);
            *reinterpret_cast<uint4*>(&BsL[row][ko]) =
                *reinterpret_cast<const uint4*>(&BL[(size_t)(j0 + row) * 512 + k0 + ko]);
        }
        __syncthreads();

        bf16x8 aH[4], aL[4], bH[4], bL[4];
#pragma unroll
        for (int mi = 0; mi < 4; ++mi) {
            int ar = wy * 64 + mi * 16 + lc;
            aH[mi] = *reinterpret_cast<const bf16x8*>(&AsH[ar][kg * 8]);
            aL[mi] = *reinterpret_cast<const bf16x8*>(&AsL[ar][kg * 8]);
        }
#pragma unroll
        for (int ni = 0; ni < 4; ++ni) {
            int br = wx * 64 + ni * 16 + lc;
            bH[ni] = *reinterpret_cast<const bf16x8*>(&BsH[br][kg * 8]);
            bL[ni] = *reinterpret_cast<const bf16x8*>(&BsL[br][kg * 8]);
        }
#pragma unroll
        for (int mi = 0; mi < 4; ++mi)
#pragma unroll
            for (int ni = 0; ni < 4; ++ni) {
                acc[mi][ni] = __builtin_amdgcn_mfma_f32_16x16x32_bf16(aH[mi], bH[ni], acc[mi][ni], 0, 0, 0);
                acc[mi][ni] = __builtin_amdgcn_mfma_f32_16x16x32_bf16(aH[mi], bL[ni], acc[mi][ni], 0, 0, 0);
                acc[mi][ni] = __builtin_amdgcn_mfma_f32_16x16x32_bf16(aL[mi], bH[ni], acc[mi][ni], 0, 0, 0);
            }
    }

    float pmax[4], psum[4];
#pragma unroll
    for (int ni = 0; ni < 4; ++ni) {
        int j = j0 + wx * 64 + ni * 16 + lc;
        float s = g[j] * rsqrtf(var[j] + 1e-5f);
        float sh = be[j] - mu[j] * s;
        float pm = -BIGF, ps = 0.f;
#pragma unroll
        for (int mi = 0; mi < 4; ++mi)
#pragma unroll
            for (int r = 0; r < 4; ++r) {
                float y = fmaf(acc[mi][ni][r], s, sh);
                y = (y >= 0.f) ? y : 0.2f * y;
                pm = fmaxf(pm, y);
                ps += y;
            }
        pmax[ni] = pm; psum[ni] = ps;
    }
#pragma unroll
    for (int ni = 0; ni < 4; ++ni) {
        pmax[ni] = fmaxf(pmax[ni], __shfl_xor(pmax[ni], 16, 64));
        pmax[ni] = fmaxf(pmax[ni], __shfl_xor(pmax[ni], 32, 64));
        psum[ni] += __shfl_xor(psum[ni], 16, 64);
        psum[ni] += __shfl_xor(psum[ni], 32, 64);
    }
    if (lane < 16) {
#pragma unroll
        for (int ni = 0; ni < 4; ++ni) {
            redm[wid][ni * 16 + lc] = pmax[ni];
            reds[wid][ni * 16 + lc] = psum[ni];
        }
    }
    __syncthreads();
    if (t < 128) {
        int wxq = t >> 6, cl = t & 63;
        float m = fmaxf(redm[wxq][cl], redm[2 + wxq][cl]);
        float sv = reds[wxq][cl] + reds[2 + wxq][cl];
        int b = i0 >> 11, rb = (i0 & 2047) >> 7;
        partmax[((size_t)b * 16 + rb) * 1024 + j0 + t] = m;
        partsum[((size_t)b * 16 + rb) * 1024 + j0 + t] = sv;
    }
}

// ======================= pooling reduce =======================
__global__ __launch_bounds__(256) void pool2_kernel(const float* __restrict__ partmax,
                                                    const float* __restrict__ partsum,
                                                    float* __restrict__ pooled)
{
    const int c = blockIdx.x * 256 + threadIdx.x;
    const int b = blockIdx.y;
    float m = -BIGF, s = 0.f;
    for (int rb = 0; rb < 16; ++rb) {
        m = fmaxf(m, partmax[((size_t)b * 16 + rb) * 1024 + c]);
        s += partsum[((size_t)b * 16 + rb) * 1024 + c];
    }
    pooled[(size_t)b * 2048 + c] = m;
    pooled[(size_t)b * 2048 + 1024 + c] = s * (1.f / 2048.f);
}

// ======================= tail FCs (split-K) =======================
__global__ __launch_bounds__(512) void fc1_partial(const float* __restrict__ pooled,
                                                   const float* __restrict__ Wa,
                                                   float* __restrict__ part)
{
    const int kk = blockIdx.x, b = blockIdx.y, c = threadIdx.x;
    __shared__ float sp[128];
    if (c < 128) sp[c] = pooled[(size_t)b * 2048 + kk * 128 + c];
    __syncthreads();
    const float* w = Wa + (size_t)kk * 128 * 512 + c;
    float acc = 0.f;
#pragma unroll 8
    for (int j = 0; j < 128; ++j) acc = fmaf(sp[j], w[(size_t)j * 512], acc);
    part[((size_t)b * 16 + kk) * 512 + c] = acc;
}

__global__ __launch_bounds__(512) void fc1_reduce(const float* __restrict__ part,
                                                  const float* __restrict__ g, const float* __restrict__ be,
                                                  const float* __restrict__ mu, const float* __restrict__ var,
                                                  float* __restrict__ t1)
{
    const int b = blockIdx.x, c = threadIdx.x;
    float acc = 0.f;
#pragma unroll
    for (int kk = 0; kk < 16; ++kk) acc += part[((size_t)b * 16 + kk) * 512 + c];
    float s = g[c] * rsqrtf(var[c] + 1e-5f);
    float y = acc * s + (be[c] - mu[c] * s);
    t1[(size_t)b * 512 + c] = (y >= 0.f) ? y : 0.2f * y;
}

__global__ __launch_bounds__(256) void fc2_partial(const float* __restrict__ t1,
                                                   const float* __restrict__ Wb,
                                                   float* __restrict__ part)
{
    const int kk = blockIdx.x, b = blockIdx.y, c = threadIdx.x;
    __shared__ float sp[128];
    if (c < 128) sp[c] = t1[(size_t)b * 512 + kk * 128 + c];
    __syncthreads();
    const float* w = Wb + (size_t)kk * 128 * 256 + c;
    float acc = 0.f;
#pragma unroll 8
    for (int j = 0; j < 128; ++j) acc = fmaf(sp[j], w[(size_t)j * 256], acc);
    part[((size_t)b * 4 + kk) * 256 + c] = acc;
}

__global__ __launch_bounds__(256) void fc2_reduce(const float* __restrict__ part,
                                                  const float* __restrict__ bias_b,
                                                  const float* __restrict__ g, const float* __restrict__ be,
                                                  const float* __restrict__ mu, const float* __restrict__ var,
                                                  float* __restrict__ t2)
{
    const int b = blockIdx.x, c = threadIdx.x;
    float acc = bias_b[c];
#pragma unroll
    for (int kk = 0; kk < 4; ++kk) acc += part[((size_t)b * 4 + kk) * 256 + c];
    float s = g[c] * rsqrtf(var[c] + 1e-5f);
    float y = acc * s + (be[c] - mu[c] * s);
    t2[(size_t)b * 256 + c] = (y >= 0.f) ? y : 0.2f * y;
}

__global__ __launch_bounds__(64) void fc3_kernel(const float* __restrict__ t2,
                                                 const float* __restrict__ Wc,
                                                 const float* __restrict__ bias_c,
                                                 float* __restrict__ out)
{
    const int b = blockIdx.x, c = threadIdx.x;
    __shared__ float sp[256];
    for (int k = c; k < 256; k += 64) sp[k] = t2[(size_t)b * 256 + k];
    __syncthreads();
    if (c < 40) {
        float acc = 0.f;
#pragma unroll 8
        for (int k = 0; k < 256; ++k) acc = fmaf(sp[k], Wc[(size_t)k * 40 + c], acc);
        out[(size_t)b * 40 + c] = acc + bias_c[c];
    }
}

// ======================= launch =======================
extern "C" void kernel_launch(void* const* d_in, const int* in_sizes, int n_in,
                              void* d_out, int out_size, void* d_ws, size_t ws_size,
                              hipStream_t stream)
{
    const float* pos = (const float*)d_in[0];
    const float* W1 = (const float*)d_in[1];
    const float* g1 = (const float*)d_in[2];  const float* be1 = (const float*)d_in[3];
    const float* mu1 = (const float*)d_in[4]; const float* va1 = (const float*)d_in[5];
    const float* W2 = (const float*)d_in[6];
    const float* g2 = (const float*)d_in[7];  const float* be2 = (const float*)d_in[8];
    const float* mu2 = (const float*)d_in[9]; const float* va2 = (const float*)d_in[10];
    const float* W3 = (const float*)d_in[11];
    const float* g3 = (const float*)d_in[12]; const float* be3 = (const float*)d_in[13];
    const float* mu3 = (const float*)d_in[14];const float* va3 = (const float*)d_in[15];
    const float* W4 = (const float*)d_in[16];
    const float* g4 = (const float*)d_in[17]; const float* be4 = (const float*)d_in[18];
    const float* mu4 = (const float*)d_in[19];const float* va4 = (const float*)d_in[20];
    const float* Wm = (const float*)d_in[21];
    const float* gm = (const float*)d_in[22]; const float* bem = (const float*)d_in[23];
    const float* mum = (const float*)d_in[24];const float* vam = (const float*)d_in[25];
    const float* Wa = (const float*)d_in[26];
    const float* ga = (const float*)d_in[27]; const float* bea = (const float*)d_in[28];
    const float* mua = (const float*)d_in[29];const float* vaa = (const float*)d_in[30];
    const float* Wb = (const float*)d_in[31];
    const float* gb = (const float*)d_in[32]; const float* beb = (const float*)d_in[33];
    const float* mub = (const float*)d_in[34];const float* vab = (const float*)d_in[35];
    const float* bias_b = (const float*)d_in[36];
    const float* Wc = (const float*)d_in[37];
    const float* bias_c = (const float*)d_in[38];

    char* ws = (char*)d_ws;
    size_t off = 0;
    auto alloc = [&](size_t bytes) -> void* {
        void* p = ws + off;
        off += (bytes + 255) & ~(size_t)255;
        return p;
    };
    float* xcat    = (float*)alloc((size_t)16384 * 512 * 4);
    float* sq      = (float*)alloc((size_t)16384 * 4);
    int*   idx     = (int*)  alloc((size_t)16384 * KNN * 4);
    float* apart   = (float*)alloc((size_t)16384 * 256 * 4);
    float* bpart   = (float*)alloc((size_t)16384 * 256 * 4);
    float* partmax = (float*)alloc((size_t)8 * 16 * 1024 * 4);
    float* partsum = (float*)alloc((size_t)8 * 16 * 1024 * 4);
    float* pooled  = (float*)alloc((size_t)8 * 2048 * 4);
    float* t1      = (float*)alloc((size_t)8 * 512 * 4);
    float* t2      = (float*)alloc((size_t)8 * 256 * 4);
    float* part1   = (float*)alloc((size_t)8 * 16 * 512 * 4);
    float* part2   = (float*)alloc((size_t)8 * 4 * 256 * 4);
    unsigned short* ah   = (unsigned short*)alloc((size_t)16384 * 512 * 2);
    unsigned short* al   = (unsigned short*)alloc((size_t)16384 * 512 * 2);
    unsigned short* wmtH = (unsigned short*)alloc((size_t)1024 * 512 * 2);
    unsigned short* wmtL = (unsigned short*)alloc((size_t)1024 * 512 * 2);
    const size_t fixed = off;
    const size_t per_b16 = (size_t)NPTS * NPTS * 2;   // 8.39 MB per batch (u16 keys)

    int CB; unsigned short* d2u16;
    if      (ws_size >= fixed + 8 * per_b16) { CB = 8; d2u16 = (unsigned short*)(ws + fixed); }
    else if (ws_size >= fixed + 4 * per_b16) { CB = 4; d2u16 = (unsigned short*)(ws + fixed); }
    else { CB = 4; d2u16 = (unsigned short*)apart; }  // apart+bpart = 33.55MB, dead in this phase

    struct LayerDesc {
        const float* xin; int lda; int F; int Fout;
        float* xout; const float* W;
        const float* g; const float* be; const float* mu; const float* va;
    };
    LayerDesc Ls[4] = {
        { pos,        3,   3,   64,  xcat + 0,   W1, g1, be1, mu1, va1 },
        { xcat + 0,   512, 64,  64,  xcat + 64,  W2, g2, be2, mu2, va2 },
        { xcat + 64,  512, 64,  128, xcat + 128, W3, g3, be3, mu3, va3 },
        { xcat + 128, 512, 128, 256, xcat + 256, W4, g4, be4, mu4, va4 },
    };

    for (int L = 0; L < 4; ++L) {
        const LayerDesc& ld = Ls[L];
        sq_kernel<<<64, 256, 0, stream>>>(ld.xin, ld.lda, ld.F, sq);
        for (int b0 = 0; b0 < BATCH; b0 += CB) {
            int cb = (BATCH - b0 < CB) ? (BATCH - b0) : CB;
            distk_sym<<<dim3(136, cb), 256, 0, stream>>>(ld.xin, ld.lda, sq, d2u16, ld.F, b0);
            if (ld.F == 3)
                select_kernel<3><<<512 * cb, 256, 0, stream>>>(d2u16, ld.xin, ld.lda, sq, idx, b0);
            else if (ld.F == 64)
                select_kernel<64><<<512 * cb, 256, 0, stream>>>(d2u16, ld.xin, ld.lda, sq, idx, b0);
            else
                select_kernel<128><<<512 * cb, 256, 0, stream>>>(d2u16, ld.xin, ld.lda, sq, idx, b0);
        }
        gemm64_kernel<<<dim3(256, ld.Fout / 64, 2), 256, 0, stream>>>(
            ld.xin, ld.lda, ld.F, ld.W, ld.Fout, apart, bpart);
        if (ld.Fout == 64)
            aggregate_kernel<64><<<1024, 256, 0, stream>>>(apart, bpart, idx,
                ld.g, ld.be, ld.mu, ld.va, ld.xout);
        else if (ld.Fout == 128)
            aggregate_kernel<128><<<2048, 256, 0, stream>>>(apart, bpart, idx,
                ld.g, ld.be, ld.mu, ld.va, ld.xout);
        else
            aggregate_kernel<256><<<4096, 256, 0, stream>>>(apart, bpart, idx,
                ld.g, ld.be, ld.mu, ld.va, ld.xout);
    }

    cvt_kernel<<<4096, 256, 0, stream>>>(xcat, ah, al);
    cvtT_kernel<<<dim3(32, 16), 256, 0, stream>>>(Wm, wmtH, wmtL);
    wm_mfma_pool<<<dim3(128, 8), 256, 0, stream>>>(ah, al, wmtH, wmtL,
                                                   gm, bem, mum, vam, partmax, partsum);
    pool2_kernel<<<dim3(4, 8), 256, 0, stream>>>(partmax, partsum, pooled);
    fc1_partial<<<dim3(16, 8), 512, 0, stream>>>(pooled, Wa, part1);
    fc1_reduce<<<8, 512, 0, stream>>>(part1, ga, bea, mua, vaa, t1);
    fc2_partial<<<dim3(4, 8), 256, 0, stream>>>(t1, Wb, part2);
    fc2_reduce<<<8, 256, 0, stream>>>(part2, bias_b, gb, beb, mub, vab, t2);
    fc3_kernel<<<8, 64, 0, stream>>>(t2, Wc, bias_c, (float*)d_out);
}